// Round 12
// baseline (1242.836 us; speedup 1.0000x reference)
//
#include <hip/hip_runtime.h>

typedef _Float16 half8 __attribute__((ext_vector_type(8)));
typedef _Float16 half4 __attribute__((ext_vector_type(4)));
typedef float f32x4 __attribute__((ext_vector_type(4)));

// ---------------------------------------------------------------- transpose (f32)
__global__ __launch_bounds__(256) void transpose_f32(
    const float* __restrict__ in, int lda,
    float* __restrict__ out, int ldo)
{
  __shared__ float t[32][33];
  const int tx = threadIdx.x & 31, ty = threadIdx.x >> 5;
  const int bc = blockIdx.x * 32, br = blockIdx.y * 32;
#pragma unroll
  for (int i = 0; i < 4; ++i)
    t[ty + 8 * i][tx] = in[(size_t)(br + ty + 8 * i) * lda + bc + tx];
  __syncthreads();
#pragma unroll
  for (int i = 0; i < 4; ++i)
    out[(size_t)(bc + ty + 8 * i) * ldo + br + tx] = t[tx][ty + 8 * i];
}

// transpose with f32 -> f16 convert on output
__global__ __launch_bounds__(256) void transpose_f32_f16(
    const float* __restrict__ in, int lda,
    _Float16* __restrict__ out, int ldo)
{
  __shared__ float t[32][33];
  const int tx = threadIdx.x & 31, ty = threadIdx.x >> 5;
  const int bc = blockIdx.x * 32, br = blockIdx.y * 32;
#pragma unroll
  for (int i = 0; i < 4; ++i)
    t[ty + 8 * i][tx] = in[(size_t)(br + ty + 8 * i) * lda + bc + tx];
  __syncthreads();
#pragma unroll
  for (int i = 0; i < 4; ++i)
    out[(size_t)(bc + ty + 8 * i) * ldo + br + tx] = (_Float16)t[tx][ty + 8 * i];
}

// transpose with f32 -> f16 hi/lo SPLIT pair on output (lo plane at +plane)
__global__ __launch_bounds__(256) void transpose_f32_f16pair(
    const float* __restrict__ in, int lda,
    _Float16* __restrict__ outhi, int ldo, size_t plane)
{
  __shared__ float t[32][33];
  const int tx = threadIdx.x & 31, ty = threadIdx.x >> 5;
  const int bc = blockIdx.x * 32, br = blockIdx.y * 32;
#pragma unroll
  for (int i = 0; i < 4; ++i)
    t[ty + 8 * i][tx] = in[(size_t)(br + ty + 8 * i) * lda + bc + tx];
  __syncthreads();
#pragma unroll
  for (int i = 0; i < 4; ++i) {
    float v = t[tx][ty + 8 * i];
    _Float16 h = (_Float16)v;
    size_t idx = (size_t)(bc + ty + 8 * i) * ldo + br + tx;
    outhi[idx] = h;
    outhi[plane + idx] = (_Float16)(v - (float)h);
  }
}

// elementwise f32 -> f16 hi/lo split
__global__ __launch_bounds__(256) void split_f32_f16pair(
    const float4* __restrict__ in, _Float16* __restrict__ hi, size_t plane)
{
  size_t i = (size_t)blockIdx.x * 256 + threadIdx.x;
  float4 v = in[i];
  half4 h, l;
  h[0] = (_Float16)v.x; l[0] = (_Float16)(v.x - (float)h[0]);
  h[1] = (_Float16)v.y; l[1] = (_Float16)(v.y - (float)h[1]);
  h[2] = (_Float16)v.z; l[2] = (_Float16)(v.z - (float)h[2]);
  h[3] = (_Float16)v.w; l[3] = (_Float16)(v.w - (float)h[3]);
  ((half4*)hi)[i] = h;
  ((half4*)(hi + plane))[i] = l;
}

// ---------------------------------------------------------------- half column-sum (f16 input)
__global__ __launch_bounds__(256) void halfcolsum16(
    const _Float16* __restrict__ k0T16, float* __restrict__ csum)
{
  const int d = blockIdx.x, tid = threadIdx.x;
  float s = 0.f;
#pragma unroll
  for (int i = 0; i < 4; ++i) {
    half8 h = *(const half8*)(k0T16 + (size_t)d * 8192 + i * 2048 + tid * 8);
#pragma unroll
    for (int j = 0; j < 8; ++j) s += (float)h[j];
  }
#pragma unroll
  for (int off = 32; off; off >>= 1) s += __shfl_xor(s, off);
  __shared__ float r[4];
  if ((tid & 63) == 0) r[tid >> 6] = s;
  __syncthreads();
  if (tid == 0) csum[d] = 0.5f * ((r[0] + r[1]) + (r[2] + r[3]));
}

// ---------------------------------------------------------------- GEMM (BT)
// AMODE: 0 = f32 A, 1 = f16 A (APART planes summed), 2 = f16 hi/lo pair A
// BMODE: 0 = f32 B, 2 = f16 hi/lo pair B, 3 = f16 single plane B (pure copy)
template<int ASPL,int BSPL,int BM,int BN,int WAVES_M,int WAVES_N,int THREADS,
         int APART,bool KSPLIT,bool QF16,int MINW,int AMODE,int BMODE>
__global__ __launch_bounds__(THREADS, MINW) void gemm_bt(
    const void* __restrict__ Agv, int lda, size_t a_plane,
    const void* __restrict__ Bgv, int ldb, size_t b_plane,
    float* __restrict__ Cg, int ldc, size_t c_plane,
    const float* __restrict__ bias, int K, float scale,
    _Float16* __restrict__ q16out)
{
  constexpr int BK = 32;
  constexpr int WM = BM / WAVES_M, WN = BN / WAVES_N;
  constexpr int FM = WM / 16, FN = WN / 16;
  constexpr int NCA = (BM * 4) / THREADS;
  constexpr int NCB = (BN * 4) / THREADS;
  static_assert((BM * 4) % THREADS == 0 && (BN * 4) % THREADS == 0, "mismatch");

  __shared__ _Float16 ldsA[2][ASPL][BM][BK];
  __shared__ _Float16 ldsB[2][BSPL][BN][BK];

  const float*    Ag   = (const float*)Agv;
  const _Float16* Ag16 = (const _Float16*)Agv;
  const float*    Bg   = (const float*)Bgv;
  const _Float16* Bg16 = (const _Float16*)Bgv;

  const int tid  = threadIdx.x;
  const int lane = tid & 63;
  const int wid  = tid >> 6;
  const int wrow = wid / WAVES_N, wcol = wid % WAVES_N;
  const int l15  = lane & 15, g = lane >> 4;
  const int brow = blockIdx.y * BM;
  const int bcol = blockIdx.x * BN;

  if constexpr (KSPLIT) {
    const int kc = blockIdx.z;
    Ag += (size_t)kc * K;  Ag16 += (size_t)kc * K;
    Bg += (size_t)kc * K;  Bg16 += (size_t)kc * K;
    Cg += (size_t)kc * c_plane;
  }

  f32x4 acc[FM][FN];
#pragma unroll
  for (int mi = 0; mi < FM; ++mi)
#pragma unroll
    for (int ni = 0; ni < FN; ++ni)
      acc[mi][ni] = (f32x4){0.f, 0.f, 0.f, 0.f};

  float4 ra[NCA][2], rb[NCB][2];
  half8  rah[NCA][2], rbh[NCB][2];

  auto loadAB = [&](int kt) {
    const int k0 = kt * BK;
#pragma unroll
    for (int i = 0; i < NCA; ++i) {
      int c = tid + THREADS * i;
      int row = c >> 2, ci = c & 3;
      if constexpr (AMODE == 2) {
        const _Float16* bp = Ag16 + (size_t)(brow + row) * lda + k0 + ci * 8;
        rah[i][0] = *(const half8*)bp;
        rah[i][1] = *(const half8*)(bp + a_plane);
      } else if constexpr (AMODE == 1) {
        float4 u0 = make_float4(0.f, 0.f, 0.f, 0.f);
        float4 u1 = make_float4(0.f, 0.f, 0.f, 0.f);
        const _Float16* bp = Ag16 + (size_t)(brow + row) * lda + k0 + ci * 8;
#pragma unroll
        for (int p = 0; p < APART; ++p) {
          half8 hv = *(const half8*)(bp + (size_t)p * a_plane);
          u0.x += (float)hv[0]; u0.y += (float)hv[1]; u0.z += (float)hv[2]; u0.w += (float)hv[3];
          u1.x += (float)hv[4]; u1.y += (float)hv[5]; u1.z += (float)hv[6]; u1.w += (float)hv[7];
        }
        ra[i][0] = u0; ra[i][1] = u1;
      } else {
        const float* bp = Ag + (size_t)(brow + row) * lda + k0 + ci * 8;
        float4 u0 = ((const float4*)bp)[0];
        float4 u1 = ((const float4*)bp)[1];
#pragma unroll
        for (int p = 1; p < APART; ++p) {
          const float* pp = bp + (size_t)p * a_plane;
          float4 w0 = ((const float4*)pp)[0], w1 = ((const float4*)pp)[1];
          u0.x += w0.x; u0.y += w0.y; u0.z += w0.z; u0.w += w0.w;
          u1.x += w1.x; u1.y += w1.y; u1.z += w1.z; u1.w += w1.w;
        }
        ra[i][0] = u0; ra[i][1] = u1;
      }
    }
#pragma unroll
    for (int i = 0; i < NCB; ++i) {
      int c = tid + THREADS * i;
      int row = c >> 2, ci = c & 3;
      if constexpr (BMODE == 2) {
        const _Float16* bp = Bg16 + (size_t)(bcol + row) * ldb + k0 + ci * 8;
        rbh[i][0] = *(const half8*)bp;
        rbh[i][1] = *(const half8*)(bp + b_plane);
      } else if constexpr (BMODE == 3) {
        rbh[i][0] = *(const half8*)(Bg16 + (size_t)(bcol + row) * ldb + k0 + ci * 8);
      } else {
        const float4* p = (const float4*)(Bg + (size_t)(bcol + row) * ldb + k0 + ci * 8);
        rb[i][0] = p[0]; rb[i][1] = p[1];
      }
    }
  };

  auto stageLDS = [&](int b) {
#pragma unroll
    for (int i = 0; i < NCA; ++i) {
      int c = tid + THREADS * i;
      int row = c >> 2, ci = c & 3;
      int off = row * BK + ((ci ^ ((row >> 1) & 3)) << 3);
      if constexpr (AMODE == 2) {
        *(half8*)(&ldsA[b][0][0][0] + off) = rah[i][0];
        *(half8*)(&ldsA[b][1][0][0] + off) = rah[i][1];
      } else {
        float f[8] = {ra[i][0].x, ra[i][0].y, ra[i][0].z, ra[i][0].w,
                      ra[i][1].x, ra[i][1].y, ra[i][1].z, ra[i][1].w};
        half8 h, l;
#pragma unroll
        for (int j = 0; j < 8; ++j) {
          _Float16 hv = (_Float16)f[j];
          h[j] = hv;
          if (ASPL == 2) l[j] = (_Float16)(f[j] - (float)hv);
        }
        *(half8*)(&ldsA[b][0][0][0] + off) = h;
        if (ASPL == 2) *(half8*)(&ldsA[b][1][0][0] + off) = l;
      }
    }
#pragma unroll
    for (int i = 0; i < NCB; ++i) {
      int c = tid + THREADS * i;
      int row = c >> 2, ci = c & 3;
      int off = row * BK + ((ci ^ ((row >> 1) & 3)) << 3);
      if constexpr (BMODE == 2) {
        *(half8*)(&ldsB[b][0][0][0] + off) = rbh[i][0];
        *(half8*)(&ldsB[b][1][0][0] + off) = rbh[i][1];
      } else if constexpr (BMODE == 3) {
        *(half8*)(&ldsB[b][0][0][0] + off) = rbh[i][0];
      } else {
        float f[8] = {rb[i][0].x, rb[i][0].y, rb[i][0].z, rb[i][0].w,
                      rb[i][1].x, rb[i][1].y, rb[i][1].z, rb[i][1].w};
        half8 h, l;
#pragma unroll
        for (int j = 0; j < 8; ++j) {
          _Float16 hv = (_Float16)f[j];
          h[j] = hv;
          if (BSPL == 2) l[j] = (_Float16)(f[j] - (float)hv);
        }
        *(half8*)(&ldsB[b][0][0][0] + off) = h;
        if (BSPL == 2) *(half8*)(&ldsB[b][1][0][0] + off) = l;
      }
    }
  };

  const int nk = K / BK;
  loadAB(0);
  stageLDS(0);
  if (nk > 1) loadAB(1);
  __syncthreads();

  for (int kt = 0; kt < nk; ++kt) {
    const int cur = kt & 1, nxt = cur ^ 1;
    if (kt + 1 < nk) stageLDS(nxt);
    if (kt + 2 < nk) loadAB(kt + 2);

    half8 af[FM][ASPL];
#pragma unroll
    for (int mi = 0; mi < FM; ++mi)
#pragma unroll
      for (int sa = 0; sa < ASPL; ++sa) {
        int row = wrow * WM + mi * 16 + l15;
        af[mi][sa] = *(const half8*)(&ldsA[cur][sa][0][0] + row * BK + ((g ^ ((row >> 1) & 3)) << 3));
      }
#pragma unroll
    for (int ni = 0; ni < FN; ++ni) {
      half8 bf[BSPL];
#pragma unroll
      for (int sb = 0; sb < BSPL; ++sb) {
        int row = wcol * WN + ni * 16 + l15;
        bf[sb] = *(const half8*)(&ldsB[cur][sb][0][0] + row * BK + ((g ^ ((row >> 1) & 3)) << 3));
      }
#pragma unroll
      for (int mi = 0; mi < FM; ++mi)
#pragma unroll
        for (int sa = 0; sa < ASPL; ++sa)
#pragma unroll
          for (int sb = 0; sb < BSPL; ++sb) {
            if (ASPL == 2 && BSPL == 2 && sa == 1 && sb == 1) continue;
            acc[mi][ni] = __builtin_amdgcn_mfma_f32_16x16x32_f16(af[mi][sa], bf[sb], acc[mi][ni], 0, 0, 0);
          }
    }
    __syncthreads();
  }

#pragma unroll
  for (int mi = 0; mi < FM; ++mi)
#pragma unroll
    for (int ni = 0; ni < FN; ++ni) {
      int col = bcol + wcol * WN + ni * 16 + l15;
      float bv = bias ? bias[col] : 0.f;
#pragma unroll
      for (int j = 0; j < 4; ++j) {
        int r = brow + wrow * WM + mi * 16 + g * 4 + j;
        float v = acc[mi][ni][j] * scale + bv;
        Cg[(size_t)r * ldc + col] = v;
        if constexpr (QF16) {
          if (col < 512) q16out[(size_t)r * 512 + col] = (_Float16)v;
        }
      }
    }
}

// ---------------------------------------------------------------- GEMM f16 x f16 (K3)
template<int BM,int BN,int THREADS,bool STATS,int MINW>
__global__ __launch_bounds__(THREADS, MINW) void gemm_ff16(
    const _Float16* __restrict__ Ag, int lda,
    const _Float16* __restrict__ Bg, int ldb,
    float* __restrict__ Cg, int ldc,
    int K, float scale,
    float* __restrict__ mxout, float* __restrict__ smout, int ntiles)
{
  constexpr int BK = 32;
  constexpr int WAVES_M = 2, WAVES_N = 2;
  constexpr int WM = BM / WAVES_M, WN = BN / WAVES_N;
  constexpr int FM = WM / 16, FN = WN / 16;
  constexpr int NCA = (BM * 4) / THREADS;
  constexpr int NCB = (BN * 4) / THREADS;

  __shared__ _Float16 ldsA[2][BM][BK];
  __shared__ _Float16 ldsB[2][BN][BK];

  const int tid  = threadIdx.x;
  const int lane = tid & 63;
  const int wid  = tid >> 6;
  const int wrow = wid >> 1, wcol = wid & 1;
  const int l15  = lane & 15, g = lane >> 4;
  const int brow = blockIdx.y * BM;
  const int bcol = blockIdx.x * BN;

  f32x4 acc[FM][FN];
#pragma unroll
  for (int mi = 0; mi < FM; ++mi)
#pragma unroll
    for (int ni = 0; ni < FN; ++ni)
      acc[mi][ni] = (f32x4){0.f, 0.f, 0.f, 0.f};

  half8 ra[NCA], rb[NCB];

  auto loadAB = [&](int kt) {
    const int k0 = kt * BK;
#pragma unroll
    for (int i = 0; i < NCA; ++i) {
      int c = tid + THREADS * i;
      int row = c >> 2, ci = c & 3;
      ra[i] = *(const half8*)(Ag + (size_t)(brow + row) * lda + k0 + ci * 8);
    }
#pragma unroll
    for (int i = 0; i < NCB; ++i) {
      int c = tid + THREADS * i;
      int row = c >> 2, ci = c & 3;
      rb[i] = *(const half8*)(Bg + (size_t)(bcol + row) * ldb + k0 + ci * 8);
    }
  };

  auto stageLDS = [&](int b) {
#pragma unroll
    for (int i = 0; i < NCA; ++i) {
      int c = tid + THREADS * i;
      int row = c >> 2, ci = c & 3;
      int off = row * BK + ((ci ^ ((row >> 1) & 3)) << 3);
      *(half8*)(&ldsA[b][0][0] + off) = ra[i];
    }
#pragma unroll
    for (int i = 0; i < NCB; ++i) {
      int c = tid + THREADS * i;
      int row = c >> 2, ci = c & 3;
      int off = row * BK + ((ci ^ ((row >> 1) & 3)) << 3);
      *(half8*)(&ldsB[b][0][0] + off) = rb[i];
    }
  };

  const int nk = K / BK;
  loadAB(0);
  stageLDS(0);
  if (nk > 1) loadAB(1);
  __syncthreads();

  for (int kt = 0; kt < nk; ++kt) {
    const int cur = kt & 1, nxt = cur ^ 1;
    if (kt + 1 < nk) stageLDS(nxt);
    if (kt + 2 < nk) loadAB(kt + 2);

    half8 af[FM];
#pragma unroll
    for (int mi = 0; mi < FM; ++mi) {
      int row = wrow * WM + mi * 16 + l15;
      af[mi] = *(const half8*)(&ldsA[cur][0][0] + row * BK + ((g ^ ((row >> 1) & 3)) << 3));
    }
#pragma unroll
    for (int ni = 0; ni < FN; ++ni) {
      int row = wcol * WN + ni * 16 + l15;
      half8 bf = *(const half8*)(&ldsB[cur][0][0] + row * BK + ((g ^ ((row >> 1) & 3)) << 3));
#pragma unroll
      for (int mi = 0; mi < FM; ++mi)
        acc[mi][ni] = __builtin_amdgcn_mfma_f32_16x16x32_f16(af[mi], bf, acc[mi][ni], 0, 0, 0);
    }
    __syncthreads();
  }

#pragma unroll
  for (int mi = 0; mi < FM; ++mi)
#pragma unroll
    for (int ni = 0; ni < FN; ++ni) {
      int col = bcol + wcol * WN + ni * 16 + l15;
#pragma unroll
      for (int j = 0; j < 4; ++j) {
        int r = brow + wrow * WM + mi * 16 + g * 4 + j;
        Cg[(size_t)r * ldc + col] = acc[mi][ni][j] * scale;
      }
    }

  if constexpr (STATS) {
    __shared__ float s_m2[BM][2];
    __shared__ float s_s2[BM][2];
#pragma unroll
    for (int mi = 0; mi < FM; ++mi)
#pragma unroll
      for (int j = 0; j < 4; ++j) {
        float v = -3.4e38f;
#pragma unroll
        for (int ni = 0; ni < FN; ++ni) v = fmaxf(v, acc[mi][ni][j] * scale);
        v = fmaxf(v, __shfl_xor(v, 1)); v = fmaxf(v, __shfl_xor(v, 2));
        v = fmaxf(v, __shfl_xor(v, 4)); v = fmaxf(v, __shfl_xor(v, 8));
        if (l15 == 0) s_m2[wrow * WM + mi * 16 + g * 4 + j][wcol] = v;
      }
    __syncthreads();
#pragma unroll
    for (int mi = 0; mi < FM; ++mi)
#pragma unroll
      for (int j = 0; j < 4; ++j) {
        int r = wrow * WM + mi * 16 + g * 4 + j;
        float mt = fmaxf(s_m2[r][0], s_m2[r][1]);
        float s = 0.f;
#pragma unroll
        for (int ni = 0; ni < FN; ++ni) s += __expf(acc[mi][ni][j] * scale - mt);
        s += __shfl_xor(s, 1); s += __shfl_xor(s, 2);
        s += __shfl_xor(s, 4); s += __shfl_xor(s, 8);
        if (l15 == 0) s_s2[r][wcol] = s;
      }
    __syncthreads();
    if (tid < BM) {
      float mt = fmaxf(s_m2[tid][0], s_m2[tid][1]);
      float st = s_s2[tid][0] + s_s2[tid][1];
      mxout[(size_t)(brow + tid) * ntiles + blockIdx.x] = mt;
      smout[(size_t)(brow + tid) * ntiles + blockIdx.x] = st;
    }
  }
}

// ---------------------------------------------------------------- reduce 4 planes -> f16
__global__ __launch_bounds__(256) void reduce4_f16(
    const float4* __restrict__ in, _Float16* __restrict__ out16, size_t plane4,
    const float4* __restrict__ csum4)
{
  size_t i = (size_t)blockIdx.x * 256 + threadIdx.x;
  float4 a = in[i], b = in[plane4 + i], c = in[2 * plane4 + i], d = in[3 * plane4 + i];
  float4 s = csum4[i & 127];
  half4 h;
  h[0] = (_Float16)(a.x + b.x + c.x + d.x - s.x);
  h[1] = (_Float16)(a.y + b.y + c.y + d.y - s.y);
  h[2] = (_Float16)(a.z + b.z + c.z + d.z - s.z);
  h[3] = (_Float16)(a.w + b.w + c.w + d.w - s.w);
  *(half4*)(out16 + i * 4) = h;
}

// ---------------------------------------------------------------- stats combine
__global__ __launch_bounds__(256) void softmax_combine(
    const float* __restrict__ mx, const float* __restrict__ sm,
    float* __restrict__ rowm, float* __restrict__ rowinv)
{
  const int row = blockIdx.x * 4 + (threadIdx.x >> 6);
  const int lane = threadIdx.x & 63;
  float mt = mx[(size_t)row * 64 + lane];
  float m = mt;
#pragma unroll
  for (int off = 32; off; off >>= 1) m = fmaxf(m, __shfl_xor(m, off));
  float s = sm[(size_t)row * 64 + lane] * __expf(mt - m);
#pragma unroll
  for (int off = 32; off; off >>= 1) s += __shfl_xor(s, off);
  if (lane == 0) { rowm[row] = m; rowinv[row] = 1.0f / s; }
}

// ---------------------------------------------------------------- fused attn-write + PV
// Round-10 verified (199us): 1 barrier/step, dbuf LDS, setprio, f16 partials.
__global__ __launch_bounds__(512, 4) void pv_fused(
    float* __restrict__ attn,            // [8192][8192] logits in, attention out
    const _Float16* __restrict__ vT16,   // [512][8192] f16
    const float* __restrict__ rowm, const float* __restrict__ rowinv,
    _Float16* __restrict__ vals16)       // [4][8192][512] f16
{
  constexpr int BM = 64, BN = 512, BK = 32, NSTEP = 64;  // KC = 2048
  __shared__ _Float16 ldsA[2][BM][BK];   // 8 KB
  __shared__ _Float16 ldsB[2][BN][BK];   // 64 KB
  __shared__ float s_m[BM], s_inv[BM];

  const int tid = threadIdx.x, lane = tid & 63, wid = tid >> 6;
  const int wrow = wid >> 2, wcol = wid & 3;   // 2 x 4 waves
  const int l15 = lane & 15, g = lane >> 4;
  const int kc = blockIdx.x, brow = blockIdx.y * BM;
  const size_t kbase = (size_t)kc * 2048;

  if (tid < BM) { s_m[tid] = rowm[brow + tid]; s_inv[tid] = rowinv[brow + tid]; }

  f32x4 acc[2][8];
#pragma unroll
  for (int mi = 0; mi < 2; ++mi)
#pragma unroll
    for (int ni = 0; ni < 8; ++ni) acc[mi][ni] = (f32x4){0.f, 0.f, 0.f, 0.f};

  const int arow = (tid & 255) >> 2, aci = tid & 3;
  float4 ra[2];
  half8 rbh[4];

  auto loadA = [&](int kt) {
    if (tid < 256) {
      const float4* p = (const float4*)(attn + (size_t)(brow + arow) * 8192 + kbase + kt * BK + aci * 8);
      ra[0] = p[0]; ra[1] = p[1];
    }
  };
  auto loadB = [&](int kt) {
#pragma unroll
    for (int i = 0; i < 4; ++i) {
      int c = tid + 512 * i; int r = c >> 2, ci = c & 3;
      rbh[i] = *(const half8*)(vT16 + (size_t)r * 8192 + kbase + kt * BK + ci * 8);
    }
  };
  auto stage = [&](int kt, int b) {
    if (tid < 256) {
      const float m = s_m[arow], inv = s_inv[arow];
      float f[8] = {ra[0].x, ra[0].y, ra[0].z, ra[0].w, ra[1].x, ra[1].y, ra[1].z, ra[1].w};
      float e[8]; half8 h;
#pragma unroll
      for (int j = 0; j < 8; ++j) {
        e[j] = __expf(f[j] - m) * inv;
        h[j] = (_Float16)e[j];
      }
      float4* w = (float4*)(attn + (size_t)(brow + arow) * 8192 + kbase + kt * BK + aci * 8);
      w[0] = make_float4(e[0], e[1], e[2], e[3]);
      w[1] = make_float4(e[4], e[5], e[6], e[7]);
      int off = arow * BK + ((aci ^ ((arow >> 1) & 3)) << 3);
      *(half8*)(&ldsA[b][0][0] + off) = h;
    }
#pragma unroll
    for (int i = 0; i < 4; ++i) {
      int c = tid + 512 * i; int r = c >> 2, ci = c & 3;
      int off2 = r * BK + ((ci ^ ((r >> 1) & 3)) << 3);
      *(half8*)(&ldsB[b][0][0] + off2) = rbh[i];
    }
  };

  loadA(0); loadB(0);
  __syncthreads();            // s_m / s_inv visible
  stage(0, 0);
  loadA(1); loadB(1);
  __syncthreads();            // buf0 staged

  for (int kt = 0; kt < NSTEP; ++kt) {
    const int cur = kt & 1, nxt = cur ^ 1;
    if (kt + 1 < NSTEP) stage(kt + 1, nxt);
    if (kt + 2 < NSTEP) { loadA(kt + 2); loadB(kt + 2); }
    half8 af[2];
#pragma unroll
    for (int mi = 0; mi < 2; ++mi) {
      int row = wrow * 32 + mi * 16 + l15;
      af[mi] = *(const half8*)(&ldsA[cur][0][0] + row * BK + ((g ^ ((row >> 1) & 3)) << 3));
    }
    __builtin_amdgcn_s_setprio(1);
#pragma unroll
    for (int ni = 0; ni < 8; ++ni) {
      int rn = wcol * 128 + ni * 16 + l15;
      half8 bf = *(const half8*)(&ldsB[cur][0][0] + rn * BK + ((g ^ ((rn >> 1) & 3)) << 3));
#pragma unroll
      for (int mi = 0; mi < 2; ++mi)
        acc[mi][ni] = __builtin_amdgcn_mfma_f32_16x16x32_f16(af[mi], bf, acc[mi][ni], 0, 0, 0);
    }
    __builtin_amdgcn_s_setprio(0);
    __syncthreads();
  }

  const size_t plane = (size_t)8192 * 512;
#pragma unroll
  for (int mi = 0; mi < 2; ++mi)
#pragma unroll
    for (int ni = 0; ni < 8; ++ni) {
      int col = wcol * 128 + ni * 16 + l15;
#pragma unroll
      for (int j = 0; j < 4; ++j) {
        int row = brow + wrow * 32 + mi * 16 + g * 4 + j;
        vals16[(size_t)kc * plane + (size_t)row * 512 + col] = (_Float16)acc[mi][ni][j];
      }
    }
}

// ---------------------------------------------------------------- launch
extern "C" void kernel_launch(void* const* d_in, const int* in_sizes, int n_in,
                              void* d_out, int out_size, void* d_ws, size_t ws_size,
                              hipStream_t stream)
{
  const float* x    = (const float*)d_in[0];
  const float* Amat = (const float*)d_in[1];
  const float* Wqkv = (const float*)d_in[2];
  const float* bqkv = (const float*)d_in[3];
  const float* Wo   = (const float*)d_in[4];
  const float* bo   = (const float*)d_in[5];

  float* o    = (float*)d_out;                       // [8192,512]
  float* attn = (float*)d_out + (size_t)8192 * 512;  // [8192,8192]

  float* ws = (float*)d_ws;
  _Float16*  vals16 = (_Float16*)ws;              // 16.7M f16 (4 planes)
  float*     qkv    = ws;                         // 12.58M f32 (dead after transposes)
  _Float16*  k0T16  = (_Float16*)(ws + 12582912); // [512][8192] f16 (single plane)
  _Float16*  vT16   = (_Float16*)(ws + 16777216); // [512][8192] f16
  _Float16*  Whi    = (_Float16*)(ws + 18874368); // pair planes [1536][512] f16 (hi, lo)
  float*     WoT    = ws + 19660800;              // [512][512] f32
  _Float16*  kbuf16 = (_Float16*)(ws + 19922944); // [8192][512] f16
  float*     mx     = ws + 24117248;
  float*     sm     = ws + 24641536;
  float*     rowm   = ws + 25165824;
  float*     rowinv = ws + 25174016;
  float*     csum   = ws + 25182208;
  _Float16*  q16    = (_Float16*)(ws + 25183232); // [8192][512] f16
  float*     kpart  = attn;                       // d_out attn region pre-K3
  _Float16*  xhi    = (_Float16*)attn;            // x pair planes (dead before kpart use)

  const dim3 b256(256), b512(512);
  const float qk_scale = 0.04419417382415922f;  // 1/sqrt(512)
  const size_t plane = (size_t)8192 * 512;      // 4,194,304

  // pre-split x into f16 hi/lo pair (lives in d_out attn region until K2)
  split_f32_f16pair<<<dim3(4096), b256, 0, stream>>>((const float4*)x, xhi, plane);
  // weight transposes: Wqkv -> f16 pair, Wo -> f32
  transpose_f32_f16pair<<<dim3(48, 16), b256, 0, stream>>>(Wqkv, 1536, Whi, 512, 786432);
  transpose_f32<<<dim3(16, 16), b256, 0, stream>>>(Wo, 512, WoT, 512);

  // K1: qkv = x @ Wqkv + bqkv (3-pass, pair-staged both sides) + f16 q copy
  gemm_bt<2, 2, 128, 128, 2, 2, 256, 1, false, true, 2, 2, 2>
      <<<dim3(12, 64), b256, 0, stream>>>(
      xhi, 512, plane, Whi, 512, 786432, qkv, 1536, 0, bqkv, 512, 1.0f, q16);

  // k0 -> f16 single plane (transposed), v -> f16 (transposed)
  transpose_f32_f16<<<dim3(16, 256), b256, 0, stream>>>(qkv + 512, 1536, k0T16, 8192);
  transpose_f32_f16<<<dim3(16, 256), b256, 0, stream>>>(qkv + 1024, 1536, vT16, 8192);
  halfcolsum16<<<dim3(512), b256, 0, stream>>>(k0T16, csum);

  // K2: k = A @ k0 (single-pass: A f32->f16, B f16 pure copy), split-K 4 chunks
  gemm_bt<1, 1, 128, 256, 2, 4, 512, 1, true, false, 6, 0, 3>
      <<<dim3(2, 64, 4), b512, 0, stream>>>(
      Amat, 8192, 0, k0T16, 8192, 0, kpart, 512, plane, nullptr, 2048, 1.0f, nullptr);

  // kbuf16 = f16(sum of partials - 0.5*colsum(k0))
  reduce4_f16<<<dim3(4096), b256, 0, stream>>>((const float4*)kpart, kbuf16, plane / 4,
                                               (const float4*)csum);

  // K3: logits = (q16 @ kbuf16^T)*scale + per-tile softmax stats
  gemm_ff16<128, 128, 256, true, 4>
      <<<dim3(64, 64), b256, 0, stream>>>(
      q16, 512, kbuf16, 512, attn, 8192, 512, qk_scale, mx, sm, 64);

  softmax_combine<<<dim3(2048), b256, 0, stream>>>(mx, sm, rowm, rowinv);

  // K5': attention = exp(l-m)/s in place; vals partials f16
  pv_fused<<<dim3(4, 128), b512, 0, stream>>>(attn, vT16, rowm, rowinv, vals16);

  // K6: o = (sum of 4 f16 vals partials) @ Wo + bo
  gemm_bt<1, 1, 128, 128, 2, 2, 256, 4, false, false, 3, 1, 0>
      <<<dim3(4, 64), b256, 0, stream>>>(
      vals16, 512, plane, WoT, 512, 0, o, 512, 0, bo, 512, 1.0f, nullptr);
}

// Round 13
// 603.814 us; speedup vs baseline: 2.0583x; 2.0583x over previous
//
#include <hip/hip_runtime.h>

typedef _Float16 half8 __attribute__((ext_vector_type(8)));
typedef _Float16 half4 __attribute__((ext_vector_type(4)));
typedef float f32x4 __attribute__((ext_vector_type(4)));

// ---------------------------------------------------------------- transpose (f32)
__global__ __launch_bounds__(256) void transpose_f32(
    const float* __restrict__ in, int lda,
    float* __restrict__ out, int ldo)
{
  __shared__ float t[32][33];
  const int tx = threadIdx.x & 31, ty = threadIdx.x >> 5;
  const int bc = blockIdx.x * 32, br = blockIdx.y * 32;
#pragma unroll
  for (int i = 0; i < 4; ++i)
    t[ty + 8 * i][tx] = in[(size_t)(br + ty + 8 * i) * lda + bc + tx];
  __syncthreads();
#pragma unroll
  for (int i = 0; i < 4; ++i)
    out[(size_t)(bc + ty + 8 * i) * ldo + br + tx] = t[tx][ty + 8 * i];
}

// transpose with f32 -> f16 convert on output
__global__ __launch_bounds__(256) void transpose_f32_f16(
    const float* __restrict__ in, int lda,
    _Float16* __restrict__ out, int ldo)
{
  __shared__ float t[32][33];
  const int tx = threadIdx.x & 31, ty = threadIdx.x >> 5;
  const int bc = blockIdx.x * 32, br = blockIdx.y * 32;
#pragma unroll
  for (int i = 0; i < 4; ++i)
    t[ty + 8 * i][tx] = in[(size_t)(br + ty + 8 * i) * lda + bc + tx];
  __syncthreads();
#pragma unroll
  for (int i = 0; i < 4; ++i)
    out[(size_t)(bc + ty + 8 * i) * ldo + br + tx] = (_Float16)t[tx][ty + 8 * i];
}

// transpose with f32 -> f16 hi/lo SPLIT pair on output (lo plane at +plane)
__global__ __launch_bounds__(256) void transpose_f32_f16pair(
    const float* __restrict__ in, int lda,
    _Float16* __restrict__ outhi, int ldo, size_t plane)
{
  __shared__ float t[32][33];
  const int tx = threadIdx.x & 31, ty = threadIdx.x >> 5;
  const int bc = blockIdx.x * 32, br = blockIdx.y * 32;
#pragma unroll
  for (int i = 0; i < 4; ++i)
    t[ty + 8 * i][tx] = in[(size_t)(br + ty + 8 * i) * lda + bc + tx];
  __syncthreads();
#pragma unroll
  for (int i = 0; i < 4; ++i) {
    float v = t[tx][ty + 8 * i];
    _Float16 h = (_Float16)v;
    size_t idx = (size_t)(bc + ty + 8 * i) * ldo + br + tx;
    outhi[idx] = h;
    outhi[plane + idx] = (_Float16)(v - (float)h);
  }
}

// elementwise f32 -> f16 hi/lo split
__global__ __launch_bounds__(256) void split_f32_f16pair(
    const float4* __restrict__ in, _Float16* __restrict__ hi, size_t plane)
{
  size_t i = (size_t)blockIdx.x * 256 + threadIdx.x;
  float4 v = in[i];
  half4 h, l;
  h[0] = (_Float16)v.x; l[0] = (_Float16)(v.x - (float)h[0]);
  h[1] = (_Float16)v.y; l[1] = (_Float16)(v.y - (float)h[1]);
  h[2] = (_Float16)v.z; l[2] = (_Float16)(v.z - (float)h[2]);
  h[3] = (_Float16)v.w; l[3] = (_Float16)(v.w - (float)h[3]);
  ((half4*)hi)[i] = h;
  ((half4*)(hi + plane))[i] = l;
}

// ---------------------------------------------------------------- half column-sum (f16 input)
__global__ __launch_bounds__(256) void halfcolsum16(
    const _Float16* __restrict__ k0T16, float* __restrict__ csum)
{
  const int d = blockIdx.x, tid = threadIdx.x;
  float s = 0.f;
#pragma unroll
  for (int i = 0; i < 4; ++i) {
    half8 h = *(const half8*)(k0T16 + (size_t)d * 8192 + i * 2048 + tid * 8);
#pragma unroll
    for (int j = 0; j < 8; ++j) s += (float)h[j];
  }
#pragma unroll
  for (int off = 32; off; off >>= 1) s += __shfl_xor(s, off);
  __shared__ float r[4];
  if ((tid & 63) == 0) r[tid >> 6] = s;
  __syncthreads();
  if (tid == 0) csum[d] = 0.5f * ((r[0] + r[1]) + (r[2] + r[3]));
}

// ---------------------------------------------------------------- GEMM (BT)
// AMODE: 0 = f32 A, 1 = f16 A (APART planes summed), 2 = f16 hi/lo pair A
// BMODE: 0 = f32 B, 2 = f16 hi/lo pair B, 3 = f16 single plane B (pure copy)
template<int ASPL,int BSPL,int BM,int BN,int WAVES_M,int WAVES_N,int THREADS,
         int APART,bool KSPLIT,bool QF16,int MINW,int AMODE,int BMODE>
__global__ __launch_bounds__(THREADS, MINW) void gemm_bt(
    const void* __restrict__ Agv, int lda, size_t a_plane,
    const void* __restrict__ Bgv, int ldb, size_t b_plane,
    float* __restrict__ Cg, int ldc, size_t c_plane,
    const float* __restrict__ bias, int K, float scale,
    _Float16* __restrict__ q16out)
{
  constexpr int BK = 32;
  constexpr int WM = BM / WAVES_M, WN = BN / WAVES_N;
  constexpr int FM = WM / 16, FN = WN / 16;
  constexpr int NCA = (BM * 4) / THREADS;
  constexpr int NCB = (BN * 4) / THREADS;
  static_assert((BM * 4) % THREADS == 0 && (BN * 4) % THREADS == 0, "mismatch");

  __shared__ _Float16 ldsA[2][ASPL][BM][BK];
  __shared__ _Float16 ldsB[2][BSPL][BN][BK];

  const float*    Ag   = (const float*)Agv;
  const _Float16* Ag16 = (const _Float16*)Agv;
  const float*    Bg   = (const float*)Bgv;
  const _Float16* Bg16 = (const _Float16*)Bgv;

  const int tid  = threadIdx.x;
  const int lane = tid & 63;
  const int wid  = tid >> 6;
  const int wrow = wid / WAVES_N, wcol = wid % WAVES_N;
  const int l15  = lane & 15, g = lane >> 4;
  const int brow = blockIdx.y * BM;
  const int bcol = blockIdx.x * BN;

  if constexpr (KSPLIT) {
    const int kc = blockIdx.z;
    Ag += (size_t)kc * K;  Ag16 += (size_t)kc * K;
    Bg += (size_t)kc * K;  Bg16 += (size_t)kc * K;
    Cg += (size_t)kc * c_plane;
  }

  f32x4 acc[FM][FN];
#pragma unroll
  for (int mi = 0; mi < FM; ++mi)
#pragma unroll
    for (int ni = 0; ni < FN; ++ni)
      acc[mi][ni] = (f32x4){0.f, 0.f, 0.f, 0.f};

  float4 ra[NCA][2], rb[NCB][2];
  half8  rah[NCA][2], rbh[NCB][2];

  auto loadAB = [&](int kt) {
    const int k0 = kt * BK;
#pragma unroll
    for (int i = 0; i < NCA; ++i) {
      int c = tid + THREADS * i;
      int row = c >> 2, ci = c & 3;
      if constexpr (AMODE == 2) {
        const _Float16* bp = Ag16 + (size_t)(brow + row) * lda + k0 + ci * 8;
        rah[i][0] = *(const half8*)bp;
        rah[i][1] = *(const half8*)(bp + a_plane);
      } else if constexpr (AMODE == 1) {
        float4 u0 = make_float4(0.f, 0.f, 0.f, 0.f);
        float4 u1 = make_float4(0.f, 0.f, 0.f, 0.f);
        const _Float16* bp = Ag16 + (size_t)(brow + row) * lda + k0 + ci * 8;
#pragma unroll
        for (int p = 0; p < APART; ++p) {
          half8 hv = *(const half8*)(bp + (size_t)p * a_plane);
          u0.x += (float)hv[0]; u0.y += (float)hv[1]; u0.z += (float)hv[2]; u0.w += (float)hv[3];
          u1.x += (float)hv[4]; u1.y += (float)hv[5]; u1.z += (float)hv[6]; u1.w += (float)hv[7];
        }
        ra[i][0] = u0; ra[i][1] = u1;
      } else {
        const float* bp = Ag + (size_t)(brow + row) * lda + k0 + ci * 8;
        float4 u0 = ((const float4*)bp)[0];
        float4 u1 = ((const float4*)bp)[1];
#pragma unroll
        for (int p = 1; p < APART; ++p) {
          const float* pp = bp + (size_t)p * a_plane;
          float4 w0 = ((const float4*)pp)[0], w1 = ((const float4*)pp)[1];
          u0.x += w0.x; u0.y += w0.y; u0.z += w0.z; u0.w += w0.w;
          u1.x += w1.x; u1.y += w1.y; u1.z += w1.z; u1.w += w1.w;
        }
        ra[i][0] = u0; ra[i][1] = u1;
      }
    }
#pragma unroll
    for (int i = 0; i < NCB; ++i) {
      int c = tid + THREADS * i;
      int row = c >> 2, ci = c & 3;
      if constexpr (BMODE == 2) {
        const _Float16* bp = Bg16 + (size_t)(bcol + row) * ldb + k0 + ci * 8;
        rbh[i][0] = *(const half8*)bp;
        rbh[i][1] = *(const half8*)(bp + b_plane);
      } else if constexpr (BMODE == 3) {
        rbh[i][0] = *(const half8*)(Bg16 + (size_t)(bcol + row) * ldb + k0 + ci * 8);
      } else {
        const float4* p = (const float4*)(Bg + (size_t)(bcol + row) * ldb + k0 + ci * 8);
        rb[i][0] = p[0]; rb[i][1] = p[1];
      }
    }
  };

  auto stageLDS = [&](int b) {
#pragma unroll
    for (int i = 0; i < NCA; ++i) {
      int c = tid + THREADS * i;
      int row = c >> 2, ci = c & 3;
      int off = row * BK + ((ci ^ ((row >> 1) & 3)) << 3);
      if constexpr (AMODE == 2) {
        *(half8*)(&ldsA[b][0][0][0] + off) = rah[i][0];
        *(half8*)(&ldsA[b][1][0][0] + off) = rah[i][1];
      } else {
        float f[8] = {ra[i][0].x, ra[i][0].y, ra[i][0].z, ra[i][0].w,
                      ra[i][1].x, ra[i][1].y, ra[i][1].z, ra[i][1].w};
        half8 h, l;
#pragma unroll
        for (int j = 0; j < 8; ++j) {
          _Float16 hv = (_Float16)f[j];
          h[j] = hv;
          if (ASPL == 2) l[j] = (_Float16)(f[j] - (float)hv);
        }
        *(half8*)(&ldsA[b][0][0][0] + off) = h;
        if (ASPL == 2) *(half8*)(&ldsA[b][1][0][0] + off) = l;
      }
    }
#pragma unroll
    for (int i = 0; i < NCB; ++i) {
      int c = tid + THREADS * i;
      int row = c >> 2, ci = c & 3;
      int off = row * BK + ((ci ^ ((row >> 1) & 3)) << 3);
      if constexpr (BMODE == 2) {
        *(half8*)(&ldsB[b][0][0][0] + off) = rbh[i][0];
        *(half8*)(&ldsB[b][1][0][0] + off) = rbh[i][1];
      } else if constexpr (BMODE == 3) {
        *(half8*)(&ldsB[b][0][0][0] + off) = rbh[i][0];
      } else {
        float f[8] = {rb[i][0].x, rb[i][0].y, rb[i][0].z, rb[i][0].w,
                      rb[i][1].x, rb[i][1].y, rb[i][1].z, rb[i][1].w};
        half8 h, l;
#pragma unroll
        for (int j = 0; j < 8; ++j) {
          _Float16 hv = (_Float16)f[j];
          h[j] = hv;
          if (BSPL == 2) l[j] = (_Float16)(f[j] - (float)hv);
        }
        *(half8*)(&ldsB[b][0][0][0] + off) = h;
        if (BSPL == 2) *(half8*)(&ldsB[b][1][0][0] + off) = l;
      }
    }
  };

  const int nk = K / BK;
  loadAB(0);
  stageLDS(0);
  if (nk > 1) loadAB(1);
  __syncthreads();

  for (int kt = 0; kt < nk; ++kt) {
    const int cur = kt & 1, nxt = cur ^ 1;
    if (kt + 1 < nk) stageLDS(nxt);
    if (kt + 2 < nk) loadAB(kt + 2);

    half8 af[FM][ASPL];
#pragma unroll
    for (int mi = 0; mi < FM; ++mi)
#pragma unroll
      for (int sa = 0; sa < ASPL; ++sa) {
        int row = wrow * WM + mi * 16 + l15;
        af[mi][sa] = *(const half8*)(&ldsA[cur][sa][0][0] + row * BK + ((g ^ ((row >> 1) & 3)) << 3));
      }
#pragma unroll
    for (int ni = 0; ni < FN; ++ni) {
      half8 bf[BSPL];
#pragma unroll
      for (int sb = 0; sb < BSPL; ++sb) {
        int row = wcol * WN + ni * 16 + l15;
        bf[sb] = *(const half8*)(&ldsB[cur][sb][0][0] + row * BK + ((g ^ ((row >> 1) & 3)) << 3));
      }
#pragma unroll
      for (int mi = 0; mi < FM; ++mi)
#pragma unroll
        for (int sa = 0; sa < ASPL; ++sa)
#pragma unroll
          for (int sb = 0; sb < BSPL; ++sb) {
            if (ASPL == 2 && BSPL == 2 && sa == 1 && sb == 1) continue;
            acc[mi][ni] = __builtin_amdgcn_mfma_f32_16x16x32_f16(af[mi][sa], bf[sb], acc[mi][ni], 0, 0, 0);
          }
    }
    __syncthreads();
  }

#pragma unroll
  for (int mi = 0; mi < FM; ++mi)
#pragma unroll
    for (int ni = 0; ni < FN; ++ni) {
      int col = bcol + wcol * WN + ni * 16 + l15;
      float bv = bias ? bias[col] : 0.f;
#pragma unroll
      for (int j = 0; j < 4; ++j) {
        int r = brow + wrow * WM + mi * 16 + g * 4 + j;
        float v = acc[mi][ni][j] * scale + bv;
        Cg[(size_t)r * ldc + col] = v;
        if constexpr (QF16) {
          if (col < 512) q16out[(size_t)r * 512 + col] = (_Float16)v;
        }
      }
    }
}

// ---------------------------------------------------------------- GEMM f16 x f16 (K3)
template<int BM,int BN,int THREADS,bool STATS,int MINW>
__global__ __launch_bounds__(THREADS, MINW) void gemm_ff16(
    const _Float16* __restrict__ Ag, int lda,
    const _Float16* __restrict__ Bg, int ldb,
    float* __restrict__ Cg, int ldc,
    int K, float scale,
    float* __restrict__ mxout, float* __restrict__ smout, int ntiles)
{
  constexpr int BK = 32;
  constexpr int WAVES_M = 2, WAVES_N = 2;
  constexpr int WM = BM / WAVES_M, WN = BN / WAVES_N;
  constexpr int FM = WM / 16, FN = WN / 16;
  constexpr int NCA = (BM * 4) / THREADS;
  constexpr int NCB = (BN * 4) / THREADS;

  __shared__ _Float16 ldsA[2][BM][BK];
  __shared__ _Float16 ldsB[2][BN][BK];

  const int tid  = threadIdx.x;
  const int lane = tid & 63;
  const int wid  = tid >> 6;
  const int wrow = wid >> 1, wcol = wid & 1;
  const int l15  = lane & 15, g = lane >> 4;
  const int brow = blockIdx.y * BM;
  const int bcol = blockIdx.x * BN;

  f32x4 acc[FM][FN];
#pragma unroll
  for (int mi = 0; mi < FM; ++mi)
#pragma unroll
    for (int ni = 0; ni < FN; ++ni)
      acc[mi][ni] = (f32x4){0.f, 0.f, 0.f, 0.f};

  half8 ra[NCA], rb[NCB];

  auto loadAB = [&](int kt) {
    const int k0 = kt * BK;
#pragma unroll
    for (int i = 0; i < NCA; ++i) {
      int c = tid + THREADS * i;
      int row = c >> 2, ci = c & 3;
      ra[i] = *(const half8*)(Ag + (size_t)(brow + row) * lda + k0 + ci * 8);
    }
#pragma unroll
    for (int i = 0; i < NCB; ++i) {
      int c = tid + THREADS * i;
      int row = c >> 2, ci = c & 3;
      rb[i] = *(const half8*)(Bg + (size_t)(bcol + row) * ldb + k0 + ci * 8);
    }
  };

  auto stageLDS = [&](int b) {
#pragma unroll
    for (int i = 0; i < NCA; ++i) {
      int c = tid + THREADS * i;
      int row = c >> 2, ci = c & 3;
      int off = row * BK + ((ci ^ ((row >> 1) & 3)) << 3);
      *(half8*)(&ldsA[b][0][0] + off) = ra[i];
    }
#pragma unroll
    for (int i = 0; i < NCB; ++i) {
      int c = tid + THREADS * i;
      int row = c >> 2, ci = c & 3;
      int off = row * BK + ((ci ^ ((row >> 1) & 3)) << 3);
      *(half8*)(&ldsB[b][0][0] + off) = rb[i];
    }
  };

  const int nk = K / BK;
  loadAB(0);
  stageLDS(0);
  if (nk > 1) loadAB(1);
  __syncthreads();

  for (int kt = 0; kt < nk; ++kt) {
    const int cur = kt & 1, nxt = cur ^ 1;
    if (kt + 1 < nk) stageLDS(nxt);
    if (kt + 2 < nk) loadAB(kt + 2);

    half8 af[FM];
#pragma unroll
    for (int mi = 0; mi < FM; ++mi) {
      int row = wrow * WM + mi * 16 + l15;
      af[mi] = *(const half8*)(&ldsA[cur][0][0] + row * BK + ((g ^ ((row >> 1) & 3)) << 3));
    }
#pragma unroll
    for (int ni = 0; ni < FN; ++ni) {
      int row = wcol * WN + ni * 16 + l15;
      half8 bf = *(const half8*)(&ldsB[cur][0][0] + row * BK + ((g ^ ((row >> 1) & 3)) << 3));
#pragma unroll
      for (int mi = 0; mi < FM; ++mi)
        acc[mi][ni] = __builtin_amdgcn_mfma_f32_16x16x32_f16(af[mi], bf, acc[mi][ni], 0, 0, 0);
    }
    __syncthreads();
  }

#pragma unroll
  for (int mi = 0; mi < FM; ++mi)
#pragma unroll
    for (int ni = 0; ni < FN; ++ni) {
      int col = bcol + wcol * WN + ni * 16 + l15;
#pragma unroll
      for (int j = 0; j < 4; ++j) {
        int r = brow + wrow * WM + mi * 16 + g * 4 + j;
        Cg[(size_t)r * ldc + col] = acc[mi][ni][j] * scale;
      }
    }

  if constexpr (STATS) {
    __shared__ float s_m2[BM][2];
    __shared__ float s_s2[BM][2];
#pragma unroll
    for (int mi = 0; mi < FM; ++mi)
#pragma unroll
      for (int j = 0; j < 4; ++j) {
        float v = -3.4e38f;
#pragma unroll
        for (int ni = 0; ni < FN; ++ni) v = fmaxf(v, acc[mi][ni][j] * scale);
        v = fmaxf(v, __shfl_xor(v, 1)); v = fmaxf(v, __shfl_xor(v, 2));
        v = fmaxf(v, __shfl_xor(v, 4)); v = fmaxf(v, __shfl_xor(v, 8));
        if (l15 == 0) s_m2[wrow * WM + mi * 16 + g * 4 + j][wcol] = v;
      }
    __syncthreads();
#pragma unroll
    for (int mi = 0; mi < FM; ++mi)
#pragma unroll
      for (int j = 0; j < 4; ++j) {
        int r = wrow * WM + mi * 16 + g * 4 + j;
        float mt = fmaxf(s_m2[r][0], s_m2[r][1]);
        float s = 0.f;
#pragma unroll
        for (int ni = 0; ni < FN; ++ni) s += __expf(acc[mi][ni][j] * scale - mt);
        s += __shfl_xor(s, 1); s += __shfl_xor(s, 2);
        s += __shfl_xor(s, 4); s += __shfl_xor(s, 8);
        if (l15 == 0) s_s2[r][wcol] = s;
      }
    __syncthreads();
    if (tid < BM) {
      float mt = fmaxf(s_m2[tid][0], s_m2[tid][1]);
      float st = s_s2[tid][0] + s_s2[tid][1];
      mxout[(size_t)(brow + tid) * ntiles + blockIdx.x] = mt;
      smout[(size_t)(brow + tid) * ntiles + blockIdx.x] = st;
    }
  }
}

// ---------------------------------------------------------------- reduce 4 planes -> f16
__global__ __launch_bounds__(256) void reduce4_f16(
    const float4* __restrict__ in, _Float16* __restrict__ out16, size_t plane4,
    const float4* __restrict__ csum4)
{
  size_t i = (size_t)blockIdx.x * 256 + threadIdx.x;
  float4 a = in[i], b = in[plane4 + i], c = in[2 * plane4 + i], d = in[3 * plane4 + i];
  float4 s = csum4[i & 127];
  half4 h;
  h[0] = (_Float16)(a.x + b.x + c.x + d.x - s.x);
  h[1] = (_Float16)(a.y + b.y + c.y + d.y - s.y);
  h[2] = (_Float16)(a.z + b.z + c.z + d.z - s.z);
  h[3] = (_Float16)(a.w + b.w + c.w + d.w - s.w);
  *(half4*)(out16 + i * 4) = h;
}

// ---------------------------------------------------------------- stats combine
__global__ __launch_bounds__(256) void softmax_combine(
    const float* __restrict__ mx, const float* __restrict__ sm,
    float* __restrict__ rowm, float* __restrict__ rowinv)
{
  const int row = blockIdx.x * 4 + (threadIdx.x >> 6);
  const int lane = threadIdx.x & 63;
  float mt = mx[(size_t)row * 64 + lane];
  float m = mt;
#pragma unroll
  for (int off = 32; off; off >>= 1) m = fmaxf(m, __shfl_xor(m, off));
  float s = sm[(size_t)row * 64 + lane] * __expf(mt - m);
#pragma unroll
  for (int off = 32; off; off >>= 1) s += __shfl_xor(s, off);
  if (lane == 0) { rowm[row] = m; rowinv[row] = 1.0f / s; }
}

// ---------------------------------------------------------------- fused attn-write + PV
// Round-10 verified (199us): 1 barrier/step, dbuf LDS, setprio, f16 partials.
__global__ __launch_bounds__(512, 4) void pv_fused(
    float* __restrict__ attn,            // [8192][8192] logits in, attention out
    const _Float16* __restrict__ vT16,   // [512][8192] f16
    const float* __restrict__ rowm, const float* __restrict__ rowinv,
    _Float16* __restrict__ vals16)       // [4][8192][512] f16
{
  constexpr int BM = 64, BN = 512, BK = 32, NSTEP = 64;  // KC = 2048
  __shared__ _Float16 ldsA[2][BM][BK];   // 8 KB
  __shared__ _Float16 ldsB[2][BN][BK];   // 64 KB
  __shared__ float s_m[BM], s_inv[BM];

  const int tid = threadIdx.x, lane = tid & 63, wid = tid >> 6;
  const int wrow = wid >> 2, wcol = wid & 3;   // 2 x 4 waves
  const int l15 = lane & 15, g = lane >> 4;
  const int kc = blockIdx.x, brow = blockIdx.y * BM;
  const size_t kbase = (size_t)kc * 2048;

  if (tid < BM) { s_m[tid] = rowm[brow + tid]; s_inv[tid] = rowinv[brow + tid]; }

  f32x4 acc[2][8];
#pragma unroll
  for (int mi = 0; mi < 2; ++mi)
#pragma unroll
    for (int ni = 0; ni < 8; ++ni) acc[mi][ni] = (f32x4){0.f, 0.f, 0.f, 0.f};

  const int arow = (tid & 255) >> 2, aci = tid & 3;
  float4 ra[2];
  half8 rbh[4];

  auto loadA = [&](int kt) {
    if (tid < 256) {
      const float4* p = (const float4*)(attn + (size_t)(brow + arow) * 8192 + kbase + kt * BK + aci * 8);
      ra[0] = p[0]; ra[1] = p[1];
    }
  };
  auto loadB = [&](int kt) {
#pragma unroll
    for (int i = 0; i < 4; ++i) {
      int c = tid + 512 * i; int r = c >> 2, ci = c & 3;
      rbh[i] = *(const half8*)(vT16 + (size_t)r * 8192 + kbase + kt * BK + ci * 8);
    }
  };
  auto stage = [&](int kt, int b) {
    if (tid < 256) {
      const float m = s_m[arow], inv = s_inv[arow];
      float f[8] = {ra[0].x, ra[0].y, ra[0].z, ra[0].w, ra[1].x, ra[1].y, ra[1].z, ra[1].w};
      float e[8]; half8 h;
#pragma unroll
      for (int j = 0; j < 8; ++j) {
        e[j] = __expf(f[j] - m) * inv;
        h[j] = (_Float16)e[j];
      }
      float4* w = (float4*)(attn + (size_t)(brow + arow) * 8192 + kbase + kt * BK + aci * 8);
      w[0] = make_float4(e[0], e[1], e[2], e[3]);
      w[1] = make_float4(e[4], e[5], e[6], e[7]);
      int off = arow * BK + ((aci ^ ((arow >> 1) & 3)) << 3);
      *(half8*)(&ldsA[b][0][0] + off) = h;
    }
#pragma unroll
    for (int i = 0; i < 4; ++i) {
      int c = tid + 512 * i; int r = c >> 2, ci = c & 3;
      int off2 = r * BK + ((ci ^ ((r >> 1) & 3)) << 3);
      *(half8*)(&ldsB[b][0][0] + off2) = rbh[i];
    }
  };

  loadA(0); loadB(0);
  __syncthreads();            // s_m / s_inv visible
  stage(0, 0);
  loadA(1); loadB(1);
  __syncthreads();            // buf0 staged

  for (int kt = 0; kt < NSTEP; ++kt) {
    const int cur = kt & 1, nxt = cur ^ 1;
    if (kt + 1 < NSTEP) stage(kt + 1, nxt);
    if (kt + 2 < NSTEP) { loadA(kt + 2); loadB(kt + 2); }
    half8 af[2];
#pragma unroll
    for (int mi = 0; mi < 2; ++mi) {
      int row = wrow * 32 + mi * 16 + l15;
      af[mi] = *(const half8*)(&ldsA[cur][0][0] + row * BK + ((g ^ ((row >> 1) & 3)) << 3));
    }
    __builtin_amdgcn_s_setprio(1);
#pragma unroll
    for (int ni = 0; ni < 8; ++ni) {
      int rn = wcol * 128 + ni * 16 + l15;
      half8 bf = *(const half8*)(&ldsB[cur][0][0] + rn * BK + ((g ^ ((rn >> 1) & 3)) << 3));
#pragma unroll
      for (int mi = 0; mi < 2; ++mi)
        acc[mi][ni] = __builtin_amdgcn_mfma_f32_16x16x32_f16(af[mi], bf, acc[mi][ni], 0, 0, 0);
    }
    __builtin_amdgcn_s_setprio(0);
    __syncthreads();
  }

  const size_t plane = (size_t)8192 * 512;
#pragma unroll
  for (int mi = 0; mi < 2; ++mi)
#pragma unroll
    for (int ni = 0; ni < 8; ++ni) {
      int col = wcol * 128 + ni * 16 + l15;
#pragma unroll
      for (int j = 0; j < 4; ++j) {
        int row = brow + wrow * 32 + mi * 16 + g * 4 + j;
        vals16[(size_t)kc * plane + (size_t)row * 512 + col] = (_Float16)acc[mi][ni][j];
      }
    }
}

// ---------------------------------------------------------------- launch
extern "C" void kernel_launch(void* const* d_in, const int* in_sizes, int n_in,
                              void* d_out, int out_size, void* d_ws, size_t ws_size,
                              hipStream_t stream)
{
  const float* x    = (const float*)d_in[0];
  const float* Amat = (const float*)d_in[1];
  const float* Wqkv = (const float*)d_in[2];
  const float* bqkv = (const float*)d_in[3];
  const float* Wo   = (const float*)d_in[4];
  const float* bo   = (const float*)d_in[5];

  float* o    = (float*)d_out;                       // [8192,512]
  float* attn = (float*)d_out + (size_t)8192 * 512;  // [8192,8192]

  float* ws = (float*)d_ws;
  _Float16*  vals16 = (_Float16*)ws;              // 16.7M f16 (4 planes)
  float*     qkv    = ws;                         // 12.58M f32 (dead after transposes)
  _Float16*  k0T16  = (_Float16*)(ws + 12582912); // [512][8192] f16 (single plane)
  _Float16*  vT16   = (_Float16*)(ws + 16777216); // [512][8192] f16
  _Float16*  Whi    = (_Float16*)(ws + 18874368); // pair planes [1536][512] f16 (hi, lo)
  float*     WoT    = ws + 19660800;              // [512][512] f32
  _Float16*  kbuf16 = (_Float16*)(ws + 19922944); // [8192][512] f16
  float*     mx     = ws + 24117248;
  float*     sm     = ws + 24641536;
  float*     rowm   = ws + 25165824;
  float*     rowinv = ws + 25174016;
  float*     csum   = ws + 25182208;
  _Float16*  q16    = (_Float16*)(ws + 25183232); // [8192][512] f16
  float*     kpart  = attn;                       // d_out attn region pre-K3
  _Float16*  xhi    = (_Float16*)attn;            // x pair planes (dead before kpart use)

  const dim3 b256(256), b512(512);
  const float qk_scale = 0.04419417382415922f;  // 1/sqrt(512)
  const size_t plane = (size_t)8192 * 512;      // 4,194,304

  // pre-split x into f16 hi/lo pair (lives in d_out attn region until K2)
  split_f32_f16pair<<<dim3(4096), b256, 0, stream>>>((const float4*)x, xhi, plane);
  // weight transposes: Wqkv -> f16 pair, Wo -> f32
  transpose_f32_f16pair<<<dim3(48, 16), b256, 0, stream>>>(Wqkv, 1536, Whi, 512, 786432);
  transpose_f32<<<dim3(16, 16), b256, 0, stream>>>(Wo, 512, WoT, 512);

  // K1: qkv = x @ Wqkv + bqkv (3-pass, pair-staged both sides) + f16 q copy
  gemm_bt<2, 2, 128, 128, 2, 2, 256, 1, false, true, 2, 2, 2>
      <<<dim3(12, 64), b256, 0, stream>>>(
      xhi, 512, plane, Whi, 512, 786432, qkv, 1536, 0, bqkv, 512, 1.0f, q16);

  // k0 -> f16 single plane (transposed), v -> f16 (transposed)
  transpose_f32_f16<<<dim3(16, 256), b256, 0, stream>>>(qkv + 512, 1536, k0T16, 8192);
  transpose_f32_f16<<<dim3(16, 256), b256, 0, stream>>>(qkv + 1024, 1536, vT16, 8192);
  halfcolsum16<<<dim3(512), b256, 0, stream>>>(k0T16, csum);

  // K2: k = A @ k0 (single-pass: A f32->f16, B f16 pure copy), split-K 4 chunks.
  // MINW=4 (NOT 6): MINW=6 capped VGPRs at ~85 < acc footprint -> acc spilled
  // to scratch (round 12: 3 GB scratch traffic, 800us). 64 VGPR fits at MINW=4.
  gemm_bt<1, 1, 128, 256, 2, 4, 512, 1, true, false, 4, 0, 3>
      <<<dim3(2, 64, 4), b512, 0, stream>>>(
      Amat, 8192, 0, k0T16, 8192, 0, kpart, 512, plane, nullptr, 2048, 1.0f, nullptr);

  // kbuf16 = f16(sum of partials - 0.5*colsum(k0))
  reduce4_f16<<<dim3(4096), b256, 0, stream>>>((const float4*)kpart, kbuf16, plane / 4,
                                               (const float4*)csum);

  // K3: logits = (q16 @ kbuf16^T)*scale + per-tile softmax stats
  gemm_ff16<128, 128, 256, true, 4>
      <<<dim3(64, 64), b256, 0, stream>>>(
      q16, 512, kbuf16, 512, attn, 8192, 512, qk_scale, mx, sm, 64);

  softmax_combine<<<dim3(2048), b256, 0, stream>>>(mx, sm, rowm, rowinv);

  // K5': attention = exp(l-m)/s in place; vals partials f16
  pv_fused<<<dim3(4, 128), b512, 0, stream>>>(attn, vT16, rowm, rowinv, vals16);

  // K6: o = (sum of 4 f16 vals partials) @ Wo + bo
  gemm_bt<1, 1, 128, 128, 2, 2, 256, 4, false, false, 3, 1, 0>
      <<<dim3(4, 64), b256, 0, stream>>>(
      vals16, 512, plane, WoT, 512, 0, o, 512, 0, bo, 512, 1.0f, nullptr);
}

// Round 14
// 584.561 us; speedup vs baseline: 2.1261x; 1.0329x over previous
//
#include <hip/hip_runtime.h>

typedef _Float16 half8 __attribute__((ext_vector_type(8)));
typedef _Float16 half4 __attribute__((ext_vector_type(4)));
typedef float f32x4 __attribute__((ext_vector_type(4)));

// ---------------------------------------------------------------- transpose (f32)
__global__ __launch_bounds__(256) void transpose_f32(
    const float* __restrict__ in, int lda,
    float* __restrict__ out, int ldo)
{
  __shared__ float t[32][33];
  const int tx = threadIdx.x & 31, ty = threadIdx.x >> 5;
  const int bc = blockIdx.x * 32, br = blockIdx.y * 32;
#pragma unroll
  for (int i = 0; i < 4; ++i)
    t[ty + 8 * i][tx] = in[(size_t)(br + ty + 8 * i) * lda + bc + tx];
  __syncthreads();
#pragma unroll
  for (int i = 0; i < 4; ++i)
    out[(size_t)(bc + ty + 8 * i) * ldo + br + tx] = t[tx][ty + 8 * i];
}

// transpose with f32 -> f16 convert on output
__global__ __launch_bounds__(256) void transpose_f32_f16(
    const float* __restrict__ in, int lda,
    _Float16* __restrict__ out, int ldo)
{
  __shared__ float t[32][33];
  const int tx = threadIdx.x & 31, ty = threadIdx.x >> 5;
  const int bc = blockIdx.x * 32, br = blockIdx.y * 32;
#pragma unroll
  for (int i = 0; i < 4; ++i)
    t[ty + 8 * i][tx] = in[(size_t)(br + ty + 8 * i) * lda + bc + tx];
  __syncthreads();
#pragma unroll
  for (int i = 0; i < 4; ++i)
    out[(size_t)(bc + ty + 8 * i) * ldo + br + tx] = (_Float16)t[tx][ty + 8 * i];
}

// elementwise f32 -> f16 convert
__global__ __launch_bounds__(256) void conv_f32_f16(
    const float4* __restrict__ in, _Float16* __restrict__ out)
{
  size_t i = (size_t)blockIdx.x * 256 + threadIdx.x;
  float4 v = in[i];
  half4 h;
  h[0] = (_Float16)v.x; h[1] = (_Float16)v.y;
  h[2] = (_Float16)v.z; h[3] = (_Float16)v.w;
  ((half4*)out)[i] = h;
}

// ---------------------------------------------------------------- half column-sum (f16 input)
__global__ __launch_bounds__(256) void halfcolsum16(
    const _Float16* __restrict__ k0T16, float* __restrict__ csum)
{
  const int d = blockIdx.x, tid = threadIdx.x;
  float s = 0.f;
#pragma unroll
  for (int i = 0; i < 4; ++i) {
    half8 h = *(const half8*)(k0T16 + (size_t)d * 8192 + i * 2048 + tid * 8);
#pragma unroll
    for (int j = 0; j < 8; ++j) s += (float)h[j];
  }
#pragma unroll
  for (int off = 32; off; off >>= 1) s += __shfl_xor(s, off);
  __shared__ float r[4];
  if ((tid & 63) == 0) r[tid >> 6] = s;
  __syncthreads();
  if (tid == 0) csum[d] = 0.5f * ((r[0] + r[1]) + (r[2] + r[3]));
}

// ---------------------------------------------------------------- GEMM (BT)
// AMODE: 0 = f32 A, 1 = f16 A (APART planes summed), 2 = f16 hi/lo pair A,
//        3 = f16 single plane A (pure-copy staging, requires ASPL==1)
// BMODE: 0 = f32 B, 2 = f16 hi/lo pair B, 3 = f16 single plane B (pure copy)
// QF16: q-third (col<512) written ONLY as f16 to q16out (f32 store skipped).
template<int ASPL,int BSPL,int BM,int BN,int WAVES_M,int WAVES_N,int THREADS,
         int APART,bool KSPLIT,bool QF16,int MINW,int AMODE,int BMODE>
__global__ __launch_bounds__(THREADS, MINW) void gemm_bt(
    const void* __restrict__ Agv, int lda, size_t a_plane,
    const void* __restrict__ Bgv, int ldb, size_t b_plane,
    float* __restrict__ Cg, int ldc, size_t c_plane,
    const float* __restrict__ bias, int K, float scale,
    _Float16* __restrict__ q16out)
{
  constexpr int BK = 32;
  constexpr int WM = BM / WAVES_M, WN = BN / WAVES_N;
  constexpr int FM = WM / 16, FN = WN / 16;
  constexpr int NCA = (BM * 4) / THREADS;
  constexpr int NCB = (BN * 4) / THREADS;
  static_assert((BM * 4) % THREADS == 0 && (BN * 4) % THREADS == 0, "mismatch");
  static_assert(AMODE != 3 || ASPL == 1, "AMODE 3 needs ASPL 1");

  __shared__ _Float16 ldsA[2][ASPL][BM][BK];
  __shared__ _Float16 ldsB[2][BSPL][BN][BK];

  const float*    Ag   = (const float*)Agv;
  const _Float16* Ag16 = (const _Float16*)Agv;
  const float*    Bg   = (const float*)Bgv;
  const _Float16* Bg16 = (const _Float16*)Bgv;

  const int tid  = threadIdx.x;
  const int lane = tid & 63;
  const int wid  = tid >> 6;
  const int wrow = wid / WAVES_N, wcol = wid % WAVES_N;
  const int l15  = lane & 15, g = lane >> 4;
  const int brow = blockIdx.y * BM;
  const int bcol = blockIdx.x * BN;

  if constexpr (KSPLIT) {
    const int kc = blockIdx.z;
    Ag += (size_t)kc * K;  Ag16 += (size_t)kc * K;
    Bg += (size_t)kc * K;  Bg16 += (size_t)kc * K;
    Cg += (size_t)kc * c_plane;
  }

  f32x4 acc[FM][FN];
#pragma unroll
  for (int mi = 0; mi < FM; ++mi)
#pragma unroll
    for (int ni = 0; ni < FN; ++ni)
      acc[mi][ni] = (f32x4){0.f, 0.f, 0.f, 0.f};

  float4 ra[NCA][2], rb[NCB][2];
  half8  rah[NCA][2], rbh[NCB][2];

  auto loadAB = [&](int kt) {
    const int k0 = kt * BK;
#pragma unroll
    for (int i = 0; i < NCA; ++i) {
      int c = tid + THREADS * i;
      int row = c >> 2, ci = c & 3;
      if constexpr (AMODE == 3) {
        rah[i][0] = *(const half8*)(Ag16 + (size_t)(brow + row) * lda + k0 + ci * 8);
      } else if constexpr (AMODE == 2) {
        const _Float16* bp = Ag16 + (size_t)(brow + row) * lda + k0 + ci * 8;
        rah[i][0] = *(const half8*)bp;
        rah[i][1] = *(const half8*)(bp + a_plane);
      } else if constexpr (AMODE == 1) {
        float4 u0 = make_float4(0.f, 0.f, 0.f, 0.f);
        float4 u1 = make_float4(0.f, 0.f, 0.f, 0.f);
        const _Float16* bp = Ag16 + (size_t)(brow + row) * lda + k0 + ci * 8;
#pragma unroll
        for (int p = 0; p < APART; ++p) {
          half8 hv = *(const half8*)(bp + (size_t)p * a_plane);
          u0.x += (float)hv[0]; u0.y += (float)hv[1]; u0.z += (float)hv[2]; u0.w += (float)hv[3];
          u1.x += (float)hv[4]; u1.y += (float)hv[5]; u1.z += (float)hv[6]; u1.w += (float)hv[7];
        }
        ra[i][0] = u0; ra[i][1] = u1;
      } else {
        const float* bp = Ag + (size_t)(brow + row) * lda + k0 + ci * 8;
        float4 u0 = ((const float4*)bp)[0];
        float4 u1 = ((const float4*)bp)[1];
#pragma unroll
        for (int p = 1; p < APART; ++p) {
          const float* pp = bp + (size_t)p * a_plane;
          float4 w0 = ((const float4*)pp)[0], w1 = ((const float4*)pp)[1];
          u0.x += w0.x; u0.y += w0.y; u0.z += w0.z; u0.w += w0.w;
          u1.x += w1.x; u1.y += w1.y; u1.z += w1.z; u1.w += w1.w;
        }
        ra[i][0] = u0; ra[i][1] = u1;
      }
    }
#pragma unroll
    for (int i = 0; i < NCB; ++i) {
      int c = tid + THREADS * i;
      int row = c >> 2, ci = c & 3;
      if constexpr (BMODE == 2) {
        const _Float16* bp = Bg16 + (size_t)(bcol + row) * ldb + k0 + ci * 8;
        rbh[i][0] = *(const half8*)bp;
        rbh[i][1] = *(const half8*)(bp + b_plane);
      } else if constexpr (BMODE == 3) {
        rbh[i][0] = *(const half8*)(Bg16 + (size_t)(bcol + row) * ldb + k0 + ci * 8);
      } else {
        const float4* p = (const float4*)(Bg + (size_t)(bcol + row) * ldb + k0 + ci * 8);
        rb[i][0] = p[0]; rb[i][1] = p[1];
      }
    }
  };

  auto stageLDS = [&](int b) {
#pragma unroll
    for (int i = 0; i < NCA; ++i) {
      int c = tid + THREADS * i;
      int row = c >> 2, ci = c & 3;
      int off = row * BK + ((ci ^ ((row >> 1) & 3)) << 3);
      if constexpr (AMODE == 3) {
        *(half8*)(&ldsA[b][0][0][0] + off) = rah[i][0];
      } else if constexpr (AMODE == 2) {
        *(half8*)(&ldsA[b][0][0][0] + off) = rah[i][0];
        *(half8*)(&ldsA[b][1][0][0] + off) = rah[i][1];
      } else {
        float f[8] = {ra[i][0].x, ra[i][0].y, ra[i][0].z, ra[i][0].w,
                      ra[i][1].x, ra[i][1].y, ra[i][1].z, ra[i][1].w};
        half8 h, l;
#pragma unroll
        for (int j = 0; j < 8; ++j) {
          _Float16 hv = (_Float16)f[j];
          h[j] = hv;
          if (ASPL == 2) l[j] = (_Float16)(f[j] - (float)hv);
        }
        *(half8*)(&ldsA[b][0][0][0] + off) = h;
        if (ASPL == 2) *(half8*)(&ldsA[b][1][0][0] + off) = l;
      }
    }
#pragma unroll
    for (int i = 0; i < NCB; ++i) {
      int c = tid + THREADS * i;
      int row = c >> 2, ci = c & 3;
      int off = row * BK + ((ci ^ ((row >> 1) & 3)) << 3);
      if constexpr (BMODE == 2) {
        *(half8*)(&ldsB[b][0][0][0] + off) = rbh[i][0];
        *(half8*)(&ldsB[b][1][0][0] + off) = rbh[i][1];
      } else if constexpr (BMODE == 3) {
        *(half8*)(&ldsB[b][0][0][0] + off) = rbh[i][0];
      } else {
        float f[8] = {rb[i][0].x, rb[i][0].y, rb[i][0].z, rb[i][0].w,
                      rb[i][1].x, rb[i][1].y, rb[i][1].z, rb[i][1].w};
        half8 h, l;
#pragma unroll
        for (int j = 0; j < 8; ++j) {
          _Float16 hv = (_Float16)f[j];
          h[j] = hv;
          if (BSPL == 2) l[j] = (_Float16)(f[j] - (float)hv);
        }
        *(half8*)(&ldsB[b][0][0][0] + off) = h;
        if (BSPL == 2) *(half8*)(&ldsB[b][1][0][0] + off) = l;
      }
    }
  };

  const int nk = K / BK;
  loadAB(0);
  stageLDS(0);
  if (nk > 1) loadAB(1);
  __syncthreads();

  for (int kt = 0; kt < nk; ++kt) {
    const int cur = kt & 1, nxt = cur ^ 1;
    if (kt + 1 < nk) stageLDS(nxt);
    if (kt + 2 < nk) loadAB(kt + 2);

    half8 af[FM][ASPL];
#pragma unroll
    for (int mi = 0; mi < FM; ++mi)
#pragma unroll
      for (int sa = 0; sa < ASPL; ++sa) {
        int row = wrow * WM + mi * 16 + l15;
        af[mi][sa] = *(const half8*)(&ldsA[cur][sa][0][0] + row * BK + ((g ^ ((row >> 1) & 3)) << 3));
      }
#pragma unroll
    for (int ni = 0; ni < FN; ++ni) {
      half8 bf[BSPL];
#pragma unroll
      for (int sb = 0; sb < BSPL; ++sb) {
        int row = wcol * WN + ni * 16 + l15;
        bf[sb] = *(const half8*)(&ldsB[cur][sb][0][0] + row * BK + ((g ^ ((row >> 1) & 3)) << 3));
      }
#pragma unroll
      for (int mi = 0; mi < FM; ++mi)
#pragma unroll
        for (int sa = 0; sa < ASPL; ++sa)
#pragma unroll
          for (int sb = 0; sb < BSPL; ++sb) {
            if (ASPL == 2 && BSPL == 2 && sa == 1 && sb == 1) continue;
            acc[mi][ni] = __builtin_amdgcn_mfma_f32_16x16x32_f16(af[mi][sa], bf[sb], acc[mi][ni], 0, 0, 0);
          }
    }
    __syncthreads();
  }

#pragma unroll
  for (int mi = 0; mi < FM; ++mi)
#pragma unroll
    for (int ni = 0; ni < FN; ++ni) {
      int col = bcol + wcol * WN + ni * 16 + l15;
      float bv = bias ? bias[col] : 0.f;
#pragma unroll
      for (int j = 0; j < 4; ++j) {
        int r = brow + wrow * WM + mi * 16 + g * 4 + j;
        float v = acc[mi][ni][j] * scale + bv;
        if constexpr (QF16) {
          if (col < 512) q16out[(size_t)r * 512 + col] = (_Float16)v;  // f32 q never read
          else           Cg[(size_t)r * ldc + col] = v;
        } else {
          Cg[(size_t)r * ldc + col] = v;
        }
      }
    }
}

// ---------------------------------------------------------------- GEMM f16 x f16 (K3)
template<int BM,int BN,int THREADS,bool STATS,int MINW>
__global__ __launch_bounds__(THREADS, MINW) void gemm_ff16(
    const _Float16* __restrict__ Ag, int lda,
    const _Float16* __restrict__ Bg, int ldb,
    float* __restrict__ Cg, int ldc,
    int K, float scale,
    float* __restrict__ mxout, float* __restrict__ smout, int ntiles)
{
  constexpr int BK = 32;
  constexpr int WAVES_M = 2, WAVES_N = 2;
  constexpr int WM = BM / WAVES_M, WN = BN / WAVES_N;
  constexpr int FM = WM / 16, FN = WN / 16;
  constexpr int NCA = (BM * 4) / THREADS;
  constexpr int NCB = (BN * 4) / THREADS;

  __shared__ _Float16 ldsA[2][BM][BK];
  __shared__ _Float16 ldsB[2][BN][BK];

  const int tid  = threadIdx.x;
  const int lane = tid & 63;
  const int wid  = tid >> 6;
  const int wrow = wid >> 1, wcol = wid & 1;
  const int l15  = lane & 15, g = lane >> 4;
  const int brow = blockIdx.y * BM;
  const int bcol = blockIdx.x * BN;

  f32x4 acc[FM][FN];
#pragma unroll
  for (int mi = 0; mi < FM; ++mi)
#pragma unroll
    for (int ni = 0; ni < FN; ++ni)
      acc[mi][ni] = (f32x4){0.f, 0.f, 0.f, 0.f};

  half8 ra[NCA], rb[NCB];

  auto loadAB = [&](int kt) {
    const int k0 = kt * BK;
#pragma unroll
    for (int i = 0; i < NCA; ++i) {
      int c = tid + THREADS * i;
      int row = c >> 2, ci = c & 3;
      ra[i] = *(const half8*)(Ag + (size_t)(brow + row) * lda + k0 + ci * 8);
    }
#pragma unroll
    for (int i = 0; i < NCB; ++i) {
      int c = tid + THREADS * i;
      int row = c >> 2, ci = c & 3;
      rb[i] = *(const half8*)(Bg + (size_t)(bcol + row) * ldb + k0 + ci * 8);
    }
  };

  auto stageLDS = [&](int b) {
#pragma unroll
    for (int i = 0; i < NCA; ++i) {
      int c = tid + THREADS * i;
      int row = c >> 2, ci = c & 3;
      int off = row * BK + ((ci ^ ((row >> 1) & 3)) << 3);
      *(half8*)(&ldsA[b][0][0] + off) = ra[i];
    }
#pragma unroll
    for (int i = 0; i < NCB; ++i) {
      int c = tid + THREADS * i;
      int row = c >> 2, ci = c & 3;
      int off = row * BK + ((ci ^ ((row >> 1) & 3)) << 3);
      *(half8*)(&ldsB[b][0][0] + off) = rb[i];
    }
  };

  const int nk = K / BK;
  loadAB(0);
  stageLDS(0);
  if (nk > 1) loadAB(1);
  __syncthreads();

  for (int kt = 0; kt < nk; ++kt) {
    const int cur = kt & 1, nxt = cur ^ 1;
    if (kt + 1 < nk) stageLDS(nxt);
    if (kt + 2 < nk) loadAB(kt + 2);

    half8 af[FM];
#pragma unroll
    for (int mi = 0; mi < FM; ++mi) {
      int row = wrow * WM + mi * 16 + l15;
      af[mi] = *(const half8*)(&ldsA[cur][0][0] + row * BK + ((g ^ ((row >> 1) & 3)) << 3));
    }
#pragma unroll
    for (int ni = 0; ni < FN; ++ni) {
      int row = wcol * WN + ni * 16 + l15;
      half8 bf = *(const half8*)(&ldsB[cur][0][0] + row * BK + ((g ^ ((row >> 1) & 3)) << 3));
#pragma unroll
      for (int mi = 0; mi < FM; ++mi)
        acc[mi][ni] = __builtin_amdgcn_mfma_f32_16x16x32_f16(af[mi], bf, acc[mi][ni], 0, 0, 0);
    }
    __syncthreads();
  }

#pragma unroll
  for (int mi = 0; mi < FM; ++mi)
#pragma unroll
    for (int ni = 0; ni < FN; ++ni) {
      int col = bcol + wcol * WN + ni * 16 + l15;
#pragma unroll
      for (int j = 0; j < 4; ++j) {
        int r = brow + wrow * WM + mi * 16 + g * 4 + j;
        Cg[(size_t)r * ldc + col] = acc[mi][ni][j] * scale;
      }
    }

  if constexpr (STATS) {
    __shared__ float s_m2[BM][2];
    __shared__ float s_s2[BM][2];
#pragma unroll
    for (int mi = 0; mi < FM; ++mi)
#pragma unroll
      for (int j = 0; j < 4; ++j) {
        float v = -3.4e38f;
#pragma unroll
        for (int ni = 0; ni < FN; ++ni) v = fmaxf(v, acc[mi][ni][j] * scale);
        v = fmaxf(v, __shfl_xor(v, 1)); v = fmaxf(v, __shfl_xor(v, 2));
        v = fmaxf(v, __shfl_xor(v, 4)); v = fmaxf(v, __shfl_xor(v, 8));
        if (l15 == 0) s_m2[wrow * WM + mi * 16 + g * 4 + j][wcol] = v;
      }
    __syncthreads();
#pragma unroll
    for (int mi = 0; mi < FM; ++mi)
#pragma unroll
      for (int j = 0; j < 4; ++j) {
        int r = wrow * WM + mi * 16 + g * 4 + j;
        float mt = fmaxf(s_m2[r][0], s_m2[r][1]);
        float s = 0.f;
#pragma unroll
        for (int ni = 0; ni < FN; ++ni) s += __expf(acc[mi][ni][j] * scale - mt);
        s += __shfl_xor(s, 1); s += __shfl_xor(s, 2);
        s += __shfl_xor(s, 4); s += __shfl_xor(s, 8);
        if (l15 == 0) s_s2[r][wcol] = s;
      }
    __syncthreads();
    if (tid < BM) {
      float mt = fmaxf(s_m2[tid][0], s_m2[tid][1]);
      float st = s_s2[tid][0] + s_s2[tid][1];
      mxout[(size_t)(brow + tid) * ntiles + blockIdx.x] = mt;
      smout[(size_t)(brow + tid) * ntiles + blockIdx.x] = st;
    }
  }
}

// ---------------------------------------------------------------- reduce 4 planes -> f16
__global__ __launch_bounds__(256) void reduce4_f16(
    const float4* __restrict__ in, _Float16* __restrict__ out16, size_t plane4,
    const float4* __restrict__ csum4)
{
  size_t i = (size_t)blockIdx.x * 256 + threadIdx.x;
  float4 a = in[i], b = in[plane4 + i], c = in[2 * plane4 + i], d = in[3 * plane4 + i];
  float4 s = csum4[i & 127];
  half4 h;
  h[0] = (_Float16)(a.x + b.x + c.x + d.x - s.x);
  h[1] = (_Float16)(a.y + b.y + c.y + d.y - s.y);
  h[2] = (_Float16)(a.z + b.z + c.z + d.z - s.z);
  h[3] = (_Float16)(a.w + b.w + c.w + d.w - s.w);
  *(half4*)(out16 + i * 4) = h;
}

// ---------------------------------------------------------------- stats combine
__global__ __launch_bounds__(256) void softmax_combine(
    const float* __restrict__ mx, const float* __restrict__ sm,
    float* __restrict__ rowm, float* __restrict__ rowinv)
{
  const int row = blockIdx.x * 4 + (threadIdx.x >> 6);
  const int lane = threadIdx.x & 63;
  float mt = mx[(size_t)row * 64 + lane];
  float m = mt;
#pragma unroll
  for (int off = 32; off; off >>= 1) m = fmaxf(m, __shfl_xor(m, off));
  float s = sm[(size_t)row * 64 + lane] * __expf(mt - m);
#pragma unroll
  for (int off = 32; off; off >>= 1) s += __shfl_xor(s, off);
  if (lane == 0) { rowm[row] = m; rowinv[row] = 1.0f / s; }
}

// ---------------------------------------------------------------- fused attn-write + PV
// Round-10 verified (199-210us): 1 barrier/step, dbuf LDS, setprio, f16 partials.
__global__ __launch_bounds__(512, 4) void pv_fused(
    float* __restrict__ attn,            // [8192][8192] logits in, attention out
    const _Float16* __restrict__ vT16,   // [512][8192] f16
    const float* __restrict__ rowm, const float* __restrict__ rowinv,
    _Float16* __restrict__ vals16)       // [4][8192][512] f16
{
  constexpr int BM = 64, BN = 512, BK = 32, NSTEP = 64;  // KC = 2048
  __shared__ _Float16 ldsA[2][BM][BK];   // 8 KB
  __shared__ _Float16 ldsB[2][BN][BK];   // 64 KB
  __shared__ float s_m[BM], s_inv[BM];

  const int tid = threadIdx.x, lane = tid & 63, wid = tid >> 6;
  const int wrow = wid >> 2, wcol = wid & 3;   // 2 x 4 waves
  const int l15 = lane & 15, g = lane >> 4;
  const int kc = blockIdx.x, brow = blockIdx.y * BM;
  const size_t kbase = (size_t)kc * 2048;

  if (tid < BM) { s_m[tid] = rowm[brow + tid]; s_inv[tid] = rowinv[brow + tid]; }

  f32x4 acc[2][8];
#pragma unroll
  for (int mi = 0; mi < 2; ++mi)
#pragma unroll
    for (int ni = 0; ni < 8; ++ni) acc[mi][ni] = (f32x4){0.f, 0.f, 0.f, 0.f};

  const int arow = (tid & 255) >> 2, aci = tid & 3;
  float4 ra[2];
  half8 rbh[4];

  auto loadA = [&](int kt) {
    if (tid < 256) {
      const float4* p = (const float4*)(attn + (size_t)(brow + arow) * 8192 + kbase + kt * BK + aci * 8);
      ra[0] = p[0]; ra[1] = p[1];
    }
  };
  auto loadB = [&](int kt) {
#pragma unroll
    for (int i = 0; i < 4; ++i) {
      int c = tid + 512 * i; int r = c >> 2, ci = c & 3;
      rbh[i] = *(const half8*)(vT16 + (size_t)r * 8192 + kbase + kt * BK + ci * 8);
    }
  };
  auto stage = [&](int kt, int b) {
    if (tid < 256) {
      const float m = s_m[arow], inv = s_inv[arow];
      float f[8] = {ra[0].x, ra[0].y, ra[0].z, ra[0].w, ra[1].x, ra[1].y, ra[1].z, ra[1].w};
      float e[8]; half8 h;
#pragma unroll
      for (int j = 0; j < 8; ++j) {
        e[j] = __expf(f[j] - m) * inv;
        h[j] = (_Float16)e[j];
      }
      float4* w = (float4*)(attn + (size_t)(brow + arow) * 8192 + kbase + kt * BK + aci * 8);
      w[0] = make_float4(e[0], e[1], e[2], e[3]);
      w[1] = make_float4(e[4], e[5], e[6], e[7]);
      int off = arow * BK + ((aci ^ ((arow >> 1) & 3)) << 3);
      *(half8*)(&ldsA[b][0][0] + off) = h;
    }
#pragma unroll
    for (int i = 0; i < 4; ++i) {
      int c = tid + 512 * i; int r = c >> 2, ci = c & 3;
      int off2 = r * BK + ((ci ^ ((r >> 1) & 3)) << 3);
      *(half8*)(&ldsB[b][0][0] + off2) = rbh[i];
    }
  };

  loadA(0); loadB(0);
  __syncthreads();            // s_m / s_inv visible
  stage(0, 0);
  loadA(1); loadB(1);
  __syncthreads();            // buf0 staged

  for (int kt = 0; kt < NSTEP; ++kt) {
    const int cur = kt & 1, nxt = cur ^ 1;
    if (kt + 1 < NSTEP) stage(kt + 1, nxt);
    if (kt + 2 < NSTEP) { loadA(kt + 2); loadB(kt + 2); }
    half8 af[2];
#pragma unroll
    for (int mi = 0; mi < 2; ++mi) {
      int row = wrow * 32 + mi * 16 + l15;
      af[mi] = *(const half8*)(&ldsA[cur][0][0] + row * BK + ((g ^ ((row >> 1) & 3)) << 3));
    }
    __builtin_amdgcn_s_setprio(1);
#pragma unroll
    for (int ni = 0; ni < 8; ++ni) {
      int rn = wcol * 128 + ni * 16 + l15;
      half8 bf = *(const half8*)(&ldsB[cur][0][0] + rn * BK + ((g ^ ((rn >> 1) & 3)) << 3));
#pragma unroll
      for (int mi = 0; mi < 2; ++mi)
        acc[mi][ni] = __builtin_amdgcn_mfma_f32_16x16x32_f16(af[mi], bf, acc[mi][ni], 0, 0, 0);
    }
    __builtin_amdgcn_s_setprio(0);
    __syncthreads();
  }

  const size_t plane = (size_t)8192 * 512;
#pragma unroll
  for (int mi = 0; mi < 2; ++mi)
#pragma unroll
    for (int ni = 0; ni < 8; ++ni) {
      int col = wcol * 128 + ni * 16 + l15;
#pragma unroll
      for (int j = 0; j < 4; ++j) {
        int row = brow + wrow * 32 + mi * 16 + g * 4 + j;
        vals16[(size_t)kc * plane + (size_t)row * 512 + col] = (_Float16)acc[mi][ni][j];
      }
    }
}

// ---------------------------------------------------------------- launch
extern "C" void kernel_launch(void* const* d_in, const int* in_sizes, int n_in,
                              void* d_out, int out_size, void* d_ws, size_t ws_size,
                              hipStream_t stream)
{
  const float* x    = (const float*)d_in[0];
  const float* Amat = (const float*)d_in[1];
  const float* Wqkv = (const float*)d_in[2];
  const float* bqkv = (const float*)d_in[3];
  const float* Wo   = (const float*)d_in[4];
  const float* bo   = (const float*)d_in[5];

  float* o    = (float*)d_out;                       // [8192,512]
  float* attn = (float*)d_out + (size_t)8192 * 512;  // [8192,8192]

  float* ws = (float*)d_ws;
  _Float16*  vals16 = (_Float16*)ws;              // 16.7M f16 (4 planes)
  float*     qkv    = ws;                         // 12.58M f32 (dead after transposes)
  _Float16*  k0T16  = (_Float16*)(ws + 12582912); // [512][8192] f16
  _Float16*  vT16   = (_Float16*)(ws + 16777216); // [512][8192] f16
  _Float16*  W16T   = (_Float16*)(ws + 18874368); // [1536][512] f16
  float*     WoT    = ws + 19660800;              // [512][512] f32
  _Float16*  kbuf16 = (_Float16*)(ws + 19922944); // [8192][512] f16
  float*     mx     = ws + 24117248;
  float*     sm     = ws + 24641536;
  float*     rowm   = ws + 25165824;
  float*     rowinv = ws + 25174016;
  float*     csum   = ws + 25182208;
  _Float16*  q16    = (_Float16*)(ws + 25183232); // [8192][512] f16
  float*     kpart  = attn;                       // d_out attn region pre-K3
  _Float16*  x16    = (_Float16*)attn;            // x f16 (dead before kpart use)

  const dim3 b256(256), b512(512);
  const float qk_scale = 0.04419417382415922f;  // 1/sqrt(512)
  const size_t plane = (size_t)8192 * 512;      // 4,194,304

  // x -> f16 (lives in d_out attn region until K2); weights -> f16 / f32
  conv_f32_f16<<<dim3(4096), b256, 0, stream>>>((const float4*)x, x16);
  transpose_f32_f16<<<dim3(48, 16), b256, 0, stream>>>(Wqkv, 1536, W16T, 512);
  transpose_f32<<<dim3(16, 16), b256, 0, stream>>>(Wo, 512, WoT, 512);

  // K1: qkv = x @ Wqkv + bqkv (single-pass f16: all consumers are f16 anyway)
  // q-third emitted ONLY as f16 to q16 (f32 q never read downstream).
  gemm_bt<1, 1, 128, 128, 2, 2, 256, 1, false, true, 4, 3, 3>
      <<<dim3(12, 64), b256, 0, stream>>>(
      x16, 512, 0, W16T, 512, 0, qkv, 1536, 0, bqkv, 512, 1.0f, q16);

  // k0 -> f16 (transposed), v -> f16 (transposed)
  transpose_f32_f16<<<dim3(16, 256), b256, 0, stream>>>(qkv + 512, 1536, k0T16, 8192);
  transpose_f32_f16<<<dim3(16, 256), b256, 0, stream>>>(qkv + 1024, 1536, vT16, 8192);
  halfcolsum16<<<dim3(512), b256, 0, stream>>>(k0T16, csum);

  // K2: k = A @ k0 (single-pass: A f32->f16, B f16 pure copy), split-K 4 chunks.
  // MINW=4 (NOT 6): MINW=6 capped VGPRs below acc footprint -> scratch spill
  // (round 12: 3 GB scratch traffic, 800us).
  gemm_bt<1, 1, 128, 256, 2, 4, 512, 1, true, false, 4, 0, 3>
      <<<dim3(2, 64, 4), b512, 0, stream>>>(
      Amat, 8192, 0, k0T16, 8192, 0, kpart, 512, plane, nullptr, 2048, 1.0f, nullptr);

  // kbuf16 = f16(sum of partials - 0.5*colsum(k0))
  reduce4_f16<<<dim3(4096), b256, 0, stream>>>((const float4*)kpart, kbuf16, plane / 4,
                                               (const float4*)csum);

  // K3: logits = (q16 @ kbuf16^T)*scale + per-tile softmax stats
  gemm_ff16<128, 128, 256, true, 4>
      <<<dim3(64, 64), b256, 0, stream>>>(
      q16, 512, kbuf16, 512, attn, 8192, 512, qk_scale, mx, sm, 64);

  softmax_combine<<<dim3(2048), b256, 0, stream>>>(mx, sm, rowm, rowinv);

  // K5': attention = exp(l-m)/s in place; vals partials f16
  pv_fused<<<dim3(4, 128), b512, 0, stream>>>(attn, vT16, rowm, rowinv, vals16);

  // K6: o = (sum of 4 f16 vals partials) @ Wo + bo
  gemm_bt<1, 1, 128, 128, 2, 2, 256, 4, false, false, 3, 1, 0>
      <<<dim3(4, 64), b256, 0, stream>>>(
      vals16, 512, plane, WoT, 512, 0, o, 512, 0, bo, 512, 1.0f, nullptr);
}

// Round 15
// 580.946 us; speedup vs baseline: 2.1393x; 1.0062x over previous
//
#include <hip/hip_runtime.h>

typedef _Float16 half8 __attribute__((ext_vector_type(8)));
typedef _Float16 half4 __attribute__((ext_vector_type(4)));
typedef float f32x4 __attribute__((ext_vector_type(4)));

// ---------------------------------------------------------------- transpose (f32)
__global__ __launch_bounds__(256) void transpose_f32(
    const float* __restrict__ in, int lda,
    float* __restrict__ out, int ldo)
{
  __shared__ float t[32][33];
  const int tx = threadIdx.x & 31, ty = threadIdx.x >> 5;
  const int bc = blockIdx.x * 32, br = blockIdx.y * 32;
#pragma unroll
  for (int i = 0; i < 4; ++i)
    t[ty + 8 * i][tx] = in[(size_t)(br + ty + 8 * i) * lda + bc + tx];
  __syncthreads();
#pragma unroll
  for (int i = 0; i < 4; ++i)
    out[(size_t)(bc + ty + 8 * i) * ldo + br + tx] = t[tx][ty + 8 * i];
}

// transpose with f32 -> f16 convert on output (weights)
__global__ __launch_bounds__(256) void transpose_f32_f16(
    const float* __restrict__ in, int lda,
    _Float16* __restrict__ out, int ldo)
{
  __shared__ float t[32][33];
  const int tx = threadIdx.x & 31, ty = threadIdx.x >> 5;
  const int bc = blockIdx.x * 32, br = blockIdx.y * 32;
#pragma unroll
  for (int i = 0; i < 4; ++i)
    t[ty + 8 * i][tx] = in[(size_t)(br + ty + 8 * i) * lda + bc + tx];
  __syncthreads();
#pragma unroll
  for (int i = 0; i < 4; ++i)
    out[(size_t)(bc + ty + 8 * i) * ldo + br + tx] = (_Float16)t[tx][ty + 8 * i];
}

// f16 -> f16 transpose, 64x64 tile ([64][66] pad: store-phase reads are 2-way/free)
__global__ __launch_bounds__(256) void transpose_f16(
    const _Float16* __restrict__ in, int lda,
    _Float16* __restrict__ out, int ldo)
{
  __shared__ _Float16 t[64][66];
  const int tx = threadIdx.x & 63, ty = threadIdx.x >> 6;   // 64 x 4
  const int bc = blockIdx.x * 64, br = blockIdx.y * 64;
#pragma unroll
  for (int i = 0; i < 16; ++i)
    t[ty + 4 * i][tx] = in[(size_t)(br + ty + 4 * i) * lda + bc + tx];
  __syncthreads();
#pragma unroll
  for (int i = 0; i < 16; ++i)
    out[(size_t)(bc + ty + 4 * i) * ldo + br + tx] = t[tx][ty + 4 * i];
}

// elementwise f32 -> f16 convert
__global__ __launch_bounds__(256) void conv_f32_f16(
    const float4* __restrict__ in, _Float16* __restrict__ out)
{
  size_t i = (size_t)blockIdx.x * 256 + threadIdx.x;
  float4 v = in[i];
  half4 h;
  h[0] = (_Float16)v.x; h[1] = (_Float16)v.y;
  h[2] = (_Float16)v.z; h[3] = (_Float16)v.w;
  ((half4*)out)[i] = h;
}

// ---------------------------------------------------------------- half column-sum (f16 input)
__global__ __launch_bounds__(256) void halfcolsum16(
    const _Float16* __restrict__ k0T16, float* __restrict__ csum)
{
  const int d = blockIdx.x, tid = threadIdx.x;
  float s = 0.f;
#pragma unroll
  for (int i = 0; i < 4; ++i) {
    half8 h = *(const half8*)(k0T16 + (size_t)d * 8192 + i * 2048 + tid * 8);
#pragma unroll
    for (int j = 0; j < 8; ++j) s += (float)h[j];
  }
#pragma unroll
  for (int off = 32; off; off >>= 1) s += __shfl_xor(s, off);
  __shared__ float r[4];
  if ((tid & 63) == 0) r[tid >> 6] = s;
  __syncthreads();
  if (tid == 0) csum[d] = 0.5f * ((r[0] + r[1]) + (r[2] + r[3]));
}

// ---------------------------------------------------------------- GEMM (BT)
// AMODE: 0 = f32 A, 1 = f16 A (APART planes summed), 3 = f16 single plane A
// BMODE: 0 = f32 B, 3 = f16 single plane B (pure copy)
// CMODE: 0 = f32 C store; 2 = ALL cols stored f16 to c16out (ldc stride)
template<int ASPL,int BSPL,int BM,int BN,int WAVES_M,int WAVES_N,int THREADS,
         int APART,bool KSPLIT,int CMODE,int MINW,int AMODE,int BMODE>
__global__ __launch_bounds__(THREADS, MINW) void gemm_bt(
    const void* __restrict__ Agv, int lda, size_t a_plane,
    const void* __restrict__ Bgv, int ldb, size_t b_plane,
    float* __restrict__ Cg, int ldc, size_t c_plane,
    const float* __restrict__ bias, int K, float scale,
    _Float16* __restrict__ c16out)
{
  constexpr int BK = 32;
  constexpr int WM = BM / WAVES_M, WN = BN / WAVES_N;
  constexpr int FM = WM / 16, FN = WN / 16;
  constexpr int NCA = (BM * 4) / THREADS;
  constexpr int NCB = (BN * 4) / THREADS;
  static_assert((BM * 4) % THREADS == 0 && (BN * 4) % THREADS == 0, "mismatch");
  static_assert(AMODE != 3 || ASPL == 1, "AMODE 3 needs ASPL 1");

  __shared__ _Float16 ldsA[2][ASPL][BM][BK];
  __shared__ _Float16 ldsB[2][BSPL][BN][BK];

  const float*    Ag   = (const float*)Agv;
  const _Float16* Ag16 = (const _Float16*)Agv;
  const float*    Bg   = (const float*)Bgv;
  const _Float16* Bg16 = (const _Float16*)Bgv;

  const int tid  = threadIdx.x;
  const int lane = tid & 63;
  const int wid  = tid >> 6;
  const int wrow = wid / WAVES_N, wcol = wid % WAVES_N;
  const int l15  = lane & 15, g = lane >> 4;
  const int brow = blockIdx.y * BM;
  const int bcol = blockIdx.x * BN;

  if constexpr (KSPLIT) {
    const int kc = blockIdx.z;
    Ag += (size_t)kc * K;  Ag16 += (size_t)kc * K;
    Bg += (size_t)kc * K;  Bg16 += (size_t)kc * K;
    Cg += (size_t)kc * c_plane;
  }

  f32x4 acc[FM][FN];
#pragma unroll
  for (int mi = 0; mi < FM; ++mi)
#pragma unroll
    for (int ni = 0; ni < FN; ++ni)
      acc[mi][ni] = (f32x4){0.f, 0.f, 0.f, 0.f};

  float4 ra[NCA][2], rb[NCB][2];
  half8  rah[NCA], rbh[NCB];

  auto loadAB = [&](int kt) {
    const int k0 = kt * BK;
#pragma unroll
    for (int i = 0; i < NCA; ++i) {
      int c = tid + THREADS * i;
      int row = c >> 2, ci = c & 3;
      if constexpr (AMODE == 3) {
        rah[i] = *(const half8*)(Ag16 + (size_t)(brow + row) * lda + k0 + ci * 8);
      } else if constexpr (AMODE == 1) {
        float4 u0 = make_float4(0.f, 0.f, 0.f, 0.f);
        float4 u1 = make_float4(0.f, 0.f, 0.f, 0.f);
        const _Float16* bp = Ag16 + (size_t)(brow + row) * lda + k0 + ci * 8;
#pragma unroll
        for (int p = 0; p < APART; ++p) {
          half8 hv = *(const half8*)(bp + (size_t)p * a_plane);
          u0.x += (float)hv[0]; u0.y += (float)hv[1]; u0.z += (float)hv[2]; u0.w += (float)hv[3];
          u1.x += (float)hv[4]; u1.y += (float)hv[5]; u1.z += (float)hv[6]; u1.w += (float)hv[7];
        }
        ra[i][0] = u0; ra[i][1] = u1;
      } else {
        const float* bp = Ag + (size_t)(brow + row) * lda + k0 + ci * 8;
        float4 u0 = ((const float4*)bp)[0];
        float4 u1 = ((const float4*)bp)[1];
#pragma unroll
        for (int p = 1; p < APART; ++p) {
          const float* pp = bp + (size_t)p * a_plane;
          float4 w0 = ((const float4*)pp)[0], w1 = ((const float4*)pp)[1];
          u0.x += w0.x; u0.y += w0.y; u0.z += w0.z; u0.w += w0.w;
          u1.x += w1.x; u1.y += w1.y; u1.z += w1.z; u1.w += w1.w;
        }
        ra[i][0] = u0; ra[i][1] = u1;
      }
    }
#pragma unroll
    for (int i = 0; i < NCB; ++i) {
      int c = tid + THREADS * i;
      int row = c >> 2, ci = c & 3;
      if constexpr (BMODE == 3) {
        rbh[i] = *(const half8*)(Bg16 + (size_t)(bcol + row) * ldb + k0 + ci * 8);
      } else {
        const float4* p = (const float4*)(Bg + (size_t)(bcol + row) * ldb + k0 + ci * 8);
        rb[i][0] = p[0]; rb[i][1] = p[1];
      }
    }
  };

  auto stageLDS = [&](int b) {
#pragma unroll
    for (int i = 0; i < NCA; ++i) {
      int c = tid + THREADS * i;
      int row = c >> 2, ci = c & 3;
      int off = row * BK + ((ci ^ ((row >> 1) & 3)) << 3);
      if constexpr (AMODE == 3) {
        *(half8*)(&ldsA[b][0][0][0] + off) = rah[i];
      } else {
        float f[8] = {ra[i][0].x, ra[i][0].y, ra[i][0].z, ra[i][0].w,
                      ra[i][1].x, ra[i][1].y, ra[i][1].z, ra[i][1].w};
        half8 h, l;
#pragma unroll
        for (int j = 0; j < 8; ++j) {
          _Float16 hv = (_Float16)f[j];
          h[j] = hv;
          if (ASPL == 2) l[j] = (_Float16)(f[j] - (float)hv);
        }
        *(half8*)(&ldsA[b][0][0][0] + off) = h;
        if (ASPL == 2) *(half8*)(&ldsA[b][1][0][0] + off) = l;
      }
    }
#pragma unroll
    for (int i = 0; i < NCB; ++i) {
      int c = tid + THREADS * i;
      int row = c >> 2, ci = c & 3;
      int off = row * BK + ((ci ^ ((row >> 1) & 3)) << 3);
      if constexpr (BMODE == 3) {
        *(half8*)(&ldsB[b][0][0][0] + off) = rbh[i];
      } else {
        float f[8] = {rb[i][0].x, rb[i][0].y, rb[i][0].z, rb[i][0].w,
                      rb[i][1].x, rb[i][1].y, rb[i][1].z, rb[i][1].w};
        half8 h, l;
#pragma unroll
        for (int j = 0; j < 8; ++j) {
          _Float16 hv = (_Float16)f[j];
          h[j] = hv;
          if (BSPL == 2) l[j] = (_Float16)(f[j] - (float)hv);
        }
        *(half8*)(&ldsB[b][0][0][0] + off) = h;
        if (BSPL == 2) *(half8*)(&ldsB[b][1][0][0] + off) = l;
      }
    }
  };

  const int nk = K / BK;
  loadAB(0);
  stageLDS(0);
  if (nk > 1) loadAB(1);
  __syncthreads();

  for (int kt = 0; kt < nk; ++kt) {
    const int cur = kt & 1, nxt = cur ^ 1;
    if (kt + 1 < nk) stageLDS(nxt);
    if (kt + 2 < nk) loadAB(kt + 2);

    half8 af[FM][ASPL];
#pragma unroll
    for (int mi = 0; mi < FM; ++mi)
#pragma unroll
      for (int sa = 0; sa < ASPL; ++sa) {
        int row = wrow * WM + mi * 16 + l15;
        af[mi][sa] = *(const half8*)(&ldsA[cur][sa][0][0] + row * BK + ((g ^ ((row >> 1) & 3)) << 3));
      }
#pragma unroll
    for (int ni = 0; ni < FN; ++ni) {
      half8 bf[BSPL];
#pragma unroll
      for (int sb = 0; sb < BSPL; ++sb) {
        int row = wcol * WN + ni * 16 + l15;
        bf[sb] = *(const half8*)(&ldsB[cur][sb][0][0] + row * BK + ((g ^ ((row >> 1) & 3)) << 3));
      }
#pragma unroll
      for (int mi = 0; mi < FM; ++mi)
#pragma unroll
        for (int sa = 0; sa < ASPL; ++sa)
#pragma unroll
          for (int sb = 0; sb < BSPL; ++sb) {
            if (ASPL == 2 && BSPL == 2 && sa == 1 && sb == 1) continue;
            acc[mi][ni] = __builtin_amdgcn_mfma_f32_16x16x32_f16(af[mi][sa], bf[sb], acc[mi][ni], 0, 0, 0);
          }
    }
    __syncthreads();
  }

#pragma unroll
  for (int mi = 0; mi < FM; ++mi)
#pragma unroll
    for (int ni = 0; ni < FN; ++ni) {
      int col = bcol + wcol * WN + ni * 16 + l15;
      float bv = bias ? bias[col] : 0.f;
#pragma unroll
      for (int j = 0; j < 4; ++j) {
        int r = brow + wrow * WM + mi * 16 + g * 4 + j;
        float v = acc[mi][ni][j] * scale + bv;
        if constexpr (CMODE == 2) {
          c16out[(size_t)r * ldc + col] = (_Float16)v;   // f16-only C (K1)
        } else {
          Cg[(size_t)r * ldc + col] = v;
        }
      }
    }
}

// ---------------------------------------------------------------- GEMM f16 x f16 (K3)
// SWZ: 1-D grid of 4096, XCD-bijective remap (nwg % 8 == 0)
template<int BM,int BN,int THREADS,bool STATS,int MINW>
__global__ __launch_bounds__(THREADS, MINW) void gemm_ff16(
    const _Float16* __restrict__ Ag, int lda,
    const _Float16* __restrict__ Bg, int ldb,
    float* __restrict__ Cg, int ldc,
    int K, float scale,
    float* __restrict__ mxout, float* __restrict__ smout, int ntiles)
{
  constexpr int BK = 32;
  constexpr int WAVES_M = 2, WAVES_N = 2;
  constexpr int WM = BM / WAVES_M, WN = BN / WAVES_N;
  constexpr int FM = WM / 16, FN = WN / 16;
  constexpr int NCA = (BM * 4) / THREADS;
  constexpr int NCB = (BN * 4) / THREADS;

  __shared__ _Float16 ldsA[2][BM][BK];
  __shared__ _Float16 ldsB[2][BN][BK];

  const int tid  = threadIdx.x;
  const int lane = tid & 63;
  const int wid  = tid >> 6;
  const int wrow = wid >> 1, wcol = wid & 1;
  const int l15  = lane & 15, g = lane >> 4;

  // XCD-bijective swizzle: each XCD owns 512 consecutive (by,bx) tiles
  const int id = blockIdx.x;                 // 0..4095
  const int wgid = (id & 7) * 512 + (id >> 3);
  const int bxv = wgid & 63, byv = wgid >> 6;
  const int brow = byv * BM;
  const int bcol = bxv * BN;

  f32x4 acc[FM][FN];
#pragma unroll
  for (int mi = 0; mi < FM; ++mi)
#pragma unroll
    for (int ni = 0; ni < FN; ++ni)
      acc[mi][ni] = (f32x4){0.f, 0.f, 0.f, 0.f};

  half8 ra[NCA], rb[NCB];

  auto loadAB = [&](int kt) {
    const int k0 = kt * BK;
#pragma unroll
    for (int i = 0; i < NCA; ++i) {
      int c = tid + THREADS * i;
      int row = c >> 2, ci = c & 3;
      ra[i] = *(const half8*)(Ag + (size_t)(brow + row) * lda + k0 + ci * 8);
    }
#pragma unroll
    for (int i = 0; i < NCB; ++i) {
      int c = tid + THREADS * i;
      int row = c >> 2, ci = c & 3;
      rb[i] = *(const half8*)(Bg + (size_t)(bcol + row) * ldb + k0 + ci * 8);
    }
  };

  auto stageLDS = [&](int b) {
#pragma unroll
    for (int i = 0; i < NCA; ++i) {
      int c = tid + THREADS * i;
      int row = c >> 2, ci = c & 3;
      int off = row * BK + ((ci ^ ((row >> 1) & 3)) << 3);
      *(half8*)(&ldsA[b][0][0] + off) = ra[i];
    }
#pragma unroll
    for (int i = 0; i < NCB; ++i) {
      int c = tid + THREADS * i;
      int row = c >> 2, ci = c & 3;
      int off = row * BK + ((ci ^ ((row >> 1) & 3)) << 3);
      *(half8*)(&ldsB[b][0][0] + off) = rb[i];
    }
  };

  const int nk = K / BK;
  loadAB(0);
  stageLDS(0);
  if (nk > 1) loadAB(1);
  __syncthreads();

  for (int kt = 0; kt < nk; ++kt) {
    const int cur = kt & 1, nxt = cur ^ 1;
    if (kt + 1 < nk) stageLDS(nxt);
    if (kt + 2 < nk) loadAB(kt + 2);

    half8 af[FM];
#pragma unroll
    for (int mi = 0; mi < FM; ++mi) {
      int row = wrow * WM + mi * 16 + l15;
      af[mi] = *(const half8*)(&ldsA[cur][0][0] + row * BK + ((g ^ ((row >> 1) & 3)) << 3));
    }
#pragma unroll
    for (int ni = 0; ni < FN; ++ni) {
      int row = wcol * WN + ni * 16 + l15;
      half8 bf = *(const half8*)(&ldsB[cur][0][0] + row * BK + ((g ^ ((row >> 1) & 3)) << 3));
#pragma unroll
      for (int mi = 0; mi < FM; ++mi)
        acc[mi][ni] = __builtin_amdgcn_mfma_f32_16x16x32_f16(af[mi], bf, acc[mi][ni], 0, 0, 0);
    }
    __syncthreads();
  }

#pragma unroll
  for (int mi = 0; mi < FM; ++mi)
#pragma unroll
    for (int ni = 0; ni < FN; ++ni) {
      int col = bcol + wcol * WN + ni * 16 + l15;
#pragma unroll
      for (int j = 0; j < 4; ++j) {
        int r = brow + wrow * WM + mi * 16 + g * 4 + j;
        Cg[(size_t)r * ldc + col] = acc[mi][ni][j] * scale;
      }
    }

  if constexpr (STATS) {
    __shared__ float s_m2[BM][2];
    __shared__ float s_s2[BM][2];
#pragma unroll
    for (int mi = 0; mi < FM; ++mi)
#pragma unroll
      for (int j = 0; j < 4; ++j) {
        float v = -3.4e38f;
#pragma unroll
        for (int ni = 0; ni < FN; ++ni) v = fmaxf(v, acc[mi][ni][j] * scale);
        v = fmaxf(v, __shfl_xor(v, 1)); v = fmaxf(v, __shfl_xor(v, 2));
        v = fmaxf(v, __shfl_xor(v, 4)); v = fmaxf(v, __shfl_xor(v, 8));
        if (l15 == 0) s_m2[wrow * WM + mi * 16 + g * 4 + j][wcol] = v;
      }
    __syncthreads();
#pragma unroll
    for (int mi = 0; mi < FM; ++mi)
#pragma unroll
      for (int j = 0; j < 4; ++j) {
        int r = wrow * WM + mi * 16 + g * 4 + j;
        float mt = fmaxf(s_m2[r][0], s_m2[r][1]);
        float s = 0.f;
#pragma unroll
        for (int ni = 0; ni < FN; ++ni) s += __expf(acc[mi][ni][j] * scale - mt);
        s += __shfl_xor(s, 1); s += __shfl_xor(s, 2);
        s += __shfl_xor(s, 4); s += __shfl_xor(s, 8);
        if (l15 == 0) s_s2[r][wcol] = s;
      }
    __syncthreads();
    if (tid < BM) {
      float mt = fmaxf(s_m2[tid][0], s_m2[tid][1]);
      float st = s_s2[tid][0] + s_s2[tid][1];
      mxout[(size_t)(brow + tid) * ntiles + bxv] = mt;
      smout[(size_t)(brow + tid) * ntiles + bxv] = st;
    }
  }
}

// ---------------------------------------------------------------- reduce 4 planes -> f16
__global__ __launch_bounds__(256) void reduce4_f16(
    const float4* __restrict__ in, _Float16* __restrict__ out16, size_t plane4,
    const float4* __restrict__ csum4)
{
  size_t i = (size_t)blockIdx.x * 256 + threadIdx.x;
  float4 a = in[i], b = in[plane4 + i], c = in[2 * plane4 + i], d = in[3 * plane4 + i];
  float4 s = csum4[i & 127];
  half4 h;
  h[0] = (_Float16)(a.x + b.x + c.x + d.x - s.x);
  h[1] = (_Float16)(a.y + b.y + c.y + d.y - s.y);
  h[2] = (_Float16)(a.z + b.z + c.z + d.z - s.z);
  h[3] = (_Float16)(a.w + b.w + c.w + d.w - s.w);
  *(half4*)(out16 + i * 4) = h;
}

// ---------------------------------------------------------------- stats combine
__global__ __launch_bounds__(256) void softmax_combine(
    const float* __restrict__ mx, const float* __restrict__ sm,
    float* __restrict__ rowm, float* __restrict__ rowinv)
{
  const int row = blockIdx.x * 4 + (threadIdx.x >> 6);
  const int lane = threadIdx.x & 63;
  float mt = mx[(size_t)row * 64 + lane];
  float m = mt;
#pragma unroll
  for (int off = 32; off; off >>= 1) m = fmaxf(m, __shfl_xor(m, off));
  float s = sm[(size_t)row * 64 + lane] * __expf(mt - m);
#pragma unroll
  for (int off = 32; off; off >>= 1) s += __shfl_xor(s, off);
  if (lane == 0) { rowm[row] = m; rowinv[row] = 1.0f / s; }
}

// ---------------------------------------------------------------- fused attn-write + PV
// Round-10 verified (~200us): 1 barrier/step, dbuf LDS, setprio, f16 partials.
__global__ __launch_bounds__(512, 4) void pv_fused(
    float* __restrict__ attn,            // [8192][8192] logits in, attention out
    const _Float16* __restrict__ vT16,   // [512][8192] f16
    const float* __restrict__ rowm, const float* __restrict__ rowinv,
    _Float16* __restrict__ vals16)       // [4][8192][512] f16
{
  constexpr int BM = 64, BN = 512, BK = 32, NSTEP = 64;  // KC = 2048
  __shared__ _Float16 ldsA[2][BM][BK];   // 8 KB
  __shared__ _Float16 ldsB[2][BN][BK];   // 64 KB
  __shared__ float s_m[BM], s_inv[BM];

  const int tid = threadIdx.x, lane = tid & 63, wid = tid >> 6;
  const int wrow = wid >> 2, wcol = wid & 3;   // 2 x 4 waves
  const int l15 = lane & 15, g = lane >> 4;
  const int kc = blockIdx.x, brow = blockIdx.y * BM;
  const size_t kbase = (size_t)kc * 2048;

  if (tid < BM) { s_m[tid] = rowm[brow + tid]; s_inv[tid] = rowinv[brow + tid]; }

  f32x4 acc[2][8];
#pragma unroll
  for (int mi = 0; mi < 2; ++mi)
#pragma unroll
    for (int ni = 0; ni < 8; ++ni) acc[mi][ni] = (f32x4){0.f, 0.f, 0.f, 0.f};

  const int arow = (tid & 255) >> 2, aci = tid & 3;
  float4 ra[2];
  half8 rbh[4];

  auto loadA = [&](int kt) {
    if (tid < 256) {
      const float4* p = (const float4*)(attn + (size_t)(brow + arow) * 8192 + kbase + kt * BK + aci * 8);
      ra[0] = p[0]; ra[1] = p[1];
    }
  };
  auto loadB = [&](int kt) {
#pragma unroll
    for (int i = 0; i < 4; ++i) {
      int c = tid + 512 * i; int r = c >> 2, ci = c & 3;
      rbh[i] = *(const half8*)(vT16 + (size_t)r * 8192 + kbase + kt * BK + ci * 8);
    }
  };
  auto stage = [&](int kt, int b) {
    if (tid < 256) {
      const float m = s_m[arow], inv = s_inv[arow];
      float f[8] = {ra[0].x, ra[0].y, ra[0].z, ra[0].w, ra[1].x, ra[1].y, ra[1].z, ra[1].w};
      float e[8]; half8 h;
#pragma unroll
      for (int j = 0; j < 8; ++j) {
        e[j] = __expf(f[j] - m) * inv;
        h[j] = (_Float16)e[j];
      }
      float4* w = (float4*)(attn + (size_t)(brow + arow) * 8192 + kbase + kt * BK + aci * 8);
      w[0] = make_float4(e[0], e[1], e[2], e[3]);
      w[1] = make_float4(e[4], e[5], e[6], e[7]);
      int off = arow * BK + ((aci ^ ((arow >> 1) & 3)) << 3);
      *(half8*)(&ldsA[b][0][0] + off) = h;
    }
#pragma unroll
    for (int i = 0; i < 4; ++i) {
      int c = tid + 512 * i; int r = c >> 2, ci = c & 3;
      int off2 = r * BK + ((ci ^ ((r >> 1) & 3)) << 3);
      *(half8*)(&ldsB[b][0][0] + off2) = rbh[i];
    }
  };

  loadA(0); loadB(0);
  __syncthreads();            // s_m / s_inv visible
  stage(0, 0);
  loadA(1); loadB(1);
  __syncthreads();            // buf0 staged

  for (int kt = 0; kt < NSTEP; ++kt) {
    const int cur = kt & 1, nxt = cur ^ 1;
    if (kt + 1 < NSTEP) stage(kt + 1, nxt);
    if (kt + 2 < NSTEP) { loadA(kt + 2); loadB(kt + 2); }
    half8 af[2];
#pragma unroll
    for (int mi = 0; mi < 2; ++mi) {
      int row = wrow * 32 + mi * 16 + l15;
      af[mi] = *(const half8*)(&ldsA[cur][0][0] + row * BK + ((g ^ ((row >> 1) & 3)) << 3));
    }
    __builtin_amdgcn_s_setprio(1);
#pragma unroll
    for (int ni = 0; ni < 8; ++ni) {
      int rn = wcol * 128 + ni * 16 + l15;
      half8 bf = *(const half8*)(&ldsB[cur][0][0] + rn * BK + ((g ^ ((rn >> 1) & 3)) << 3));
#pragma unroll
      for (int mi = 0; mi < 2; ++mi)
        acc[mi][ni] = __builtin_amdgcn_mfma_f32_16x16x32_f16(af[mi], bf, acc[mi][ni], 0, 0, 0);
    }
    __builtin_amdgcn_s_setprio(0);
    __syncthreads();
  }

  const size_t plane = (size_t)8192 * 512;
#pragma unroll
  for (int mi = 0; mi < 2; ++mi)
#pragma unroll
    for (int ni = 0; ni < 8; ++ni) {
      int col = wcol * 128 + ni * 16 + l15;
#pragma unroll
      for (int j = 0; j < 4; ++j) {
        int row = brow + wrow * 32 + mi * 16 + g * 4 + j;
        vals16[(size_t)kc * plane + (size_t)row * 512 + col] = (_Float16)acc[mi][ni][j];
      }
    }
}

// ---------------------------------------------------------------- launch
extern "C" void kernel_launch(void* const* d_in, const int* in_sizes, int n_in,
                              void* d_out, int out_size, void* d_ws, size_t ws_size,
                              hipStream_t stream)
{
  const float* x    = (const float*)d_in[0];
  const float* Amat = (const float*)d_in[1];
  const float* Wqkv = (const float*)d_in[2];
  const float* bqkv = (const float*)d_in[3];
  const float* Wo   = (const float*)d_in[4];
  const float* bo   = (const float*)d_in[5];

  float* o    = (float*)d_out;                       // [8192,512]
  float* attn = (float*)d_out + (size_t)8192 * 512;  // [8192,8192]

  float* ws = (float*)d_ws;
  _Float16*  vals16 = (_Float16*)ws;              // [4][8192][512] f16 (33.5 MB)
  _Float16*  qkv16  = (_Float16*)(ws + 8388608);  // [8192][1536] f16 (25 MB); q = +0 (lda 1536)
  _Float16*  k0T16  = (_Float16*)(ws + 14680064); // [512][8192] f16
  _Float16*  vT16   = (_Float16*)(ws + 16777216); // [512][8192] f16
  _Float16*  W16T   = (_Float16*)(ws + 18874368); // [1536][512] f16
  float*     WoT    = ws + 19660800;              // [512][512] f32
  _Float16*  kbuf16 = (_Float16*)(ws + 19922944); // [8192][512] f16
  float*     mx     = ws + 24117248;
  float*     sm     = ws + 24641536;
  float*     rowm   = ws + 25165824;
  float*     rowinv = ws + 25174016;
  float*     csum   = ws + 25182208;
  float*     kpart  = attn;                       // d_out attn region pre-K3
  _Float16*  x16    = (_Float16*)attn;            // x f16 (dead before kpart use)

  const dim3 b256(256), b512(512);
  const float qk_scale = 0.04419417382415922f;  // 1/sqrt(512)
  const size_t plane = (size_t)8192 * 512;      // 4,194,304

  // x -> f16 (lives in d_out attn region until K2); weights -> f16 / f32
  conv_f32_f16<<<dim3(4096), b256, 0, stream>>>((const float4*)x, x16);
  transpose_f32_f16<<<dim3(48, 16), b256, 0, stream>>>(Wqkv, 1536, W16T, 512);
  transpose_f32<<<dim3(16, 16), b256, 0, stream>>>(Wo, 512, WoT, 512);

  // K1: qkv16 = f16(x @ Wqkv + bqkv)  — single f16 store, no f32 qkv at all
  gemm_bt<1, 1, 128, 128, 2, 2, 256, 1, false, 2, 4, 3, 3>
      <<<dim3(12, 64), b256, 0, stream>>>(
      x16, 512, 0, W16T, 512, 0, nullptr, 1536, 0, bqkv, 512, 1.0f, qkv16);

  // k0 / v thirds -> transposed f16 (f16->f16, bit-identical to old f32 path)
  transpose_f16<<<dim3(8, 128), b256, 0, stream>>>(qkv16 + 512, 1536, k0T16, 8192);
  transpose_f16<<<dim3(8, 128), b256, 0, stream>>>(qkv16 + 1024, 1536, vT16, 8192);
  halfcolsum16<<<dim3(512), b256, 0, stream>>>(k0T16, csum);

  // K2: k = A @ k0 (single-pass: A f32->f16 staged, B f16 pure copy), split-K 4.
  // MINW=4 (NOT 6): higher MINW caps VGPR below acc footprint -> scratch spill
  // (round 12: 3 GB scratch traffic, 800us).
  gemm_bt<1, 1, 128, 256, 2, 4, 512, 1, true, 0, 4, 0, 3>
      <<<dim3(2, 64, 4), b512, 0, stream>>>(
      Amat, 8192, 0, k0T16, 8192, 0, kpart, 512, plane, nullptr, 2048, 1.0f, nullptr);

  // kbuf16 = f16(sum of partials - 0.5*colsum(k0))
  reduce4_f16<<<dim3(4096), b256, 0, stream>>>((const float4*)kpart, kbuf16, plane / 4,
                                               (const float4*)csum);

  // K3: logits = (q16 @ kbuf16^T)*scale + per-tile softmax stats (XCD swizzle)
  gemm_ff16<128, 128, 256, true, 4>
      <<<dim3(4096), b256, 0, stream>>>(
      qkv16, 1536, kbuf16, 512, attn, 8192, 512, qk_scale, mx, sm, 64);

  softmax_combine<<<dim3(2048), b256, 0, stream>>>(mx, sm, rowm, rowinv);

  // K5': attention = exp(l-m)/s in place; vals partials f16
  pv_fused<<<dim3(4, 128), b512, 0, stream>>>(attn, vT16, rowm, rowinv, vals16);

  // K6: o = (sum of 4 f16 vals partials) @ Wo + bo
  gemm_bt<1, 1, 128, 128, 2, 2, 256, 4, false, 0, 3, 1, 0>
      <<<dim3(4, 64), b256, 0, stream>>>(
      vals16, 512, plane, WoT, 512, 0, o, 512, 0, bo, 512, 1.0f, nullptr);
}

// Round 17
// 547.345 us; speedup vs baseline: 2.2707x; 1.0614x over previous
//
#include <hip/hip_runtime.h>

typedef _Float16 half8 __attribute__((ext_vector_type(8)));
typedef _Float16 half4 __attribute__((ext_vector_type(4)));
typedef float f32x4 __attribute__((ext_vector_type(4)));

// ---------------------------------------------------------------- transpose (f32)
__global__ __launch_bounds__(256) void transpose_f32(
    const float* __restrict__ in, int lda,
    float* __restrict__ out, int ldo)
{
  __shared__ float t[32][33];
  const int tx = threadIdx.x & 31, ty = threadIdx.x >> 5;
  const int bc = blockIdx.x * 32, br = blockIdx.y * 32;
#pragma unroll
  for (int i = 0; i < 4; ++i)
    t[ty + 8 * i][tx] = in[(size_t)(br + ty + 8 * i) * lda + bc + tx];
  __syncthreads();
#pragma unroll
  for (int i = 0; i < 4; ++i)
    out[(size_t)(bc + ty + 8 * i) * ldo + br + tx] = t[tx][ty + 8 * i];
}

// transpose with f32 -> f16 convert on output (weights)
__global__ __launch_bounds__(256) void transpose_f32_f16(
    const float* __restrict__ in, int lda,
    _Float16* __restrict__ out, int ldo)
{
  __shared__ float t[32][33];
  const int tx = threadIdx.x & 31, ty = threadIdx.x >> 5;
  const int bc = blockIdx.x * 32, br = blockIdx.y * 32;
#pragma unroll
  for (int i = 0; i < 4; ++i)
    t[ty + 8 * i][tx] = in[(size_t)(br + ty + 8 * i) * lda + bc + tx];
  __syncthreads();
#pragma unroll
  for (int i = 0; i < 4; ++i)
    out[(size_t)(bc + ty + 8 * i) * ldo + br + tx] = (_Float16)t[tx][ty + 8 * i];
}

// f16 -> f16 transpose, 64x64 tile
__global__ __launch_bounds__(256) void transpose_f16(
    const _Float16* __restrict__ in, int lda,
    _Float16* __restrict__ out, int ldo)
{
  __shared__ _Float16 t[64][66];
  const int tx = threadIdx.x & 63, ty = threadIdx.x >> 6;   // 64 x 4
  const int bc = blockIdx.x * 64, br = blockIdx.y * 64;
#pragma unroll
  for (int i = 0; i < 16; ++i)
    t[ty + 4 * i][tx] = in[(size_t)(br + ty + 4 * i) * lda + bc + tx];
  __syncthreads();
#pragma unroll
  for (int i = 0; i < 16; ++i)
    out[(size_t)(bc + ty + 4 * i) * ldo + br + tx] = t[tx][ty + 4 * i];
}

// elementwise f32 -> f16 convert
__global__ __launch_bounds__(256) void conv_f32_f16(
    const float4* __restrict__ in, _Float16* __restrict__ out)
{
  size_t i = (size_t)blockIdx.x * 256 + threadIdx.x;
  float4 v = in[i];
  half4 h;
  h[0] = (_Float16)v.x; h[1] = (_Float16)v.y;
  h[2] = (_Float16)v.z; h[3] = (_Float16)v.w;
  ((half4*)out)[i] = h;
}

// ---------------------------------------------------------------- half column-sum (f16 input)
__global__ __launch_bounds__(256) void halfcolsum16(
    const _Float16* __restrict__ k0T16, float* __restrict__ csum)
{
  const int d = blockIdx.x, tid = threadIdx.x;
  float s = 0.f;
#pragma unroll
  for (int i = 0; i < 4; ++i) {
    half8 h = *(const half8*)(k0T16 + (size_t)d * 8192 + i * 2048 + tid * 8);
#pragma unroll
    for (int j = 0; j < 8; ++j) s += (float)h[j];
  }
#pragma unroll
  for (int off = 32; off; off >>= 1) s += __shfl_xor(s, off);
  __shared__ float r[4];
  if ((tid & 63) == 0) r[tid >> 6] = s;
  __syncthreads();
  if (tid == 0) csum[d] = 0.5f * ((r[0] + r[1]) + (r[2] + r[3]));
}

// ---------------------------------------------------------------- GEMM (BT)
// AMODE: 0 = f32 A, 1 = f16 A (APART planes summed), 3 = f16 single plane A
// BMODE: 0 = f32 B, 3 = f16 single plane B (pure copy)
// CMODE: 0 = f32 C store; 2 = ALL cols stored f16 to c16out (ldc stride)
template<int ASPL,int BSPL,int BM,int BN,int WAVES_M,int WAVES_N,int THREADS,
         int APART,bool KSPLIT,int CMODE,int MINW,int AMODE,int BMODE>
__global__ __launch_bounds__(THREADS, MINW) void gemm_bt(
    const void* __restrict__ Agv, int lda, size_t a_plane,
    const void* __restrict__ Bgv, int ldb, size_t b_plane,
    float* __restrict__ Cg, int ldc, size_t c_plane,
    const float* __restrict__ bias, int K, float scale,
    _Float16* __restrict__ c16out)
{
  constexpr int BK = 32;
  constexpr int WM = BM / WAVES_M, WN = BN / WAVES_N;
  constexpr int FM = WM / 16, FN = WN / 16;
  constexpr int NCA = (BM * 4) / THREADS;
  constexpr int NCB = (BN * 4) / THREADS;
  static_assert((BM * 4) % THREADS == 0 && (BN * 4) % THREADS == 0, "mismatch");
  static_assert(AMODE != 3 || ASPL == 1, "AMODE 3 needs ASPL 1");

  __shared__ _Float16 ldsA[2][ASPL][BM][BK];
  __shared__ _Float16 ldsB[2][BSPL][BN][BK];

  const float*    Ag   = (const float*)Agv;
  const _Float16* Ag16 = (const _Float16*)Agv;
  const float*    Bg   = (const float*)Bgv;
  const _Float16* Bg16 = (const _Float16*)Bgv;

  const int tid  = threadIdx.x;
  const int lane = tid & 63;
  const int wid  = tid >> 6;
  const int wrow = wid / WAVES_N, wcol = wid % WAVES_N;
  const int l15  = lane & 15, g = lane >> 4;
  const int brow = blockIdx.y * BM;
  const int bcol = blockIdx.x * BN;

  if constexpr (KSPLIT) {
    const int kc = blockIdx.z;
    Ag += (size_t)kc * K;  Ag16 += (size_t)kc * K;
    Bg += (size_t)kc * K;  Bg16 += (size_t)kc * K;
    Cg += (size_t)kc * c_plane;
  }

  f32x4 acc[FM][FN];
#pragma unroll
  for (int mi = 0; mi < FM; ++mi)
#pragma unroll
    for (int ni = 0; ni < FN; ++ni)
      acc[mi][ni] = (f32x4){0.f, 0.f, 0.f, 0.f};

  float4 ra[NCA][2], rb[NCB][2];
  half8  rah[NCA], rbh[NCB];

  auto loadAB = [&](int kt) {
    const int k0 = kt * BK;
#pragma unroll
    for (int i = 0; i < NCA; ++i) {
      int c = tid + THREADS * i;
      int row = c >> 2, ci = c & 3;
      if constexpr (AMODE == 3) {
        rah[i] = *(const half8*)(Ag16 + (size_t)(brow + row) * lda + k0 + ci * 8);
      } else if constexpr (AMODE == 1) {
        float4 u0 = make_float4(0.f, 0.f, 0.f, 0.f);
        float4 u1 = make_float4(0.f, 0.f, 0.f, 0.f);
        const _Float16* bp = Ag16 + (size_t)(brow + row) * lda + k0 + ci * 8;
#pragma unroll
        for (int p = 0; p < APART; ++p) {
          half8 hv = *(const half8*)(bp + (size_t)p * a_plane);
          u0.x += (float)hv[0]; u0.y += (float)hv[1]; u0.z += (float)hv[2]; u0.w += (float)hv[3];
          u1.x += (float)hv[4]; u1.y += (float)hv[5]; u1.z += (float)hv[6]; u1.w += (float)hv[7];
        }
        ra[i][0] = u0; ra[i][1] = u1;
      } else {
        const float* bp = Ag + (size_t)(brow + row) * lda + k0 + ci * 8;
        float4 u0 = ((const float4*)bp)[0];
        float4 u1 = ((const float4*)bp)[1];
#pragma unroll
        for (int p = 1; p < APART; ++p) {
          const float* pp = bp + (size_t)p * a_plane;
          float4 w0 = ((const float4*)pp)[0], w1 = ((const float4*)pp)[1];
          u0.x += w0.x; u0.y += w0.y; u0.z += w0.z; u0.w += w0.w;
          u1.x += w1.x; u1.y += w1.y; u1.z += w1.z; u1.w += w1.w;
        }
        ra[i][0] = u0; ra[i][1] = u1;
      }
    }
#pragma unroll
    for (int i = 0; i < NCB; ++i) {
      int c = tid + THREADS * i;
      int row = c >> 2, ci = c & 3;
      if constexpr (BMODE == 3) {
        rbh[i] = *(const half8*)(Bg16 + (size_t)(bcol + row) * ldb + k0 + ci * 8);
      } else {
        const float4* p = (const float4*)(Bg + (size_t)(bcol + row) * ldb + k0 + ci * 8);
        rb[i][0] = p[0]; rb[i][1] = p[1];
      }
    }
  };

  auto stageLDS = [&](int b) {
#pragma unroll
    for (int i = 0; i < NCA; ++i) {
      int c = tid + THREADS * i;
      int row = c >> 2, ci = c & 3;
      int off = row * BK + ((ci ^ ((row >> 1) & 3)) << 3);
      if constexpr (AMODE == 3) {
        *(half8*)(&ldsA[b][0][0][0] + off) = rah[i];
      } else {
        float f[8] = {ra[i][0].x, ra[i][0].y, ra[i][0].z, ra[i][0].w,
                      ra[i][1].x, ra[i][1].y, ra[i][1].z, ra[i][1].w};
        half8 h, l;
#pragma unroll
        for (int j = 0; j < 8; ++j) {
          _Float16 hv = (_Float16)f[j];
          h[j] = hv;
          if (ASPL == 2) l[j] = (_Float16)(f[j] - (float)hv);
        }
        *(half8*)(&ldsA[b][0][0][0] + off) = h;
        if (ASPL == 2) *(half8*)(&ldsA[b][1][0][0] + off) = l;
      }
    }
#pragma unroll
    for (int i = 0; i < NCB; ++i) {
      int c = tid + THREADS * i;
      int row = c >> 2, ci = c & 3;
      int off = row * BK + ((ci ^ ((row >> 1) & 3)) << 3);
      if constexpr (BMODE == 3) {
        *(half8*)(&ldsB[b][0][0][0] + off) = rbh[i];
      } else {
        float f[8] = {rb[i][0].x, rb[i][0].y, rb[i][0].z, rb[i][0].w,
                      rb[i][1].x, rb[i][1].y, rb[i][1].z, rb[i][1].w};
        half8 h, l;
#pragma unroll
        for (int j = 0; j < 8; ++j) {
          _Float16 hv = (_Float16)f[j];
          h[j] = hv;
          if (BSPL == 2) l[j] = (_Float16)(f[j] - (float)hv);
        }
        *(half8*)(&ldsB[b][0][0][0] + off) = h;
        if (BSPL == 2) *(half8*)(&ldsB[b][1][0][0] + off) = l;
      }
    }
  };

  const int nk = K / BK;
  loadAB(0);
  stageLDS(0);
  if (nk > 1) loadAB(1);
  __syncthreads();

  for (int kt = 0; kt < nk; ++kt) {
    const int cur = kt & 1, nxt = cur ^ 1;
    if (kt + 1 < nk) stageLDS(nxt);
    if (kt + 2 < nk) loadAB(kt + 2);

    half8 af[FM][ASPL];
#pragma unroll
    for (int mi = 0; mi < FM; ++mi)
#pragma unroll
      for (int sa = 0; sa < ASPL; ++sa) {
        int row = wrow * WM + mi * 16 + l15;
        af[mi][sa] = *(const half8*)(&ldsA[cur][sa][0][0] + row * BK + ((g ^ ((row >> 1) & 3)) << 3));
      }
#pragma unroll
    for (int ni = 0; ni < FN; ++ni) {
      half8 bf[BSPL];
#pragma unroll
      for (int sb = 0; sb < BSPL; ++sb) {
        int row = wcol * WN + ni * 16 + l15;
        bf[sb] = *(const half8*)(&ldsB[cur][sb][0][0] + row * BK + ((g ^ ((row >> 1) & 3)) << 3));
      }
#pragma unroll
      for (int mi = 0; mi < FM; ++mi)
#pragma unroll
        for (int sa = 0; sa < ASPL; ++sa)
#pragma unroll
          for (int sb = 0; sb < BSPL; ++sb) {
            if (ASPL == 2 && BSPL == 2 && sa == 1 && sb == 1) continue;
            acc[mi][ni] = __builtin_amdgcn_mfma_f32_16x16x32_f16(af[mi][sa], bf[sb], acc[mi][ni], 0, 0, 0);
          }
    }
    __syncthreads();
  }

#pragma unroll
  for (int mi = 0; mi < FM; ++mi)
#pragma unroll
    for (int ni = 0; ni < FN; ++ni) {
      int col = bcol + wcol * WN + ni * 16 + l15;
      float bv = bias ? bias[col] : 0.f;
#pragma unroll
      for (int j = 0; j < 4; ++j) {
        int r = brow + wrow * WM + mi * 16 + g * 4 + j;
        float v = acc[mi][ni][j] * scale + bv;
        if constexpr (CMODE == 2) {
          c16out[(size_t)r * ldc + col] = (_Float16)v;   // f16-only C (K1)
        } else {
          Cg[(size_t)r * ldc + col] = v;
        }
      }
    }
}

// ---------------------------------------------------------------- GEMM f16 x f16 (K3)
// XCD-bijective 1-D swizzle. CM: 0 = f32 absolute logits; 1 = f16 logits stored
// RELATIVE to per-(row,128-tile) max (values <= 0; near-max entries have tiny
// ulp -> exp error <= ~0.8% worst case, vs ~6% for absolute-f16 [round 16 fail]).
template<int BM,int BN,int THREADS,bool STATS,int MINW,int CM>
__global__ __launch_bounds__(THREADS, MINW) void gemm_ff16(
    const _Float16* __restrict__ Ag, int lda,
    const _Float16* __restrict__ Bg, int ldb,
    float* __restrict__ Cg, _Float16* __restrict__ Cg16, int ldc,
    int K, float scale,
    float* __restrict__ mxout, float* __restrict__ smout, int ntiles)
{
  constexpr int BK = 32;
  constexpr int WAVES_M = 2, WAVES_N = 2;
  constexpr int WM = BM / WAVES_M, WN = BN / WAVES_N;
  constexpr int FM = WM / 16, FN = WN / 16;
  constexpr int NCA = (BM * 4) / THREADS;
  constexpr int NCB = (BN * 4) / THREADS;

  __shared__ _Float16 ldsA[2][BM][BK];
  __shared__ _Float16 ldsB[2][BN][BK];

  const int tid  = threadIdx.x;
  const int lane = tid & 63;
  const int wid  = tid >> 6;
  const int wrow = wid >> 1, wcol = wid & 1;
  const int l15  = lane & 15, g = lane >> 4;

  const int id = blockIdx.x;                 // 0..4095
  const int wgid = (id & 7) * 512 + (id >> 3);
  const int bxv = wgid & 63, byv = wgid >> 6;
  const int brow = byv * BM;
  const int bcol = bxv * BN;

  f32x4 acc[FM][FN];
#pragma unroll
  for (int mi = 0; mi < FM; ++mi)
#pragma unroll
    for (int ni = 0; ni < FN; ++ni)
      acc[mi][ni] = (f32x4){0.f, 0.f, 0.f, 0.f};

  half8 ra[NCA], rb[NCB];

  auto loadAB = [&](int kt) {
    const int k0 = kt * BK;
#pragma unroll
    for (int i = 0; i < NCA; ++i) {
      int c = tid + THREADS * i;
      int row = c >> 2, ci = c & 3;
      ra[i] = *(const half8*)(Ag + (size_t)(brow + row) * lda + k0 + ci * 8);
    }
#pragma unroll
    for (int i = 0; i < NCB; ++i) {
      int c = tid + THREADS * i;
      int row = c >> 2, ci = c & 3;
      rb[i] = *(const half8*)(Bg + (size_t)(bcol + row) * ldb + k0 + ci * 8);
    }
  };

  auto stageLDS = [&](int b) {
#pragma unroll
    for (int i = 0; i < NCA; ++i) {
      int c = tid + THREADS * i;
      int row = c >> 2, ci = c & 3;
      int off = row * BK + ((ci ^ ((row >> 1) & 3)) << 3);
      *(half8*)(&ldsA[b][0][0] + off) = ra[i];
    }
#pragma unroll
    for (int i = 0; i < NCB; ++i) {
      int c = tid + THREADS * i;
      int row = c >> 2, ci = c & 3;
      int off = row * BK + ((ci ^ ((row >> 1) & 3)) << 3);
      *(half8*)(&ldsB[b][0][0] + off) = rb[i];
    }
  };

  const int nk = K / BK;
  loadAB(0);
  stageLDS(0);
  if (nk > 1) loadAB(1);
  __syncthreads();

  for (int kt = 0; kt < nk; ++kt) {
    const int cur = kt & 1, nxt = cur ^ 1;
    if (kt + 1 < nk) stageLDS(nxt);
    if (kt + 2 < nk) loadAB(kt + 2);

    half8 af[FM];
#pragma unroll
    for (int mi = 0; mi < FM; ++mi) {
      int row = wrow * WM + mi * 16 + l15;
      af[mi] = *(const half8*)(&ldsA[cur][0][0] + row * BK + ((g ^ ((row >> 1) & 3)) << 3));
    }
#pragma unroll
    for (int ni = 0; ni < FN; ++ni) {
      int row = wcol * WN + ni * 16 + l15;
      half8 bf = *(const half8*)(&ldsB[cur][0][0] + row * BK + ((g ^ ((row >> 1) & 3)) << 3));
#pragma unroll
      for (int mi = 0; mi < FM; ++mi)
        acc[mi][ni] = __builtin_amdgcn_mfma_f32_16x16x32_f16(af[mi], bf, acc[mi][ni], 0, 0, 0);
    }
    __syncthreads();
  }

  if constexpr (CM == 0) {
#pragma unroll
    for (int mi = 0; mi < FM; ++mi)
#pragma unroll
      for (int ni = 0; ni < FN; ++ni) {
        int col = bcol + wcol * WN + ni * 16 + l15;
#pragma unroll
        for (int j = 0; j < 4; ++j) {
          int r = brow + wrow * WM + mi * 16 + g * 4 + j;
          Cg[(size_t)r * ldc + col] = acc[mi][ni][j] * scale;
        }
      }
  }

  if constexpr (STATS) {
    __shared__ float s_m2[BM][2];
    __shared__ float s_s2[BM][2];
#pragma unroll
    for (int mi = 0; mi < FM; ++mi)
#pragma unroll
      for (int j = 0; j < 4; ++j) {
        float v = -3.4e38f;
#pragma unroll
        for (int ni = 0; ni < FN; ++ni) v = fmaxf(v, acc[mi][ni][j] * scale);
        v = fmaxf(v, __shfl_xor(v, 1)); v = fmaxf(v, __shfl_xor(v, 2));
        v = fmaxf(v, __shfl_xor(v, 4)); v = fmaxf(v, __shfl_xor(v, 8));
        if (l15 == 0) s_m2[wrow * WM + mi * 16 + g * 4 + j][wcol] = v;
      }
    __syncthreads();
#pragma unroll
    for (int mi = 0; mi < FM; ++mi)
#pragma unroll
      for (int j = 0; j < 4; ++j) {
        int r = wrow * WM + mi * 16 + g * 4 + j;
        float mt = fmaxf(s_m2[r][0], s_m2[r][1]);
        float s = 0.f;
#pragma unroll
        for (int ni = 0; ni < FN; ++ni) {
          float lv = acc[mi][ni][j] * scale - mt;   // <= 0 by construction
          s += __expf(lv);
          if constexpr (CM == 1) {
            int col = bcol + wcol * WN + ni * 16 + l15;
            Cg16[(size_t)(brow + r) * ldc + col] = (_Float16)lv;
          }
        }
        s += __shfl_xor(s, 1); s += __shfl_xor(s, 2);
        s += __shfl_xor(s, 4); s += __shfl_xor(s, 8);
        if (l15 == 0) s_s2[r][wcol] = s;
      }
    __syncthreads();
    if (tid < BM) {
      float mt = fmaxf(s_m2[tid][0], s_m2[tid][1]);
      float st = s_s2[tid][0] + s_s2[tid][1];
      mxout[(size_t)(brow + tid) * ntiles + bxv] = mt;
      smout[(size_t)(brow + tid) * ntiles + bxv] = st;
    }
  }
}

// ---------------------------------------------------------------- reduce 4 planes -> f16
__global__ __launch_bounds__(256) void reduce4_f16(
    const float4* __restrict__ in, _Float16* __restrict__ out16, size_t plane4,
    const float4* __restrict__ csum4)
{
  size_t i = (size_t)blockIdx.x * 256 + threadIdx.x;
  float4 a = in[i], b = in[plane4 + i], c = in[2 * plane4 + i], d = in[3 * plane4 + i];
  float4 s = csum4[i & 127];
  half4 h;
  h[0] = (_Float16)(a.x + b.x + c.x + d.x - s.x);
  h[1] = (_Float16)(a.y + b.y + c.y + d.y - s.y);
  h[2] = (_Float16)(a.z + b.z + c.z + d.z - s.z);
  h[3] = (_Float16)(a.w + b.w + c.w + d.w - s.w);
  *(half4*)(out16 + i * 4) = h;
}

// ---------------------------------------------------------------- stats combine
__global__ __launch_bounds__(256) void softmax_combine(
    const float* __restrict__ mx, const float* __restrict__ sm,
    float* __restrict__ rowm, float* __restrict__ rowinv)
{
  const int row = blockIdx.x * 4 + (threadIdx.x >> 6);
  const int lane = threadIdx.x & 63;
  float mt = mx[(size_t)row * 64 + lane];
  float m = mt;
#pragma unroll
  for (int off = 32; off; off >>= 1) m = fmaxf(m, __shfl_xor(m, off));
  float s = sm[(size_t)row * 64 + lane] * __expf(mt - m);
#pragma unroll
  for (int off = 32; off; off >>= 1) s += __shfl_xor(s, off);
  if (lane == 0) { rowm[row] = m; rowinv[row] = 1.0f / s; }
}

// ---------------------------------------------------------------- fused attn-write + PV
// A16=0: f32 absolute logits in-place. A16=1: f16 tile-relative logits in lin;
// per-(row,tile) maxes preloaded from mxbuf into LDS; attention f32 to attn_out.
template<int A16>
__global__ __launch_bounds__(512, 4) void pv_fused(
    const void* __restrict__ lin,        // logits (f32 abs or f16 tile-relative)
    float* __restrict__ attn_out,        // [8192][8192] attention out
    const _Float16* __restrict__ vT16,   // [512][8192] f16
    const float* __restrict__ rowm, const float* __restrict__ rowinv,
    const float* __restrict__ mxbuf,     // [8192][64] per-(row,tile) maxes
    _Float16* __restrict__ vals16)       // [4][8192][512] f16
{
  constexpr int BM = 64, BN = 512, BK = 32, NSTEP = 64;  // KC = 2048
  __shared__ _Float16 ldsA[2][BM][BK];   // 8 KB
  __shared__ _Float16 ldsB[2][BN][BK];   // 64 KB
  __shared__ float s_m[BM], s_inv[BM];
  __shared__ float s_mt[BM][16];         // 4 KB (A16 only): tile maxes for this kc

  const int tid = threadIdx.x, lane = tid & 63, wid = tid >> 6;
  const int wrow = wid >> 2, wcol = wid & 3;   // 2 x 4 waves
  const int l15 = lane & 15, g = lane >> 4;
  const int kc = blockIdx.x, brow = blockIdx.y * BM;
  const size_t kbase = (size_t)kc * 2048;

  const float*    lf32 = (const float*)lin;
  const _Float16* lf16 = (const _Float16*)lin;

  if (tid < BM) { s_m[tid] = rowm[brow + tid]; s_inv[tid] = rowinv[brow + tid]; }
  if constexpr (A16 == 1) {
#pragma unroll
    for (int i = 0; i < 2; ++i) {
      int idx = tid + i * 512;               // 1024 entries = 64 rows x 16 tiles
      int row = idx >> 4, t = idx & 15;
      s_mt[row][t] = mxbuf[(size_t)(brow + row) * 64 + kc * 16 + t];
    }
  }

  f32x4 acc[2][8];
#pragma unroll
  for (int mi = 0; mi < 2; ++mi)
#pragma unroll
    for (int ni = 0; ni < 8; ++ni) acc[mi][ni] = (f32x4){0.f, 0.f, 0.f, 0.f};

  const int arow = (tid & 255) >> 2, aci = tid & 3;
  float4 ra[2];
  half8 ra16;
  half8 rbh[4];

  auto loadA = [&](int kt) {
    if (tid < 256) {
      if constexpr (A16 == 1) {
        ra16 = *(const half8*)(lf16 + (size_t)(brow + arow) * 8192 + kbase + kt * BK + aci * 8);
      } else {
        const float4* p = (const float4*)(lf32 + (size_t)(brow + arow) * 8192 + kbase + kt * BK + aci * 8);
        ra[0] = p[0]; ra[1] = p[1];
      }
    }
  };
  auto loadB = [&](int kt) {
#pragma unroll
    for (int i = 0; i < 4; ++i) {
      int c = tid + 512 * i; int r = c >> 2, ci = c & 3;
      rbh[i] = *(const half8*)(vT16 + (size_t)r * 8192 + kbase + kt * BK + ci * 8);
    }
  };
  auto stage = [&](int kt, int b) {
    if (tid < 256) {
      const float m = s_m[arow], inv = s_inv[arow];
      float f[8];
      float madj;
      if constexpr (A16 == 1) {
        madj = s_mt[arow][kt >> 2] - m;      // (l - m_tile) + m_tile - m_row
#pragma unroll
        for (int j = 0; j < 8; ++j) f[j] = (float)ra16[j] + madj;
      } else {
#pragma unroll
        for (int j = 0; j < 4; ++j) { f[j] = (&ra[0].x)[j] - m; f[4 + j] = (&ra[1].x)[j] - m; }
      }
      float e[8]; half8 h;
#pragma unroll
      for (int j = 0; j < 8; ++j) {
        e[j] = __expf(f[j]) * inv;
        h[j] = (_Float16)e[j];
      }
      float4* w = (float4*)(attn_out + (size_t)(brow + arow) * 8192 + kbase + kt * BK + aci * 8);
      w[0] = make_float4(e[0], e[1], e[2], e[3]);
      w[1] = make_float4(e[4], e[5], e[6], e[7]);
      int off = arow * BK + ((aci ^ ((arow >> 1) & 3)) << 3);
      *(half8*)(&ldsA[b][0][0] + off) = h;
    }
#pragma unroll
    for (int i = 0; i < 4; ++i) {
      int c = tid + 512 * i; int r = c >> 2, ci = c & 3;
      int off2 = r * BK + ((ci ^ ((r >> 1) & 3)) << 3);
      *(half8*)(&ldsB[b][0][0] + off2) = rbh[i];
    }
  };

  loadA(0); loadB(0);
  __syncthreads();            // s_m / s_inv / s_mt visible
  stage(0, 0);
  loadA(1); loadB(1);
  __syncthreads();            // buf0 staged

  for (int kt = 0; kt < NSTEP; ++kt) {
    const int cur = kt & 1, nxt = cur ^ 1;
    if (kt + 1 < NSTEP) stage(kt + 1, nxt);
    if (kt + 2 < NSTEP) { loadA(kt + 2); loadB(kt + 2); }
    half8 af[2];
#pragma unroll
    for (int mi = 0; mi < 2; ++mi) {
      int row = wrow * 32 + mi * 16 + l15;
      af[mi] = *(const half8*)(&ldsA[cur][0][0] + row * BK + ((g ^ ((row >> 1) & 3)) << 3));
    }
    __builtin_amdgcn_s_setprio(1);
#pragma unroll
    for (int ni = 0; ni < 8; ++ni) {
      int rn = wcol * 128 + ni * 16 + l15;
      half8 bf = *(const half8*)(&ldsB[cur][0][0] + rn * BK + ((g ^ ((rn >> 1) & 3)) << 3));
#pragma unroll
      for (int mi = 0; mi < 2; ++mi)
        acc[mi][ni] = __builtin_amdgcn_mfma_f32_16x16x32_f16(af[mi], bf, acc[mi][ni], 0, 0, 0);
    }
    __builtin_amdgcn_s_setprio(0);
    __syncthreads();
  }

  const size_t plane = (size_t)8192 * 512;
#pragma unroll
  for (int mi = 0; mi < 2; ++mi)
#pragma unroll
    for (int ni = 0; ni < 8; ++ni) {
      int col = wcol * 128 + ni * 16 + l15;
#pragma unroll
      for (int j = 0; j < 4; ++j) {
        int row = brow + wrow * 32 + mi * 16 + g * 4 + j;
        vals16[(size_t)kc * plane + (size_t)row * 512 + col] = (_Float16)acc[mi][ni][j];
      }
    }
}

// ---------------------------------------------------------------- launch
extern "C" void kernel_launch(void* const* d_in, const int* in_sizes, int n_in,
                              void* d_out, int out_size, void* d_ws, size_t ws_size,
                              hipStream_t stream)
{
  const float* x    = (const float*)d_in[0];
  const float* Amat = (const float*)d_in[1];
  const float* Wqkv = (const float*)d_in[2];
  const float* bqkv = (const float*)d_in[3];
  const float* Wo   = (const float*)d_in[4];
  const float* bo   = (const float*)d_in[5];

  float* o    = (float*)d_out;                       // [8192,512]
  float* attn = (float*)d_out + (size_t)8192 * 512;  // [8192,8192]

  float* ws = (float*)d_ws;
  _Float16*  vals16 = (_Float16*)ws;              // [4][8192][512] f16 (33.5 MB)
  _Float16*  qkv16  = (_Float16*)(ws + 8388608);  // [8192][1536] f16; q view (lda 1536)
  _Float16*  k0T16  = (_Float16*)(ws + 14680064); // [512][8192] f16
  _Float16*  vT16   = (_Float16*)(ws + 16777216); // [512][8192] f16
  _Float16*  W16T   = (_Float16*)(ws + 18874368); // [1536][512] f16
  float*     WoT    = ws + 19660800;              // [512][512] f32
  _Float16*  kbuf16 = (_Float16*)(ws + 19922944); // [8192][512] f16
  float*     mx     = ws + 24117248;
  float*     sm     = ws + 24641536;
  float*     rowm   = ws + 25165824;
  float*     rowinv = ws + 25174016;
  float*     csum   = ws + 25182208;
  _Float16*  attn16 = (_Float16*)(ws + 25184256); // [8192][8192] f16 (134 MB, big-ws only)
  float*     kpart  = attn;                       // d_out attn region pre-K3
  _Float16*  x16    = (_Float16*)attn;            // x f16 (dead before kpart use)

  const bool bigws = ws_size >= (size_t)(25184256 + 33554432) * 4;

  const dim3 b256(256), b512(512);
  const float qk_scale = 0.04419417382415922f;  // 1/sqrt(512)
  const size_t plane = (size_t)8192 * 512;      // 4,194,304

  conv_f32_f16<<<dim3(4096), b256, 0, stream>>>((const float4*)x, x16);
  transpose_f32_f16<<<dim3(48, 16), b256, 0, stream>>>(Wqkv, 1536, W16T, 512);
  transpose_f32<<<dim3(16, 16), b256, 0, stream>>>(Wo, 512, WoT, 512);

  // K1: qkv16 = f16(x @ Wqkv + bqkv)
  gemm_bt<1, 1, 128, 128, 2, 2, 256, 1, false, 2, 4, 3, 3>
      <<<dim3(12, 64), b256, 0, stream>>>(
      x16, 512, 0, W16T, 512, 0, nullptr, 1536, 0, bqkv, 512, 1.0f, qkv16);

  transpose_f16<<<dim3(8, 128), b256, 0, stream>>>(qkv16 + 512, 1536, k0T16, 8192);
  transpose_f16<<<dim3(8, 128), b256, 0, stream>>>(qkv16 + 1024, 1536, vT16, 8192);
  halfcolsum16<<<dim3(512), b256, 0, stream>>>(k0T16, csum);

  // K2: k = A @ k0, split-K 4. MINW=4 (6 caused acc scratch-spill, round 12).
  gemm_bt<1, 1, 128, 256, 2, 4, 512, 1, true, 0, 4, 0, 3>
      <<<dim3(2, 64, 4), b512, 0, stream>>>(
      Amat, 8192, 0, k0T16, 8192, 0, kpart, 512, plane, nullptr, 2048, 1.0f, nullptr);

  reduce4_f16<<<dim3(4096), b256, 0, stream>>>((const float4*)kpart, kbuf16, plane / 4,
                                               (const float4*)csum);

  if (bigws) {
    // K3: f16 TILE-RELATIVE logits -> attn16 (134 MB, L3-resident) + stats
    gemm_ff16<128, 128, 256, true, 4, 1>
        <<<dim3(4096), b256, 0, stream>>>(
        qkv16, 1536, kbuf16, 512, nullptr, attn16, 8192, 512, qk_scale, mx, sm, 64);
    softmax_combine<<<dim3(2048), b256, 0, stream>>>(mx, sm, rowm, rowinv);
    pv_fused<1><<<dim3(4, 128), b512, 0, stream>>>(
        attn16, attn, vT16, rowm, rowinv, mx, vals16);
  } else {
    // fallback: f32 logits in-place (round-15 verified path)
    gemm_ff16<128, 128, 256, true, 4, 0>
        <<<dim3(4096), b256, 0, stream>>>(
        qkv16, 1536, kbuf16, 512, attn, nullptr, 8192, 512, qk_scale, mx, sm, 64);
    softmax_combine<<<dim3(2048), b256, 0, stream>>>(mx, sm, rowm, rowinv);
    pv_fused<0><<<dim3(4, 128), b512, 0, stream>>>(
        attn, attn, vT16, rowm, rowinv, nullptr, vals16);
  }

  // K6: o = (sum of 4 f16 vals partials) @ Wo + bo
  gemm_bt<1, 1, 128, 128, 2, 2, 256, 4, false, 0, 3, 1, 0>
      <<<dim3(4, 64), b256, 0, stream>>>(
      vals16, 512, plane, WoT, 512, 0, o, 512, 0, bo, 512, 1.0f, nullptr);
}

// Round 18
// 537.205 us; speedup vs baseline: 2.3135x; 1.0189x over previous
//
#include <hip/hip_runtime.h>

typedef _Float16 half8 __attribute__((ext_vector_type(8)));
typedef _Float16 half4 __attribute__((ext_vector_type(4)));
typedef float f32x4 __attribute__((ext_vector_type(4)));

// ---------------------------------------------------------------- transpose (f32)
__global__ __launch_bounds__(256) void transpose_f32(
    const float* __restrict__ in, int lda,
    float* __restrict__ out, int ldo)
{
  __shared__ float t[32][33];
  const int tx = threadIdx.x & 31, ty = threadIdx.x >> 5;
  const int bc = blockIdx.x * 32, br = blockIdx.y * 32;
#pragma unroll
  for (int i = 0; i < 4; ++i)
    t[ty + 8 * i][tx] = in[(size_t)(br + ty + 8 * i) * lda + bc + tx];
  __syncthreads();
#pragma unroll
  for (int i = 0; i < 4; ++i)
    out[(size_t)(bc + ty + 8 * i) * ldo + br + tx] = t[tx][ty + 8 * i];
}

// transpose with f32 -> f16 convert on output (weights)
__global__ __launch_bounds__(256) void transpose_f32_f16(
    const float* __restrict__ in, int lda,
    _Float16* __restrict__ out, int ldo)
{
  __shared__ float t[32][33];
  const int tx = threadIdx.x & 31, ty = threadIdx.x >> 5;
  const int bc = blockIdx.x * 32, br = blockIdx.y * 32;
#pragma unroll
  for (int i = 0; i < 4; ++i)
    t[ty + 8 * i][tx] = in[(size_t)(br + ty + 8 * i) * lda + bc + tx];
  __syncthreads();
#pragma unroll
  for (int i = 0; i < 4; ++i)
    out[(size_t)(bc + ty + 8 * i) * ldo + br + tx] = (_Float16)t[tx][ty + 8 * i];
}

// f16 -> f16 transpose, 64x64 tile
__global__ __launch_bounds__(256) void transpose_f16(
    const _Float16* __restrict__ in, int lda,
    _Float16* __restrict__ out, int ldo)
{
  __shared__ _Float16 t[64][66];
  const int tx = threadIdx.x & 63, ty = threadIdx.x >> 6;   // 64 x 4
  const int bc = blockIdx.x * 64, br = blockIdx.y * 64;
#pragma unroll
  for (int i = 0; i < 16; ++i)
    t[ty + 4 * i][tx] = in[(size_t)(br + ty + 4 * i) * lda + bc + tx];
  __syncthreads();
#pragma unroll
  for (int i = 0; i < 16; ++i)
    out[(size_t)(bc + ty + 4 * i) * ldo + br + tx] = t[tx][ty + 4 * i];
}

// ---------------------------------------------------------------- half column-sum (f16 input)
__global__ __launch_bounds__(256) void halfcolsum16(
    const _Float16* __restrict__ k0T16, float* __restrict__ csum)
{
  const int d = blockIdx.x, tid = threadIdx.x;
  float s = 0.f;
#pragma unroll
  for (int i = 0; i < 4; ++i) {
    half8 h = *(const half8*)(k0T16 + (size_t)d * 8192 + i * 2048 + tid * 8);
#pragma unroll
    for (int j = 0; j < 8; ++j) s += (float)h[j];
  }
#pragma unroll
  for (int off = 32; off; off >>= 1) s += __shfl_xor(s, off);
  __shared__ float r[4];
  if ((tid & 63) == 0) r[tid >> 6] = s;
  __syncthreads();
  if (tid == 0) csum[d] = 0.5f * ((r[0] + r[1]) + (r[2] + r[3]));
}

// ---------------------------------------------------------------- GEMM (BT)
// AMODE: 0 = f32 A (cvt in staging; ASPL=1 -> single-pass), 1 = f16 A summed,
//        3 = f16 single plane A (pure copy)
// BMODE: 0 = f32 B, 3 = f16 single plane B (pure copy)
// CMODE: 0 = f32 C store; 2 = f16 C store to c16out (KSPLIT offsets c16out)
template<int ASPL,int BSPL,int BM,int BN,int WAVES_M,int WAVES_N,int THREADS,
         int APART,bool KSPLIT,int CMODE,int MINW,int AMODE,int BMODE>
__global__ __launch_bounds__(THREADS, MINW) void gemm_bt(
    const void* __restrict__ Agv, int lda, size_t a_plane,
    const void* __restrict__ Bgv, int ldb, size_t b_plane,
    float* __restrict__ Cg, int ldc, size_t c_plane,
    const float* __restrict__ bias, int K, float scale,
    _Float16* __restrict__ c16out)
{
  constexpr int BK = 32;
  constexpr int WM = BM / WAVES_M, WN = BN / WAVES_N;
  constexpr int FM = WM / 16, FN = WN / 16;
  constexpr int NCA = (BM * 4) / THREADS;
  constexpr int NCB = (BN * 4) / THREADS;
  static_assert((BM * 4) % THREADS == 0 && (BN * 4) % THREADS == 0, "mismatch");
  static_assert(AMODE != 3 || ASPL == 1, "AMODE 3 needs ASPL 1");

  __shared__ _Float16 ldsA[2][ASPL][BM][BK];
  __shared__ _Float16 ldsB[2][BSPL][BN][BK];

  const float*    Ag   = (const float*)Agv;
  const _Float16* Ag16 = (const _Float16*)Agv;
  const float*    Bg   = (const float*)Bgv;
  const _Float16* Bg16 = (const _Float16*)Bgv;

  const int tid  = threadIdx.x;
  const int lane = tid & 63;
  const int wid  = tid >> 6;
  const int wrow = wid / WAVES_N, wcol = wid % WAVES_N;
  const int l15  = lane & 15, g = lane >> 4;
  const int brow = blockIdx.y * BM;
  const int bcol = blockIdx.x * BN;

  if constexpr (KSPLIT) {
    const int kc = blockIdx.z;
    Ag += (size_t)kc * K;  Ag16 += (size_t)kc * K;
    Bg += (size_t)kc * K;  Bg16 += (size_t)kc * K;
    Cg += (size_t)kc * c_plane;
    if constexpr (CMODE == 2) c16out += (size_t)kc * c_plane;
  }

  f32x4 acc[FM][FN];
#pragma unroll
  for (int mi = 0; mi < FM; ++mi)
#pragma unroll
    for (int ni = 0; ni < FN; ++ni)
      acc[mi][ni] = (f32x4){0.f, 0.f, 0.f, 0.f};

  float4 ra[NCA][2], rb[NCB][2];
  half8  rah[NCA], rbh[NCB];

  auto loadAB = [&](int kt) {
    const int k0 = kt * BK;
#pragma unroll
    for (int i = 0; i < NCA; ++i) {
      int c = tid + THREADS * i;
      int row = c >> 2, ci = c & 3;
      if constexpr (AMODE == 3) {
        rah[i] = *(const half8*)(Ag16 + (size_t)(brow + row) * lda + k0 + ci * 8);
      } else if constexpr (AMODE == 1) {
        float4 u0 = make_float4(0.f, 0.f, 0.f, 0.f);
        float4 u1 = make_float4(0.f, 0.f, 0.f, 0.f);
        const _Float16* bp = Ag16 + (size_t)(brow + row) * lda + k0 + ci * 8;
#pragma unroll
        for (int p = 0; p < APART; ++p) {
          half8 hv = *(const half8*)(bp + (size_t)p * a_plane);
          u0.x += (float)hv[0]; u0.y += (float)hv[1]; u0.z += (float)hv[2]; u0.w += (float)hv[3];
          u1.x += (float)hv[4]; u1.y += (float)hv[5]; u1.z += (float)hv[6]; u1.w += (float)hv[7];
        }
        ra[i][0] = u0; ra[i][1] = u1;
      } else {
        const float* bp = Ag + (size_t)(brow + row) * lda + k0 + ci * 8;
        float4 u0 = ((const float4*)bp)[0];
        float4 u1 = ((const float4*)bp)[1];
#pragma unroll
        for (int p = 1; p < APART; ++p) {
          const float* pp = bp + (size_t)p * a_plane;
          float4 w0 = ((const float4*)pp)[0], w1 = ((const float4*)pp)[1];
          u0.x += w0.x; u0.y += w0.y; u0.z += w0.z; u0.w += w0.w;
          u1.x += w1.x; u1.y += w1.y; u1.z += w1.z; u1.w += w1.w;
        }
        ra[i][0] = u0; ra[i][1] = u1;
      }
    }
#pragma unroll
    for (int i = 0; i < NCB; ++i) {
      int c = tid + THREADS * i;
      int row = c >> 2, ci = c & 3;
      if constexpr (BMODE == 3) {
        rbh[i] = *(const half8*)(Bg16 + (size_t)(bcol + row) * ldb + k0 + ci * 8);
      } else {
        const float4* p = (const float4*)(Bg + (size_t)(bcol + row) * ldb + k0 + ci * 8);
        rb[i][0] = p[0]; rb[i][1] = p[1];
      }
    }
  };

  auto stageLDS = [&](int b) {
#pragma unroll
    for (int i = 0; i < NCA; ++i) {
      int c = tid + THREADS * i;
      int row = c >> 2, ci = c & 3;
      int off = row * BK + ((ci ^ ((row >> 1) & 3)) << 3);
      if constexpr (AMODE == 3) {
        *(half8*)(&ldsA[b][0][0][0] + off) = rah[i];
      } else {
        float f[8] = {ra[i][0].x, ra[i][0].y, ra[i][0].z, ra[i][0].w,
                      ra[i][1].x, ra[i][1].y, ra[i][1].z, ra[i][1].w};
        half8 h, l;
#pragma unroll
        for (int j = 0; j < 8; ++j) {
          _Float16 hv = (_Float16)f[j];
          h[j] = hv;
          if (ASPL == 2) l[j] = (_Float16)(f[j] - (float)hv);
        }
        *(half8*)(&ldsA[b][0][0][0] + off) = h;
        if (ASPL == 2) *(half8*)(&ldsA[b][1][0][0] + off) = l;
      }
    }
#pragma unroll
    for (int i = 0; i < NCB; ++i) {
      int c = tid + THREADS * i;
      int row = c >> 2, ci = c & 3;
      int off = row * BK + ((ci ^ ((row >> 1) & 3)) << 3);
      if constexpr (BMODE == 3) {
        *(half8*)(&ldsB[b][0][0][0] + off) = rbh[i];
      } else {
        float f[8] = {rb[i][0].x, rb[i][0].y, rb[i][0].z, rb[i][0].w,
                      rb[i][1].x, rb[i][1].y, rb[i][1].z, rb[i][1].w};
        half8 h, l;
#pragma unroll
        for (int j = 0; j < 8; ++j) {
          _Float16 hv = (_Float16)f[j];
          h[j] = hv;
          if (BSPL == 2) l[j] = (_Float16)(f[j] - (float)hv);
        }
        *(half8*)(&ldsB[b][0][0][0] + off) = h;
        if (BSPL == 2) *(half8*)(&ldsB[b][1][0][0] + off) = l;
      }
    }
  };

  const int nk = K / BK;
  loadAB(0);
  stageLDS(0);
  if (nk > 1) loadAB(1);
  __syncthreads();

  for (int kt = 0; kt < nk; ++kt) {
    const int cur = kt & 1, nxt = cur ^ 1;
    if (kt + 1 < nk) stageLDS(nxt);
    if (kt + 2 < nk) loadAB(kt + 2);

    half8 af[FM][ASPL];
#pragma unroll
    for (int mi = 0; mi < FM; ++mi)
#pragma unroll
      for (int sa = 0; sa < ASPL; ++sa) {
        int row = wrow * WM + mi * 16 + l15;
        af[mi][sa] = *(const half8*)(&ldsA[cur][sa][0][0] + row * BK + ((g ^ ((row >> 1) & 3)) << 3));
      }
#pragma unroll
    for (int ni = 0; ni < FN; ++ni) {
      half8 bf[BSPL];
#pragma unroll
      for (int sb = 0; sb < BSPL; ++sb) {
        int row = wcol * WN + ni * 16 + l15;
        bf[sb] = *(const half8*)(&ldsB[cur][sb][0][0] + row * BK + ((g ^ ((row >> 1) & 3)) << 3));
      }
#pragma unroll
      for (int mi = 0; mi < FM; ++mi)
#pragma unroll
        for (int sa = 0; sa < ASPL; ++sa)
#pragma unroll
          for (int sb = 0; sb < BSPL; ++sb) {
            if (ASPL == 2 && BSPL == 2 && sa == 1 && sb == 1) continue;
            acc[mi][ni] = __builtin_amdgcn_mfma_f32_16x16x32_f16(af[mi][sa], bf[sb], acc[mi][ni], 0, 0, 0);
          }
    }
    __syncthreads();
  }

#pragma unroll
  for (int mi = 0; mi < FM; ++mi)
#pragma unroll
    for (int ni = 0; ni < FN; ++ni) {
      int col = bcol + wcol * WN + ni * 16 + l15;
      float bv = bias ? bias[col] : 0.f;
#pragma unroll
      for (int j = 0; j < 4; ++j) {
        int r = brow + wrow * WM + mi * 16 + g * 4 + j;
        float v = acc[mi][ni][j] * scale + bv;
        if constexpr (CMODE == 2) {
          c16out[(size_t)r * ldc + col] = (_Float16)v;   // f16-only C
        } else {
          Cg[(size_t)r * ldc + col] = v;
        }
      }
    }
}

// ---------------------------------------------------------------- GEMM f16 x f16 (K3)
// XCD-bijective 1-D swizzle. CM: 0 = f32 absolute logits; 1 = f16 logits stored
// RELATIVE to per-(row,128-tile) max (values <= 0; near-max entries tiny ulp).
template<int BM,int BN,int THREADS,bool STATS,int MINW,int CM>
__global__ __launch_bounds__(THREADS, MINW) void gemm_ff16(
    const _Float16* __restrict__ Ag, int lda,
    const _Float16* __restrict__ Bg, int ldb,
    float* __restrict__ Cg, _Float16* __restrict__ Cg16, int ldc,
    int K, float scale,
    float* __restrict__ mxout, float* __restrict__ smout, int ntiles)
{
  constexpr int BK = 32;
  constexpr int WAVES_M = 2, WAVES_N = 2;
  constexpr int WM = BM / WAVES_M, WN = BN / WAVES_N;
  constexpr int FM = WM / 16, FN = WN / 16;
  constexpr int NCA = (BM * 4) / THREADS;
  constexpr int NCB = (BN * 4) / THREADS;

  __shared__ _Float16 ldsA[2][BM][BK];
  __shared__ _Float16 ldsB[2][BN][BK];

  const int tid  = threadIdx.x;
  const int lane = tid & 63;
  const int wid  = tid >> 6;
  const int wrow = wid >> 1, wcol = wid & 1;
  const int l15  = lane & 15, g = lane >> 4;

  const int id = blockIdx.x;                 // 0..4095
  const int wgid = (id & 7) * 512 + (id >> 3);
  const int bxv = wgid & 63, byv = wgid >> 6;
  const int brow = byv * BM;
  const int bcol = bxv * BN;

  f32x4 acc[FM][FN];
#pragma unroll
  for (int mi = 0; mi < FM; ++mi)
#pragma unroll
    for (int ni = 0; ni < FN; ++ni)
      acc[mi][ni] = (f32x4){0.f, 0.f, 0.f, 0.f};

  half8 ra[NCA], rb[NCB];

  auto loadAB = [&](int kt) {
    const int k0 = kt * BK;
#pragma unroll
    for (int i = 0; i < NCA; ++i) {
      int c = tid + THREADS * i;
      int row = c >> 2, ci = c & 3;
      ra[i] = *(const half8*)(Ag + (size_t)(brow + row) * lda + k0 + ci * 8);
    }
#pragma unroll
    for (int i = 0; i < NCB; ++i) {
      int c = tid + THREADS * i;
      int row = c >> 2, ci = c & 3;
      rb[i] = *(const half8*)(Bg + (size_t)(bcol + row) * ldb + k0 + ci * 8);
    }
  };

  auto stageLDS = [&](int b) {
#pragma unroll
    for (int i = 0; i < NCA; ++i) {
      int c = tid + THREADS * i;
      int row = c >> 2, ci = c & 3;
      int off = row * BK + ((ci ^ ((row >> 1) & 3)) << 3);
      *(half8*)(&ldsA[b][0][0] + off) = ra[i];
    }
#pragma unroll
    for (int i = 0; i < NCB; ++i) {
      int c = tid + THREADS * i;
      int row = c >> 2, ci = c & 3;
      int off = row * BK + ((ci ^ ((row >> 1) & 3)) << 3);
      *(half8*)(&ldsB[b][0][0] + off) = rb[i];
    }
  };

  const int nk = K / BK;
  loadAB(0);
  stageLDS(0);
  if (nk > 1) loadAB(1);
  __syncthreads();

  for (int kt = 0; kt < nk; ++kt) {
    const int cur = kt & 1, nxt = cur ^ 1;
    if (kt + 1 < nk) stageLDS(nxt);
    if (kt + 2 < nk) loadAB(kt + 2);

    half8 af[FM];
#pragma unroll
    for (int mi = 0; mi < FM; ++mi) {
      int row = wrow * WM + mi * 16 + l15;
      af[mi] = *(const half8*)(&ldsA[cur][0][0] + row * BK + ((g ^ ((row >> 1) & 3)) << 3));
    }
#pragma unroll
    for (int ni = 0; ni < FN; ++ni) {
      int row = wcol * WN + ni * 16 + l15;
      half8 bf = *(const half8*)(&ldsB[cur][0][0] + row * BK + ((g ^ ((row >> 1) & 3)) << 3));
#pragma unroll
      for (int mi = 0; mi < FM; ++mi)
        acc[mi][ni] = __builtin_amdgcn_mfma_f32_16x16x32_f16(af[mi], bf, acc[mi][ni], 0, 0, 0);
    }
    __syncthreads();
  }

  if constexpr (CM == 0) {
#pragma unroll
    for (int mi = 0; mi < FM; ++mi)
#pragma unroll
      for (int ni = 0; ni < FN; ++ni) {
        int col = bcol + wcol * WN + ni * 16 + l15;
#pragma unroll
        for (int j = 0; j < 4; ++j) {
          int r = brow + wrow * WM + mi * 16 + g * 4 + j;
          Cg[(size_t)r * ldc + col] = acc[mi][ni][j] * scale;
        }
      }
  }

  if constexpr (STATS) {
    __shared__ float s_m2[BM][2];
    __shared__ float s_s2[BM][2];
#pragma unroll
    for (int mi = 0; mi < FM; ++mi)
#pragma unroll
      for (int j = 0; j < 4; ++j) {
        float v = -3.4e38f;
#pragma unroll
        for (int ni = 0; ni < FN; ++ni) v = fmaxf(v, acc[mi][ni][j] * scale);
        v = fmaxf(v, __shfl_xor(v, 1)); v = fmaxf(v, __shfl_xor(v, 2));
        v = fmaxf(v, __shfl_xor(v, 4)); v = fmaxf(v, __shfl_xor(v, 8));
        if (l15 == 0) s_m2[wrow * WM + mi * 16 + g * 4 + j][wcol] = v;
      }
    __syncthreads();
#pragma unroll
    for (int mi = 0; mi < FM; ++mi)
#pragma unroll
      for (int j = 0; j < 4; ++j) {
        int r = wrow * WM + mi * 16 + g * 4 + j;
        float mt = fmaxf(s_m2[r][0], s_m2[r][1]);
        float s = 0.f;
#pragma unroll
        for (int ni = 0; ni < FN; ++ni) {
          float lv = acc[mi][ni][j] * scale - mt;   // <= 0 by construction
          s += __expf(lv);
          if constexpr (CM == 1) {
            int col = bcol + wcol * WN + ni * 16 + l15;
            Cg16[(size_t)(brow + r) * ldc + col] = (_Float16)lv;
          }
        }
        s += __shfl_xor(s, 1); s += __shfl_xor(s, 2);
        s += __shfl_xor(s, 4); s += __shfl_xor(s, 8);
        if (l15 == 0) s_s2[r][wcol] = s;
      }
    __syncthreads();
    if (tid < BM) {
      float mt = fmaxf(s_m2[tid][0], s_m2[tid][1]);
      float st = s_s2[tid][0] + s_s2[tid][1];
      mxout[(size_t)(brow + tid) * ntiles + bxv] = mt;
      smout[(size_t)(brow + tid) * ntiles + bxv] = st;
    }
  }
}

// ---------------------------------------------------------------- reduce 4 f16 planes -> f16
__global__ __launch_bounds__(256) void reduce4_f16in(
    const _Float16* __restrict__ in, _Float16* __restrict__ out16, size_t planeE,
    const float* __restrict__ csum)
{
  size_t i = ((size_t)blockIdx.x * 256 + threadIdx.x) * 8;
  half8 a = *(const half8*)(in + i);
  half8 b = *(const half8*)(in + planeE + i);
  half8 c = *(const half8*)(in + 2 * planeE + i);
  half8 d = *(const half8*)(in + 3 * planeE + i);
  const int col = (int)(i & 511);
  half8 h;
#pragma unroll
  for (int j = 0; j < 8; ++j) {
    float s = ((float)a[j] + (float)b[j]) + ((float)c[j] + (float)d[j]) - csum[col + j];
    h[j] = (_Float16)s;
  }
  *(half8*)(out16 + i) = h;
}

// ---------------------------------------------------------------- stats combine
__global__ __launch_bounds__(256) void softmax_combine(
    const float* __restrict__ mx, const float* __restrict__ sm,
    float* __restrict__ rowm, float* __restrict__ rowinv)
{
  const int row = blockIdx.x * 4 + (threadIdx.x >> 6);
  const int lane = threadIdx.x & 63;
  float mt = mx[(size_t)row * 64 + lane];
  float m = mt;
#pragma unroll
  for (int off = 32; off; off >>= 1) m = fmaxf(m, __shfl_xor(m, off));
  float s = sm[(size_t)row * 64 + lane] * __expf(mt - m);
#pragma unroll
  for (int off = 32; off; off >>= 1) s += __shfl_xor(s, off);
  if (lane == 0) { rowm[row] = m; rowinv[row] = 1.0f / s; }
}

// ---------------------------------------------------------------- fused attn-write + PV
// A16=0: f32 absolute logits in-place. A16=1: f16 tile-relative logits in lin;
// per-(row,tile) maxes preloaded from mxbuf into LDS; attention f32 to attn_out.
template<int A16>
__global__ __launch_bounds__(512, 4) void pv_fused(
    const void* __restrict__ lin,        // logits (f32 abs or f16 tile-relative)
    float* __restrict__ attn_out,        // [8192][8192] attention out
    const _Float16* __restrict__ vT16,   // [512][8192] f16
    const float* __restrict__ rowm, const float* __restrict__ rowinv,
    const float* __restrict__ mxbuf,     // [8192][64] per-(row,tile) maxes
    _Float16* __restrict__ vals16)       // [4][8192][512] f16
{
  constexpr int BM = 64, BN = 512, BK = 32, NSTEP = 64;  // KC = 2048
  __shared__ _Float16 ldsA[2][BM][BK];   // 8 KB
  __shared__ _Float16 ldsB[2][BN][BK];   // 64 KB
  __shared__ float s_m[BM], s_inv[BM];
  __shared__ float s_mt[BM][16];         // 4 KB (A16 only): tile maxes for this kc

  const int tid = threadIdx.x, lane = tid & 63, wid = tid >> 6;
  const int wrow = wid >> 2, wcol = wid & 3;   // 2 x 4 waves
  const int l15 = lane & 15, g = lane >> 4;
  const int kc = blockIdx.x, brow = blockIdx.y * BM;
  const size_t kbase = (size_t)kc * 2048;

  const float*    lf32 = (const float*)lin;
  const _Float16* lf16 = (const _Float16*)lin;

  if (tid < BM) { s_m[tid] = rowm[brow + tid]; s_inv[tid] = rowinv[brow + tid]; }
  if constexpr (A16 == 1) {
#pragma unroll
    for (int i = 0; i < 2; ++i) {
      int idx = tid + i * 512;               // 1024 entries = 64 rows x 16 tiles
      int row = idx >> 4, t = idx & 15;
      s_mt[row][t] = mxbuf[(size_t)(brow + row) * 64 + kc * 16 + t];
    }
  }

  f32x4 acc[2][8];
#pragma unroll
  for (int mi = 0; mi < 2; ++mi)
#pragma unroll
    for (int ni = 0; ni < 8; ++ni) acc[mi][ni] = (f32x4){0.f, 0.f, 0.f, 0.f};

  const int arow = (tid & 255) >> 2, aci = tid & 3;
  float4 ra[2];
  half8 ra16;
  half8 rbh[4];

  auto loadA = [&](int kt) {
    if (tid < 256) {
      if constexpr (A16 == 1) {
        ra16 = *(const half8*)(lf16 + (size_t)(brow + arow) * 8192 + kbase + kt * BK + aci * 8);
      } else {
        const float4* p = (const float4*)(lf32 + (size_t)(brow + arow) * 8192 + kbase + kt * BK + aci * 8);
        ra[0] = p[0]; ra[1] = p[1];
      }
    }
  };
  auto loadB = [&](int kt) {
#pragma unroll
    for (int i = 0; i < 4; ++i) {
      int c = tid + 512 * i; int r = c >> 2, ci = c & 3;
      rbh[i] = *(const half8*)(vT16 + (size_t)r * 8192 + kbase + kt * BK + ci * 8);
    }
  };
  auto stage = [&](int kt, int b) {
    if (tid < 256) {
      const float m = s_m[arow], inv = s_inv[arow];
      float f[8];
      float madj;
      if constexpr (A16 == 1) {
        madj = s_mt[arow][kt >> 2] - m;      // (l - m_tile) + m_tile - m_row
#pragma unroll
        for (int j = 0; j < 8; ++j) f[j] = (float)ra16[j] + madj;
      } else {
#pragma unroll
        for (int j = 0; j < 4; ++j) { f[j] = (&ra[0].x)[j] - m; f[4 + j] = (&ra[1].x)[j] - m; }
      }
      float e[8]; half8 h;
#pragma unroll
      for (int j = 0; j < 8; ++j) {
        e[j] = __expf(f[j]) * inv;
        h[j] = (_Float16)e[j];
      }
      float4* w = (float4*)(attn_out + (size_t)(brow + arow) * 8192 + kbase + kt * BK + aci * 8);
      w[0] = make_float4(e[0], e[1], e[2], e[3]);
      w[1] = make_float4(e[4], e[5], e[6], e[7]);
      int off = arow * BK + ((aci ^ ((arow >> 1) & 3)) << 3);
      *(half8*)(&ldsA[b][0][0] + off) = h;
    }
#pragma unroll
    for (int i = 0; i < 4; ++i) {
      int c = tid + 512 * i; int r = c >> 2, ci = c & 3;
      int off2 = r * BK + ((ci ^ ((r >> 1) & 3)) << 3);
      *(half8*)(&ldsB[b][0][0] + off2) = rbh[i];
    }
  };

  loadA(0); loadB(0);
  __syncthreads();            // s_m / s_inv / s_mt visible
  stage(0, 0);
  loadA(1); loadB(1);
  __syncthreads();            // buf0 staged

  for (int kt = 0; kt < NSTEP; ++kt) {
    const int cur = kt & 1, nxt = cur ^ 1;
    if (kt + 1 < NSTEP) stage(kt + 1, nxt);
    if (kt + 2 < NSTEP) { loadA(kt + 2); loadB(kt + 2); }
    half8 af[2];
#pragma unroll
    for (int mi = 0; mi < 2; ++mi) {
      int row = wrow * 32 + mi * 16 + l15;
      af[mi] = *(const half8*)(&ldsA[cur][0][0] + row * BK + ((g ^ ((row >> 1) & 3)) << 3));
    }
    __builtin_amdgcn_s_setprio(1);
#pragma unroll
    for (int ni = 0; ni < 8; ++ni) {
      int rn = wcol * 128 + ni * 16 + l15;
      half8 bf = *(const half8*)(&ldsB[cur][0][0] + rn * BK + ((g ^ ((rn >> 1) & 3)) << 3));
#pragma unroll
      for (int mi = 0; mi < 2; ++mi)
        acc[mi][ni] = __builtin_amdgcn_mfma_f32_16x16x32_f16(af[mi], bf, acc[mi][ni], 0, 0, 0);
    }
    __builtin_amdgcn_s_setprio(0);
    __syncthreads();
  }

  const size_t plane = (size_t)8192 * 512;
#pragma unroll
  for (int mi = 0; mi < 2; ++mi)
#pragma unroll
    for (int ni = 0; ni < 8; ++ni) {
      int col = wcol * 128 + ni * 16 + l15;
#pragma unroll
      for (int j = 0; j < 4; ++j) {
        int row = brow + wrow * 32 + mi * 16 + g * 4 + j;
        vals16[(size_t)kc * plane + (size_t)row * 512 + col] = (_Float16)acc[mi][ni][j];
      }
    }
}

// ---------------------------------------------------------------- launch
extern "C" void kernel_launch(void* const* d_in, const int* in_sizes, int n_in,
                              void* d_out, int out_size, void* d_ws, size_t ws_size,
                              hipStream_t stream)
{
  const float* x    = (const float*)d_in[0];
  const float* Amat = (const float*)d_in[1];
  const float* Wqkv = (const float*)d_in[2];
  const float* bqkv = (const float*)d_in[3];
  const float* Wo   = (const float*)d_in[4];
  const float* bo   = (const float*)d_in[5];

  float* o    = (float*)d_out;                       // [8192,512]
  float* attn = (float*)d_out + (size_t)8192 * 512;  // [8192,8192]

  float* ws = (float*)d_ws;
  _Float16*  vals16 = (_Float16*)ws;              // [4][8192][512] f16 (33.5 MB)
  _Float16*  qkv16  = (_Float16*)(ws + 8388608);  // [8192][1536] f16; q view (lda 1536)
  _Float16*  k0T16  = (_Float16*)(ws + 14680064); // [512][8192] f16
  _Float16*  vT16   = (_Float16*)(ws + 16777216); // [512][8192] f16
  _Float16*  W16T   = (_Float16*)(ws + 18874368); // [1536][512] f16
  float*     WoT    = ws + 19660800;              // [512][512] f32
  _Float16*  kbuf16 = (_Float16*)(ws + 19922944); // [8192][512] f16
  float*     mx     = ws + 24117248;
  float*     sm     = ws + 24641536;
  float*     rowm   = ws + 25165824;
  float*     rowinv = ws + 25174016;
  float*     csum   = ws + 25182208;
  _Float16*  attn16 = (_Float16*)(ws + 25184256); // [8192][8192] f16 (134 MB, big-ws only)
  _Float16*  kpart16 = (_Float16*)attn;           // f16 partial planes in d_out attn region

  const bool bigws = ws_size >= (size_t)(25184256 + 33554432) * 4;

  const dim3 b256(256), b512(512);
  const float qk_scale = 0.04419417382415922f;  // 1/sqrt(512)
  const size_t plane = (size_t)8192 * 512;      // 4,194,304

  transpose_f32_f16<<<dim3(48, 16), b256, 0, stream>>>(Wqkv, 1536, W16T, 512);
  transpose_f32<<<dim3(16, 16), b256, 0, stream>>>(Wo, 512, WoT, 512);

  // K1: qkv16 = f16(x @ Wqkv + bqkv); x read f32, cvt in staging (bit-identical
  // to pre-converted x16 path — conv kernel removed)
  gemm_bt<1, 1, 128, 128, 2, 2, 256, 1, false, 2, 4, 0, 3>
      <<<dim3(12, 64), b256, 0, stream>>>(
      x, 512, 0, W16T, 512, 0, nullptr, 1536, 0, bqkv, 512, 1.0f, qkv16);

  transpose_f16<<<dim3(8, 128), b256, 0, stream>>>(qkv16 + 512, 1536, k0T16, 8192);
  transpose_f16<<<dim3(8, 128), b256, 0, stream>>>(qkv16 + 1024, 1536, vT16, 8192);
  halfcolsum16<<<dim3(512), b256, 0, stream>>>(k0T16, csum);

  // K2: k = A @ k0, split-K 4, partials stored f16 (write+read halve).
  // MINW=4 (6 caused acc scratch-spill, round 12).
  gemm_bt<1, 1, 128, 256, 2, 4, 512, 1, true, 2, 4, 0, 3>
      <<<dim3(2, 64, 4), b512, 0, stream>>>(
      Amat, 8192, 0, k0T16, 8192, 0, nullptr, 512, plane, nullptr, 2048, 1.0f, kpart16);

  // kbuf16 = f16(sum of 4 f16 partials - 0.5*colsum(k0))
  reduce4_f16in<<<dim3(2048), b256, 0, stream>>>(kpart16, kbuf16, plane, csum);

  if (bigws) {
    // K3: f16 TILE-RELATIVE logits -> attn16 (134 MB, L3-resident) + stats
    gemm_ff16<128, 128, 256, true, 4, 1>
        <<<dim3(4096), b256, 0, stream>>>(
        qkv16, 1536, kbuf16, 512, nullptr, attn16, 8192, 512, qk_scale, mx, sm, 64);
    softmax_combine<<<dim3(2048), b256, 0, stream>>>(mx, sm, rowm, rowinv);
    pv_fused<1><<<dim3(4, 128), b512, 0, stream>>>(
        attn16, attn, vT16, rowm, rowinv, mx, vals16);
  } else {
    // fallback: f32 logits in-place (round-15 verified path)
    gemm_ff16<128, 128, 256, true, 4, 0>
        <<<dim3(4096), b256, 0, stream>>>(
        qkv16, 1536, kbuf16, 512, attn, nullptr, 8192, 512, qk_scale, mx, sm, 64);
    softmax_combine<<<dim3(2048), b256, 0, stream>>>(mx, sm, rowm, rowinv);
    pv_fused<0><<<dim3(4, 128), b512, 0, stream>>>(
        attn, attn, vT16, rowm, rowinv, nullptr, vals16);
  }

  // K6: o = (sum of 4 f16 vals partials) @ Wo + bo
  gemm_bt<1, 1, 128, 128, 2, 2, 256, 4, false, 0, 3, 1, 0>
      <<<dim3(4, 64), b256, 0, stream>>>(
      vals16, 512, plane, WoT, 512, 0, o, 512, 0, bo, 512, 1.0f, nullptr);
}

// Round 19
// 532.331 us; speedup vs baseline: 2.3347x; 1.0092x over previous
//
#include <hip/hip_runtime.h>

typedef _Float16 half8 __attribute__((ext_vector_type(8)));
typedef _Float16 half4 __attribute__((ext_vector_type(4)));
typedef float f32x4 __attribute__((ext_vector_type(4)));

// ---------------------------------------------------------------- transpose (f32)
__global__ __launch_bounds__(256) void transpose_f32(
    const float* __restrict__ in, int lda,
    float* __restrict__ out, int ldo)
{
  __shared__ float t[32][33];
  const int tx = threadIdx.x & 31, ty = threadIdx.x >> 5;
  const int bc = blockIdx.x * 32, br = blockIdx.y * 32;
#pragma unroll
  for (int i = 0; i < 4; ++i)
    t[ty + 8 * i][tx] = in[(size_t)(br + ty + 8 * i) * lda + bc + tx];
  __syncthreads();
#pragma unroll
  for (int i = 0; i < 4; ++i)
    out[(size_t)(bc + ty + 8 * i) * ldo + br + tx] = t[tx][ty + 8 * i];
}

// transpose with f32 -> f16 convert on output (weights)
__global__ __launch_bounds__(256) void transpose_f32_f16(
    const float* __restrict__ in, int lda,
    _Float16* __restrict__ out, int ldo)
{
  __shared__ float t[32][33];
  const int tx = threadIdx.x & 31, ty = threadIdx.x >> 5;
  const int bc = blockIdx.x * 32, br = blockIdx.y * 32;
#pragma unroll
  for (int i = 0; i < 4; ++i)
    t[ty + 8 * i][tx] = in[(size_t)(br + ty + 8 * i) * lda + bc + tx];
  __syncthreads();
#pragma unroll
  for (int i = 0; i < 4; ++i)
    out[(size_t)(bc + ty + 8 * i) * ldo + br + tx] = (_Float16)t[tx][ty + 8 * i];
}

// f16 -> f16 transpose, 64x64 tile
__global__ __launch_bounds__(256) void transpose_f16(
    const _Float16* __restrict__ in, int lda,
    _Float16* __restrict__ out, int ldo)
{
  __shared__ _Float16 t[64][66];
  const int tx = threadIdx.x & 63, ty = threadIdx.x >> 6;   // 64 x 4
  const int bc = blockIdx.x * 64, br = blockIdx.y * 64;
#pragma unroll
  for (int i = 0; i < 16; ++i)
    t[ty + 4 * i][tx] = in[(size_t)(br + ty + 4 * i) * lda + bc + tx];
  __syncthreads();
#pragma unroll
  for (int i = 0; i < 16; ++i)
    out[(size_t)(bc + ty + 4 * i) * ldo + br + tx] = t[tx][ty + 4 * i];
}

// ---------------------------------------------------------------- half column-sum (f16 input)
__global__ __launch_bounds__(256) void halfcolsum16(
    const _Float16* __restrict__ k0T16, float* __restrict__ csum)
{
  const int d = blockIdx.x, tid = threadIdx.x;
  float s = 0.f;
#pragma unroll
  for (int i = 0; i < 4; ++i) {
    half8 h = *(const half8*)(k0T16 + (size_t)d * 8192 + i * 2048 + tid * 8);
#pragma unroll
    for (int j = 0; j < 8; ++j) s += (float)h[j];
  }
#pragma unroll
  for (int off = 32; off; off >>= 1) s += __shfl_xor(s, off);
  __shared__ float r[4];
  if ((tid & 63) == 0) r[tid >> 6] = s;
  __syncthreads();
  if (tid == 0) csum[d] = 0.5f * ((r[0] + r[1]) + (r[2] + r[3]));
}

// ---------------------------------------------------------------- GEMM (BT)
// AMODE: 0 = f32 A (cvt in staging; ASPL=1 -> single-pass), 1 = f16 A summed,
//        3 = f16 single plane A (pure copy)
// BMODE: 0 = f32 B, 3 = f16 single plane B (pure copy)
// CMODE: 0 = f32 C store; 2 = f16 C store to c16out (KSPLIT offsets c16out)
template<int ASPL,int BSPL,int BM,int BN,int WAVES_M,int WAVES_N,int THREADS,
         int APART,bool KSPLIT,int CMODE,int MINW,int AMODE,int BMODE>
__global__ __launch_bounds__(THREADS, MINW) void gemm_bt(
    const void* __restrict__ Agv, int lda, size_t a_plane,
    const void* __restrict__ Bgv, int ldb, size_t b_plane,
    float* __restrict__ Cg, int ldc, size_t c_plane,
    const float* __restrict__ bias, int K, float scale,
    _Float16* __restrict__ c16out)
{
  constexpr int BK = 32;
  constexpr int WM = BM / WAVES_M, WN = BN / WAVES_N;
  constexpr int FM = WM / 16, FN = WN / 16;
  constexpr int NCA = (BM * 4) / THREADS;
  constexpr int NCB = (BN * 4) / THREADS;
  static_assert((BM * 4) % THREADS == 0 && (BN * 4) % THREADS == 0, "mismatch");
  static_assert(AMODE != 3 || ASPL == 1, "AMODE 3 needs ASPL 1");

  __shared__ _Float16 ldsA[2][ASPL][BM][BK];
  __shared__ _Float16 ldsB[2][BSPL][BN][BK];

  const float*    Ag   = (const float*)Agv;
  const _Float16* Ag16 = (const _Float16*)Agv;
  const float*    Bg   = (const float*)Bgv;
  const _Float16* Bg16 = (const _Float16*)Bgv;

  const int tid  = threadIdx.x;
  const int lane = tid & 63;
  const int wid  = tid >> 6;
  const int wrow = wid / WAVES_N, wcol = wid % WAVES_N;
  const int l15  = lane & 15, g = lane >> 4;
  const int brow = blockIdx.y * BM;
  const int bcol = blockIdx.x * BN;

  if constexpr (KSPLIT) {
    const int kc = blockIdx.z;
    Ag += (size_t)kc * K;  Ag16 += (size_t)kc * K;
    Bg += (size_t)kc * K;  Bg16 += (size_t)kc * K;
    Cg += (size_t)kc * c_plane;
    if constexpr (CMODE == 2) c16out += (size_t)kc * c_plane;
  }

  f32x4 acc[FM][FN];
#pragma unroll
  for (int mi = 0; mi < FM; ++mi)
#pragma unroll
    for (int ni = 0; ni < FN; ++ni)
      acc[mi][ni] = (f32x4){0.f, 0.f, 0.f, 0.f};

  float4 ra[NCA][2], rb[NCB][2];
  half8  rah[NCA], rbh[NCB];

  auto loadAB = [&](int kt) {
    const int k0 = kt * BK;
#pragma unroll
    for (int i = 0; i < NCA; ++i) {
      int c = tid + THREADS * i;
      int row = c >> 2, ci = c & 3;
      if constexpr (AMODE == 3) {
        rah[i] = *(const half8*)(Ag16 + (size_t)(brow + row) * lda + k0 + ci * 8);
      } else if constexpr (AMODE == 1) {
        float4 u0 = make_float4(0.f, 0.f, 0.f, 0.f);
        float4 u1 = make_float4(0.f, 0.f, 0.f, 0.f);
        const _Float16* bp = Ag16 + (size_t)(brow + row) * lda + k0 + ci * 8;
#pragma unroll
        for (int p = 0; p < APART; ++p) {
          half8 hv = *(const half8*)(bp + (size_t)p * a_plane);
          u0.x += (float)hv[0]; u0.y += (float)hv[1]; u0.z += (float)hv[2]; u0.w += (float)hv[3];
          u1.x += (float)hv[4]; u1.y += (float)hv[5]; u1.z += (float)hv[6]; u1.w += (float)hv[7];
        }
        ra[i][0] = u0; ra[i][1] = u1;
      } else {
        const float* bp = Ag + (size_t)(brow + row) * lda + k0 + ci * 8;
        float4 u0 = ((const float4*)bp)[0];
        float4 u1 = ((const float4*)bp)[1];
#pragma unroll
        for (int p = 1; p < APART; ++p) {
          const float* pp = bp + (size_t)p * a_plane;
          float4 w0 = ((const float4*)pp)[0], w1 = ((const float4*)pp)[1];
          u0.x += w0.x; u0.y += w0.y; u0.z += w0.z; u0.w += w0.w;
          u1.x += w1.x; u1.y += w1.y; u1.z += w1.z; u1.w += w1.w;
        }
        ra[i][0] = u0; ra[i][1] = u1;
      }
    }
#pragma unroll
    for (int i = 0; i < NCB; ++i) {
      int c = tid + THREADS * i;
      int row = c >> 2, ci = c & 3;
      if constexpr (BMODE == 3) {
        rbh[i] = *(const half8*)(Bg16 + (size_t)(bcol + row) * ldb + k0 + ci * 8);
      } else {
        const float4* p = (const float4*)(Bg + (size_t)(bcol + row) * ldb + k0 + ci * 8);
        rb[i][0] = p[0]; rb[i][1] = p[1];
      }
    }
  };

  auto stageLDS = [&](int b) {
#pragma unroll
    for (int i = 0; i < NCA; ++i) {
      int c = tid + THREADS * i;
      int row = c >> 2, ci = c & 3;
      int off = row * BK + ((ci ^ ((row >> 1) & 3)) << 3);
      if constexpr (AMODE == 3) {
        *(half8*)(&ldsA[b][0][0][0] + off) = rah[i];
      } else {
        float f[8] = {ra[i][0].x, ra[i][0].y, ra[i][0].z, ra[i][0].w,
                      ra[i][1].x, ra[i][1].y, ra[i][1].z, ra[i][1].w};
        half8 h, l;
#pragma unroll
        for (int j = 0; j < 8; ++j) {
          _Float16 hv = (_Float16)f[j];
          h[j] = hv;
          if (ASPL == 2) l[j] = (_Float16)(f[j] - (float)hv);
        }
        *(half8*)(&ldsA[b][0][0][0] + off) = h;
        if (ASPL == 2) *(half8*)(&ldsA[b][1][0][0] + off) = l;
      }
    }
#pragma unroll
    for (int i = 0; i < NCB; ++i) {
      int c = tid + THREADS * i;
      int row = c >> 2, ci = c & 3;
      int off = row * BK + ((ci ^ ((row >> 1) & 3)) << 3);
      if constexpr (BMODE == 3) {
        *(half8*)(&ldsB[b][0][0][0] + off) = rbh[i];
      } else {
        float f[8] = {rb[i][0].x, rb[i][0].y, rb[i][0].z, rb[i][0].w,
                      rb[i][1].x, rb[i][1].y, rb[i][1].z, rb[i][1].w};
        half8 h, l;
#pragma unroll
        for (int j = 0; j < 8; ++j) {
          _Float16 hv = (_Float16)f[j];
          h[j] = hv;
          if (BSPL == 2) l[j] = (_Float16)(f[j] - (float)hv);
        }
        *(half8*)(&ldsB[b][0][0][0] + off) = h;
        if (BSPL == 2) *(half8*)(&ldsB[b][1][0][0] + off) = l;
      }
    }
  };

  const int nk = K / BK;
  loadAB(0);
  stageLDS(0);
  if (nk > 1) loadAB(1);
  __syncthreads();

  for (int kt = 0; kt < nk; ++kt) {
    const int cur = kt & 1, nxt = cur ^ 1;
    if (kt + 1 < nk) stageLDS(nxt);
    if (kt + 2 < nk) loadAB(kt + 2);

    half8 af[FM][ASPL];
#pragma unroll
    for (int mi = 0; mi < FM; ++mi)
#pragma unroll
      for (int sa = 0; sa < ASPL; ++sa) {
        int row = wrow * WM + mi * 16 + l15;
        af[mi][sa] = *(const half8*)(&ldsA[cur][sa][0][0] + row * BK + ((g ^ ((row >> 1) & 3)) << 3));
      }
#pragma unroll
    for (int ni = 0; ni < FN; ++ni) {
      half8 bf[BSPL];
#pragma unroll
      for (int sb = 0; sb < BSPL; ++sb) {
        int row = wcol * WN + ni * 16 + l15;
        bf[sb] = *(const half8*)(&ldsB[cur][sb][0][0] + row * BK + ((g ^ ((row >> 1) & 3)) << 3));
      }
#pragma unroll
      for (int mi = 0; mi < FM; ++mi)
#pragma unroll
        for (int sa = 0; sa < ASPL; ++sa)
#pragma unroll
          for (int sb = 0; sb < BSPL; ++sb) {
            if (ASPL == 2 && BSPL == 2 && sa == 1 && sb == 1) continue;
            acc[mi][ni] = __builtin_amdgcn_mfma_f32_16x16x32_f16(af[mi][sa], bf[sb], acc[mi][ni], 0, 0, 0);
          }
    }
    __syncthreads();
  }

#pragma unroll
  for (int mi = 0; mi < FM; ++mi)
#pragma unroll
    for (int ni = 0; ni < FN; ++ni) {
      int col = bcol + wcol * WN + ni * 16 + l15;
      float bv = bias ? bias[col] : 0.f;
#pragma unroll
      for (int j = 0; j < 4; ++j) {
        int r = brow + wrow * WM + mi * 16 + g * 4 + j;
        float v = acc[mi][ni][j] * scale + bv;
        if constexpr (CMODE == 2) {
          c16out[(size_t)r * ldc + col] = (_Float16)v;   // f16-only C
        } else {
          Cg[(size_t)r * ldc + col] = v;
        }
      }
    }
}

// ---------------------------------------------------------------- GEMM f16 x f16 (K3)
// XCD-bijective 1-D swizzle. CM: 0 = f32 absolute logits;
// CM=1: store P = f16(exp(l - m_tile)) (in (0,1]; rel err 2^-11; reuses the
// exp already computed for the stats sum — pv then just multiplies).
template<int BM,int BN,int THREADS,bool STATS,int MINW,int CM>
__global__ __launch_bounds__(THREADS, MINW) void gemm_ff16(
    const _Float16* __restrict__ Ag, int lda,
    const _Float16* __restrict__ Bg, int ldb,
    float* __restrict__ Cg, _Float16* __restrict__ Cg16, int ldc,
    int K, float scale,
    float* __restrict__ mxout, float* __restrict__ smout, int ntiles)
{
  constexpr int BK = 32;
  constexpr int WAVES_M = 2, WAVES_N = 2;
  constexpr int WM = BM / WAVES_M, WN = BN / WAVES_N;
  constexpr int FM = WM / 16, FN = WN / 16;
  constexpr int NCA = (BM * 4) / THREADS;
  constexpr int NCB = (BN * 4) / THREADS;

  __shared__ _Float16 ldsA[2][BM][BK];
  __shared__ _Float16 ldsB[2][BN][BK];

  const int tid  = threadIdx.x;
  const int lane = tid & 63;
  const int wid  = tid >> 6;
  const int wrow = wid >> 1, wcol = wid & 1;
  const int l15  = lane & 15, g = lane >> 4;

  const int id = blockIdx.x;                 // 0..4095
  const int wgid = (id & 7) * 512 + (id >> 3);
  const int bxv = wgid & 63, byv = wgid >> 6;
  const int brow = byv * BM;
  const int bcol = bxv * BN;

  f32x4 acc[FM][FN];
#pragma unroll
  for (int mi = 0; mi < FM; ++mi)
#pragma unroll
    for (int ni = 0; ni < FN; ++ni)
      acc[mi][ni] = (f32x4){0.f, 0.f, 0.f, 0.f};

  half8 ra[NCA], rb[NCB];

  auto loadAB = [&](int kt) {
    const int k0 = kt * BK;
#pragma unroll
    for (int i = 0; i < NCA; ++i) {
      int c = tid + THREADS * i;
      int row = c >> 2, ci = c & 3;
      ra[i] = *(const half8*)(Ag + (size_t)(brow + row) * lda + k0 + ci * 8);
    }
#pragma unroll
    for (int i = 0; i < NCB; ++i) {
      int c = tid + THREADS * i;
      int row = c >> 2, ci = c & 3;
      rb[i] = *(const half8*)(Bg + (size_t)(bcol + row) * ldb + k0 + ci * 8);
    }
  };

  auto stageLDS = [&](int b) {
#pragma unroll
    for (int i = 0; i < NCA; ++i) {
      int c = tid + THREADS * i;
      int row = c >> 2, ci = c & 3;
      int off = row * BK + ((ci ^ ((row >> 1) & 3)) << 3);
      *(half8*)(&ldsA[b][0][0] + off) = ra[i];
    }
#pragma unroll
    for (int i = 0; i < NCB; ++i) {
      int c = tid + THREADS * i;
      int row = c >> 2, ci = c & 3;
      int off = row * BK + ((ci ^ ((row >> 1) & 3)) << 3);
      *(half8*)(&ldsB[b][0][0] + off) = rb[i];
    }
  };

  const int nk = K / BK;
  loadAB(0);
  stageLDS(0);
  if (nk > 1) loadAB(1);
  __syncthreads();

  for (int kt = 0; kt < nk; ++kt) {
    const int cur = kt & 1, nxt = cur ^ 1;
    if (kt + 1 < nk) stageLDS(nxt);
    if (kt + 2 < nk) loadAB(kt + 2);

    half8 af[FM];
#pragma unroll
    for (int mi = 0; mi < FM; ++mi) {
      int row = wrow * WM + mi * 16 + l15;
      af[mi] = *(const half8*)(&ldsA[cur][0][0] + row * BK + ((g ^ ((row >> 1) & 3)) << 3));
    }
#pragma unroll
    for (int ni = 0; ni < FN; ++ni) {
      int row = wcol * WN + ni * 16 + l15;
      half8 bf = *(const half8*)(&ldsB[cur][0][0] + row * BK + ((g ^ ((row >> 1) & 3)) << 3));
#pragma unroll
      for (int mi = 0; mi < FM; ++mi)
        acc[mi][ni] = __builtin_amdgcn_mfma_f32_16x16x32_f16(af[mi], bf, acc[mi][ni], 0, 0, 0);
    }
    __syncthreads();
  }

  if constexpr (CM == 0) {
#pragma unroll
    for (int mi = 0; mi < FM; ++mi)
#pragma unroll
      for (int ni = 0; ni < FN; ++ni) {
        int col = bcol + wcol * WN + ni * 16 + l15;
#pragma unroll
        for (int j = 0; j < 4; ++j) {
          int r = brow + wrow * WM + mi * 16 + g * 4 + j;
          Cg[(size_t)r * ldc + col] = acc[mi][ni][j] * scale;
        }
      }
  }

  if constexpr (STATS) {
    __shared__ float s_m2[BM][2];
    __shared__ float s_s2[BM][2];
#pragma unroll
    for (int mi = 0; mi < FM; ++mi)
#pragma unroll
      for (int j = 0; j < 4; ++j) {
        float v = -3.4e38f;
#pragma unroll
        for (int ni = 0; ni < FN; ++ni) v = fmaxf(v, acc[mi][ni][j] * scale);
        v = fmaxf(v, __shfl_xor(v, 1)); v = fmaxf(v, __shfl_xor(v, 2));
        v = fmaxf(v, __shfl_xor(v, 4)); v = fmaxf(v, __shfl_xor(v, 8));
        if (l15 == 0) s_m2[wrow * WM + mi * 16 + g * 4 + j][wcol] = v;
      }
    __syncthreads();
#pragma unroll
    for (int mi = 0; mi < FM; ++mi)
#pragma unroll
      for (int j = 0; j < 4; ++j) {
        int r = wrow * WM + mi * 16 + g * 4 + j;
        float mt = fmaxf(s_m2[r][0], s_m2[r][1]);
        float s = 0.f;
#pragma unroll
        for (int ni = 0; ni < FN; ++ni) {
          float lv = acc[mi][ni][j] * scale - mt;   // <= 0 by construction
          float ev = __expf(lv);
          s += ev;
          if constexpr (CM == 1) {
            int col = bcol + wcol * WN + ni * 16 + l15;
            Cg16[(size_t)(brow + r) * ldc + col] = (_Float16)ev;   // P in (0,1]
          }
        }
        s += __shfl_xor(s, 1); s += __shfl_xor(s, 2);
        s += __shfl_xor(s, 4); s += __shfl_xor(s, 8);
        if (l15 == 0) s_s2[r][wcol] = s;
      }
    __syncthreads();
    if (tid < BM) {
      float mt = fmaxf(s_m2[tid][0], s_m2[tid][1]);
      float st = s_s2[tid][0] + s_s2[tid][1];
      mxout[(size_t)(brow + tid) * ntiles + bxv] = mt;
      smout[(size_t)(brow + tid) * ntiles + bxv] = st;
    }
  }
}

// ---------------------------------------------------------------- reduce 4 f16 planes -> f16
__global__ __launch_bounds__(256) void reduce4_f16in(
    const _Float16* __restrict__ in, _Float16* __restrict__ out16, size_t planeE,
    const float* __restrict__ csum)
{
  size_t i = ((size_t)blockIdx.x * 256 + threadIdx.x) * 8;
  half8 a = *(const half8*)(in + i);
  half8 b = *(const half8*)(in + planeE + i);
  half8 c = *(const half8*)(in + 2 * planeE + i);
  half8 d = *(const half8*)(in + 3 * planeE + i);
  const int col = (int)(i & 511);
  half8 h;
#pragma unroll
  for (int j = 0; j < 8; ++j) {
    float s = ((float)a[j] + (float)b[j]) + ((float)c[j] + (float)d[j]) - csum[col + j];
    h[j] = (_Float16)s;
  }
  *(half8*)(out16 + i) = h;
}

// ---------------------------------------------------------------- stats combine
__global__ __launch_bounds__(256) void softmax_combine(
    const float* __restrict__ mx, const float* __restrict__ sm,
    float* __restrict__ rowm, float* __restrict__ rowinv)
{
  const int row = blockIdx.x * 4 + (threadIdx.x >> 6);
  const int lane = threadIdx.x & 63;
  float mt = mx[(size_t)row * 64 + lane];
  float m = mt;
#pragma unroll
  for (int off = 32; off; off >>= 1) m = fmaxf(m, __shfl_xor(m, off));
  float s = sm[(size_t)row * 64 + lane] * __expf(mt - m);
#pragma unroll
  for (int off = 32; off; off >>= 1) s += __shfl_xor(s, off);
  if (lane == 0) { rowm[row] = m; rowinv[row] = 1.0f / s; }
}

// ---------------------------------------------------------------- fused attn-write + PV
// A16=0: f32 absolute logits in-place (exp in stage). A16=1: f16 P-values
// (exp(l-m_tile)) in lin; stage multiplies by precomputed fac[row][tile] =
// exp(m_tile - m_row) * inv — no per-step exp at all.
template<int A16>
__global__ __launch_bounds__(512, 4) void pv_fused(
    const void* __restrict__ lin,        // logits f32 OR P-values f16
    float* __restrict__ attn_out,        // [8192][8192] attention out
    const _Float16* __restrict__ vT16,   // [512][8192] f16
    const float* __restrict__ rowm, const float* __restrict__ rowinv,
    const float* __restrict__ mxbuf,     // [8192][64] per-(row,tile) maxes
    _Float16* __restrict__ vals16)       // [4][8192][512] f16
{
  constexpr int BM = 64, BN = 512, BK = 32, NSTEP = 64;  // KC = 2048
  __shared__ _Float16 ldsA[2][BM][BK];   // 8 KB
  __shared__ _Float16 ldsB[2][BN][BK];   // 64 KB
  __shared__ float s_m[BM], s_inv[BM];
  __shared__ float s_fac[BM][16];        // 4 KB (A16): exp(m_tile-m_row)*inv

  const int tid = threadIdx.x, lane = tid & 63, wid = tid >> 6;
  const int wrow = wid >> 2, wcol = wid & 3;   // 2 x 4 waves
  const int l15 = lane & 15, g = lane >> 4;
  const int kc = blockIdx.x, brow = blockIdx.y * BM;
  const size_t kbase = (size_t)kc * 2048;

  const float*    lf32 = (const float*)lin;
  const _Float16* lf16 = (const _Float16*)lin;

  if (tid < BM) { s_m[tid] = rowm[brow + tid]; s_inv[tid] = rowinv[brow + tid]; }
  if constexpr (A16 == 1) {
#pragma unroll
    for (int i = 0; i < 2; ++i) {
      int idx = tid + i * 512;               // 1024 entries = 64 rows x 16 tiles
      int row = idx >> 4, t = idx & 15;
      float mr = rowm[brow + row];
      float iv = rowinv[brow + row];
      s_fac[row][t] = __expf(mxbuf[(size_t)(brow + row) * 64 + kc * 16 + t] - mr) * iv;
    }
  }

  f32x4 acc[2][8];
#pragma unroll
  for (int mi = 0; mi < 2; ++mi)
#pragma unroll
    for (int ni = 0; ni < 8; ++ni) acc[mi][ni] = (f32x4){0.f, 0.f, 0.f, 0.f};

  const int arow = (tid & 255) >> 2, aci = tid & 3;
  float4 ra[2];
  half8 ra16;
  half8 rbh[4];

  auto loadA = [&](int kt) {
    if (tid < 256) {
      if constexpr (A16 == 1) {
        ra16 = *(const half8*)(lf16 + (size_t)(brow + arow) * 8192 + kbase + kt * BK + aci * 8);
      } else {
        const float4* p = (const float4*)(lf32 + (size_t)(brow + arow) * 8192 + kbase + kt * BK + aci * 8);
        ra[0] = p[0]; ra[1] = p[1];
      }
    }
  };
  auto loadB = [&](int kt) {
#pragma unroll
    for (int i = 0; i < 4; ++i) {
      int c = tid + 512 * i; int r = c >> 2, ci = c & 3;
      rbh[i] = *(const half8*)(vT16 + (size_t)r * 8192 + kbase + kt * BK + ci * 8);
    }
  };
  auto stage = [&](int kt, int b) {
    if (tid < 256) {
      float e[8]; half8 h;
      if constexpr (A16 == 1) {
        const float fac = s_fac[arow][kt >> 2];
#pragma unroll
        for (int j = 0; j < 8; ++j) {
          e[j] = (float)ra16[j] * fac;      // attention = P * exp(m_t-m) * inv
          h[j] = (_Float16)e[j];
        }
      } else {
        const float m = s_m[arow], inv = s_inv[arow];
        float f[8];
#pragma unroll
        for (int j = 0; j < 4; ++j) { f[j] = (&ra[0].x)[j] - m; f[4 + j] = (&ra[1].x)[j] - m; }
#pragma unroll
        for (int j = 0; j < 8; ++j) {
          e[j] = __expf(f[j]) * inv;
          h[j] = (_Float16)e[j];
        }
      }
      float4* w = (float4*)(attn_out + (size_t)(brow + arow) * 8192 + kbase + kt * BK + aci * 8);
      w[0] = make_float4(e[0], e[1], e[2], e[3]);
      w[1] = make_float4(e[4], e[5], e[6], e[7]);
      int off = arow * BK + ((aci ^ ((arow >> 1) & 3)) << 3);
      *(half8*)(&ldsA[b][0][0] + off) = h;
    }
#pragma unroll
    for (int i = 0; i < 4; ++i) {
      int c = tid + 512 * i; int r = c >> 2, ci = c & 3;
      int off2 = r * BK + ((ci ^ ((r >> 1) & 3)) << 3);
      *(half8*)(&ldsB[b][0][0] + off2) = rbh[i];
    }
  };

  loadA(0); loadB(0);
  __syncthreads();            // s_m / s_inv / s_fac visible
  stage(0, 0);
  loadA(1); loadB(1);
  __syncthreads();            // buf0 staged

  for (int kt = 0; kt < NSTEP; ++kt) {
    const int cur = kt & 1, nxt = cur ^ 1;
    if (kt + 1 < NSTEP) stage(kt + 1, nxt);
    if (kt + 2 < NSTEP) { loadA(kt + 2); loadB(kt + 2); }
    half8 af[2];
#pragma unroll
    for (int mi = 0; mi < 2; ++mi) {
      int row = wrow * 32 + mi * 16 + l15;
      af[mi] = *(const half8*)(&ldsA[cur][0][0] + row * BK + ((g ^ ((row >> 1) & 3)) << 3));
    }
    __builtin_amdgcn_s_setprio(1);
#pragma unroll
    for (int ni = 0; ni < 8; ++ni) {
      int rn = wcol * 128 + ni * 16 + l15;
      half8 bf = *(const half8*)(&ldsB[cur][0][0] + rn * BK + ((g ^ ((rn >> 1) & 3)) << 3));
#pragma unroll
      for (int mi = 0; mi < 2; ++mi)
        acc[mi][ni] = __builtin_amdgcn_mfma_f32_16x16x32_f16(af[mi], bf, acc[mi][ni], 0, 0, 0);
    }
    __builtin_amdgcn_s_setprio(0);
    __syncthreads();
  }

  const size_t plane = (size_t)8192 * 512;
#pragma unroll
  for (int mi = 0; mi < 2; ++mi)
#pragma unroll
    for (int ni = 0; ni < 8; ++ni) {
      int col = wcol * 128 + ni * 16 + l15;
#pragma unroll
      for (int j = 0; j < 4; ++j) {
        int row = brow + wrow * 32 + mi * 16 + g * 4 + j;
        vals16[(size_t)kc * plane + (size_t)row * 512 + col] = (_Float16)acc[mi][ni][j];
      }
    }
}

// ---------------------------------------------------------------- launch
extern "C" void kernel_launch(void* const* d_in, const int* in_sizes, int n_in,
                              void* d_out, int out_size, void* d_ws, size_t ws_size,
                              hipStream_t stream)
{
  const float* x    = (const float*)d_in[0];
  const float* Amat = (const float*)d_in[1];
  const float* Wqkv = (const float*)d_in[2];
  const float* bqkv = (const float*)d_in[3];
  const float* Wo   = (const float*)d_in[4];
  const float* bo   = (const float*)d_in[5];

  float* o    = (float*)d_out;                       // [8192,512]
  float* attn = (float*)d_out + (size_t)8192 * 512;  // [8192,8192]

  float* ws = (float*)d_ws;
  _Float16*  vals16 = (_Float16*)ws;              // [4][8192][512] f16 (33.5 MB)
  _Float16*  qkv16  = (_Float16*)(ws + 8388608);  // [8192][1536] f16; q view (lda 1536)
  _Float16*  k0T16  = (_Float16*)(ws + 14680064); // [512][8192] f16
  _Float16*  vT16   = (_Float16*)(ws + 16777216); // [512][8192] f16
  _Float16*  W16T   = (_Float16*)(ws + 18874368); // [1536][512] f16
  float*     WoT    = ws + 19660800;              // [512][512] f32
  _Float16*  kbuf16 = (_Float16*)(ws + 19922944); // [8192][512] f16
  float*     mx     = ws + 24117248;
  float*     sm     = ws + 24641536;
  float*     rowm   = ws + 25165824;
  float*     rowinv = ws + 25174016;
  float*     csum   = ws + 25182208;
  _Float16*  attn16 = (_Float16*)(ws + 25184256); // [8192][8192] f16 (134 MB, big-ws only)
  _Float16*  kpart16 = (_Float16*)attn;           // f16 partial planes in d_out attn region

  const bool bigws = ws_size >= (size_t)(25184256 + 33554432) * 4;

  const dim3 b256(256), b512(512);
  const float qk_scale = 0.04419417382415922f;  // 1/sqrt(512)
  const size_t plane = (size_t)8192 * 512;      // 4,194,304

  transpose_f32_f16<<<dim3(48, 16), b256, 0, stream>>>(Wqkv, 1536, W16T, 512);
  transpose_f32<<<dim3(16, 16), b256, 0, stream>>>(Wo, 512, WoT, 512);

  // K1: qkv16 = f16(x @ Wqkv + bqkv); x read f32, cvt in staging
  gemm_bt<1, 1, 128, 128, 2, 2, 256, 1, false, 2, 4, 0, 3>
      <<<dim3(12, 64), b256, 0, stream>>>(
      x, 512, 0, W16T, 512, 0, nullptr, 1536, 0, bqkv, 512, 1.0f, qkv16);

  transpose_f16<<<dim3(8, 128), b256, 0, stream>>>(qkv16 + 512, 1536, k0T16, 8192);
  transpose_f16<<<dim3(8, 128), b256, 0, stream>>>(qkv16 + 1024, 1536, vT16, 8192);
  halfcolsum16<<<dim3(512), b256, 0, stream>>>(k0T16, csum);

  // K2: k = A @ k0, split-K 4, partials stored f16.
  // MINW=4 (6 caused acc scratch-spill, round 12).
  gemm_bt<1, 1, 128, 256, 2, 4, 512, 1, true, 2, 4, 0, 3>
      <<<dim3(2, 64, 4), b512, 0, stream>>>(
      Amat, 8192, 0, k0T16, 8192, 0, nullptr, 512, plane, nullptr, 2048, 1.0f, kpart16);

  // kbuf16 = f16(sum of 4 f16 partials - 0.5*colsum(k0))
  reduce4_f16in<<<dim3(2048), b256, 0, stream>>>(kpart16, kbuf16, plane, csum);

  if (bigws) {
    // K3: P = f16(exp(l - m_tile)) -> attn16 (L3-resident) + stats
    gemm_ff16<128, 128, 256, true, 4, 1>
        <<<dim3(4096), b256, 0, stream>>>(
        qkv16, 1536, kbuf16, 512, nullptr, attn16, 8192, 512, qk_scale, mx, sm, 64);
    softmax_combine<<<dim3(2048), b256, 0, stream>>>(mx, sm, rowm, rowinv);
    pv_fused<1><<<dim3(4, 128), b512, 0, stream>>>(
        attn16, attn, vT16, rowm, rowinv, mx, vals16);
  } else {
    // fallback: f32 logits in-place (round-15 verified path)
    gemm_ff16<128, 128, 256, true, 4, 0>
        <<<dim3(4096), b256, 0, stream>>>(
        qkv16, 1536, kbuf16, 512, attn, nullptr, 8192, 512, qk_scale, mx, sm, 64);
    softmax_combine<<<dim3(2048), b256, 0, stream>>>(mx, sm, rowm, rowinv);
    pv_fused<0><<<dim3(4, 128), b512, 0, stream>>>(
        attn, attn, vT16, rowm, rowinv, nullptr, vals16);
  }

  // K6: o = (sum of 4 f16 vals partials) @ Wo + bo
  gemm_bt<1, 1, 128, 128, 2, 2, 256, 4, false, 0, 3, 1, 0>
      <<<dim3(4, 64), b256, 0, stream>>>(
      vals16, 512, plane, WoT, 512, 0, o, 512, 0, bo, 512, 1.0f, nullptr);
}